// Round 2
// baseline (6036.165 us; speedup 1.0000x reference)
//
#include <hip/hip_runtime.h>
#include <cstdint>
#include <cstddef>

#define NN 100000
#define NE 1600000
#define HID 128
#define BN_EPS 1e-5f
#define NB_SCAN 98  // ceil(100000/1024)

// ---------------- workspace layout (bytes) ----------------
static constexpr size_t SZ_NODE = (size_t)NN * HID * 4;            // 51.2 MB
static constexpr size_t OFF_P   = 0;                               // h ping
static constexpr size_t OFF_Q   = SZ_NODE;                         // h pong / work
static constexpr size_t OFF_R   = 2 * SZ_NODE;                     // readout accumulator
static constexpr size_t OFF_CSR = 3 * SZ_NODE;                     // [NE] int32
static constexpr size_t OFF_RP  = OFF_CSR + (size_t)NE * 4;        // [NN+1] int32
static constexpr size_t OFF_ZZ  = ((OFF_RP + (size_t)(NN + 1) * 4 + 255) / 256) * 256;
static constexpr size_t OFF_CNT = OFF_ZZ;                          // [NN] int32
static constexpr size_t OFF_BS  = OFF_CNT + (((size_t)NN * 4 + 255) / 256) * 256;
static constexpr size_t OFF_ST  = OFF_BS + 512;                    // 6 x 256 f32
static constexpr size_t OFF_FLG = OFF_ST + 6 * 256 * 4;            // int flag
static constexpr size_t ZZ_END  = ((OFF_FLG + 4 + 255) / 256) * 256;
static constexpr size_t ZZ_BYTES = ZZ_END - OFF_ZZ;
static constexpr size_t OFF_AC  = ZZ_END;                          // 6 x 256 f32
static constexpr size_t WS_NEEDED = OFF_AC + 6 * 256 * 4;          // ~160.8 MB

// edge accessor: f==1 -> data is int64 little-endian, take low word
__device__ __forceinline__ int edge_at(const int* __restrict__ E, int f, int idx) {
  return f ? E[2 * (long long)idx] : E[idx];
}

// ---------------- dtype detection ----------------
__global__ void k_detect(const int* __restrict__ E, int* __restrict__ flag) {
  if (threadIdx.x == 0 && blockIdx.x == 0) {
    int f = 1;
    for (int i = 1; i < 256; i += 2)
      if (E[i] != 0) { f = 0; break; }
    *flag = f;
  }
}

// ---------------- embedding: h[n] = emb[x[n]] ----------------
__global__ __launch_bounds__(256) void k_embed(const int* __restrict__ x,
                                               const float* __restrict__ emb,
                                               float* __restrict__ h) {
  const int total = NN * 32;  // float4s
  for (int i = blockIdx.x * blockDim.x + threadIdx.x; i < total;
       i += gridDim.x * blockDim.x) {
    const int node = i >> 5, q = i & 31;
    const int xv = x[node] & 1;
    const float4 v = ((const float4*)emb)[(xv << 5) + q];
    ((float4*)(h + (size_t)node * HID))[q] = v;
  }
}

// ---------------- CSR build ----------------
__global__ __launch_bounds__(256) void k_hist(const int* __restrict__ E,
                                              const int* __restrict__ flag,
                                              int* __restrict__ cnt) {
  const int f = *flag;
  for (int e = blockIdx.x * blockDim.x + threadIdx.x; e < NE;
       e += gridDim.x * blockDim.x) {
    int d = edge_at(E, f, NE + e);
    d = min(max(d, 0), NN - 1);
    atomicAdd(&cnt[d], 1);
  }
}

__global__ __launch_bounds__(256) void k_scan1(const int* __restrict__ cnt,
                                               int* __restrict__ rp,
                                               int* __restrict__ bs) {
  __shared__ int s[256];
  const int tid = threadIdx.x;
  const int base = blockIdx.x * 1024 + tid * 4;
  int v0 = 0, v1 = 0, v2 = 0, v3 = 0;
  if (base + 0 < NN) v0 = cnt[base + 0];
  if (base + 1 < NN) v1 = cnt[base + 1];
  if (base + 2 < NN) v2 = cnt[base + 2];
  if (base + 3 < NN) v3 = cnt[base + 3];
  const int t0 = v0, t1 = t0 + v1, t2 = t1 + v2, t3 = t2 + v3;
  s[tid] = t3;
  __syncthreads();
  for (int off = 1; off < 256; off <<= 1) {
    int xv = 0;
    if (tid >= off) xv = s[tid - off];
    __syncthreads();
    if (tid >= off) s[tid] += xv;
    __syncthreads();
  }
  const int excl = tid ? s[tid - 1] : 0;
  if (base + 0 < NN) rp[base + 0] = excl;
  if (base + 1 < NN) rp[base + 1] = excl + t0;
  if (base + 2 < NN) rp[base + 2] = excl + t1;
  if (base + 3 < NN) rp[base + 3] = excl + t2;
  if (tid == 255) bs[blockIdx.x] = s[255];
}

__global__ __launch_bounds__(128) void k_scan2(int* __restrict__ bs) {
  __shared__ int s[128];
  const int tid = threadIdx.x;
  s[tid] = (tid < NB_SCAN) ? bs[tid] : 0;
  __syncthreads();
  for (int off = 1; off < 128; off <<= 1) {
    int xv = 0;
    if (tid >= off) xv = s[tid - off];
    __syncthreads();
    if (tid >= off) s[tid] += xv;
    __syncthreads();
  }
  if (tid < NB_SCAN) bs[tid] = tid ? s[tid - 1] : 0;  // exclusive block offsets
}

__global__ __launch_bounds__(256) void k_scan3(int* __restrict__ rp,
                                               const int* __restrict__ bs,
                                               int* __restrict__ cursor) {
  const int off = bs[blockIdx.x];
  const int base = blockIdx.x * 1024 + threadIdx.x * 4;
  #pragma unroll
  for (int j = 0; j < 4; ++j) {
    const int i = base + j;
    if (i < NN) {
      const int v = rp[i] + off;
      rp[i] = v;
      cursor[i] = v;
    }
  }
  if (blockIdx.x == 0 && threadIdx.x == 0) rp[NN] = NE;
}

__global__ __launch_bounds__(256) void k_scatter(const int* __restrict__ E,
                                                 const int* __restrict__ flag,
                                                 int* __restrict__ cursor,
                                                 int* __restrict__ csr) {
  const int f = *flag;
  for (int e = blockIdx.x * blockDim.x + threadIdx.x; e < NE;
       e += gridDim.x * blockDim.x) {
    int s = edge_at(E, f, e);
    int d = edge_at(E, f, NE + e);
    s = min(max(s, 0), NN - 1);
    d = min(max(d, 0), NN - 1);
    const int pos = atomicAdd(&cursor[d], 1);
    if ((unsigned)pos < (unsigned)NE) csr[pos] = s;
  }
}

// ---------------- aggregation: z[n] = h[n] + sum_{src in row n} h[src] ----------------
__global__ __launch_bounds__(256) void k_agg(const float* __restrict__ h,
                                             const int* __restrict__ rp,
                                             const int* __restrict__ csr,
                                             float* __restrict__ z) {
  const int wid = blockIdx.x * 4 + (threadIdx.x >> 6);
  const int lane = threadIdx.x & 63;
  if (wid >= NN) return;
  const int beg = rp[wid], end = rp[wid + 1];
  float2 acc = *(const float2*)(h + (size_t)wid * HID + lane * 2);
  for (int j = beg; j < end; j += 64) {
    const int cnt = min(64, end - j);
    int idx = (lane < cnt) ? csr[j + lane] : 0;
    idx = min(max(idx, 0), NN - 1);
    int k = 0;
    for (; k + 4 <= cnt; k += 4) {
      const int s0 = __shfl(idx, k + 0), s1 = __shfl(idx, k + 1);
      const int s2 = __shfl(idx, k + 2), s3 = __shfl(idx, k + 3);
      const float2 v0 = *(const float2*)(h + (size_t)s0 * HID + lane * 2);
      const float2 v1 = *(const float2*)(h + (size_t)s1 * HID + lane * 2);
      const float2 v2 = *(const float2*)(h + (size_t)s2 * HID + lane * 2);
      const float2 v3 = *(const float2*)(h + (size_t)s3 * HID + lane * 2);
      acc.x += (v0.x + v1.x) + (v2.x + v3.x);
      acc.y += (v0.y + v1.y) + (v2.y + v3.y);
    }
    for (; k < cnt; ++k) {
      const int s = __shfl(idx, k);
      const float2 v = *(const float2*)(h + (size_t)s * HID + lane * 2);
      acc.x += v.x;
      acc.y += v.y;
    }
  }
  *(float2*)(z + (size_t)wid * HID + lane * 2) = acc;
}

// ---------------- fused GEMM: out[n,:] (+)= act(A[n,:]) @ W  (K = HID) ----------------
// IN_ACT: 0 = identity, 1 = relu(A*ina + inc) applied at LDS staging
// OUT_MODE: 0 = store + column stats, 1 = store, 2 = accumulate (+=)
#define BM 96
#define KTT 64
#define AS_LD 68

template <int IN_ACT, int OUT_MODE>
__global__ __launch_bounds__(256, 2) void k_gemm(
    const float* __restrict__ A, const float* __restrict__ W,
    const float* __restrict__ ina, const float* __restrict__ inc,
    float* __restrict__ out, float* __restrict__ stats) {
  __shared__ __align__(16) float As[BM * AS_LD];
  __shared__ __align__(16) float Ws[KTT * HID];
  const int tid = threadIdx.x;
  const int tx = tid & 15, ty = tid >> 4;
  const int m0 = blockIdx.x * BM;

  float acc[6][8];
  #pragma unroll
  for (int r = 0; r < 6; ++r)
    #pragma unroll
    for (int c = 0; c < 8; ++c) acc[r][c] = 0.f;

  for (int kt = 0; kt < HID; kt += KTT) {
    if (kt) __syncthreads();
    // stage A tile [BM][KTT]
    #pragma unroll
    for (int p = 0; p < 6; ++p) {
      const int flat = p * 256 + tid;
      const int m = flat >> 4, kq = flat & 15;
      const int gm = m0 + m, gk = kt + kq * 4;
      float4 v = make_float4(0.f, 0.f, 0.f, 0.f);
      if (gm < NN) {
        v = *(const float4*)(A + (size_t)gm * HID + gk);
        if (IN_ACT == 1) {
          const float4 a4 = *(const float4*)(ina + gk);
          const float4 c4 = *(const float4*)(inc + gk);
          v.x = fmaxf(fmaf(v.x, a4.x, c4.x), 0.f);
          v.y = fmaxf(fmaf(v.y, a4.y, c4.y), 0.f);
          v.z = fmaxf(fmaf(v.z, a4.z, c4.z), 0.f);
          v.w = fmaxf(fmaf(v.w, a4.w, c4.w), 0.f);
        }
      }
      *(float4*)(&As[m * AS_LD + kq * 4]) = v;
    }
    // stage W tile [KTT][HID]
    #pragma unroll
    for (int p = 0; p < 8; ++p) {
      const int flat = p * 256 + tid;
      const int kk = flat >> 5, fq = flat & 31;
      *(float4*)(&Ws[kk * HID + fq * 4]) =
          *(const float4*)(W + (size_t)(kt + kk) * HID + fq * 4);
    }
    __syncthreads();
    #pragma unroll
    for (int k0 = 0; k0 < KTT; k0 += 4) {
      float4 af[6];
      #pragma unroll
      for (int r = 0; r < 6; ++r)
        af[r] = *(const float4*)(&As[(ty + 16 * r) * AS_LD + k0]);
      #pragma unroll
      for (int kk = 0; kk < 4; ++kk) {
        const float4 w0 = *(const float4*)(&Ws[(k0 + kk) * HID + tx * 8]);
        const float4 w1 = *(const float4*)(&Ws[(k0 + kk) * HID + tx * 8 + 4]);
        #pragma unroll
        for (int r = 0; r < 6; ++r) {
          const float a = kk == 0 ? af[r].x
                        : kk == 1 ? af[r].y
                        : kk == 2 ? af[r].z : af[r].w;
          acc[r][0] = fmaf(a, w0.x, acc[r][0]);
          acc[r][1] = fmaf(a, w0.y, acc[r][1]);
          acc[r][2] = fmaf(a, w0.z, acc[r][2]);
          acc[r][3] = fmaf(a, w0.w, acc[r][3]);
          acc[r][4] = fmaf(a, w1.x, acc[r][4]);
          acc[r][5] = fmaf(a, w1.y, acc[r][5]);
          acc[r][6] = fmaf(a, w1.z, acc[r][6]);
          acc[r][7] = fmaf(a, w1.w, acc[r][7]);
        }
      }
    }
  }

  // epilogue
  #pragma unroll
  for (int r = 0; r < 6; ++r) {
    const int gm = m0 + ty + 16 * r;
    if (gm < NN) {
      float* op = out + (size_t)gm * HID + tx * 8;
      if (OUT_MODE == 2) {
        float4 o0 = *(const float4*)(op);
        float4 o1 = *(const float4*)(op + 4);
        o0.x += acc[r][0]; o0.y += acc[r][1]; o0.z += acc[r][2]; o0.w += acc[r][3];
        o1.x += acc[r][4]; o1.y += acc[r][5]; o1.z += acc[r][6]; o1.w += acc[r][7];
        *(float4*)(op) = o0;
        *(float4*)(op + 4) = o1;
      } else {
        *(float4*)(op) = make_float4(acc[r][0], acc[r][1], acc[r][2], acc[r][3]);
        *(float4*)(op + 4) = make_float4(acc[r][4], acc[r][5], acc[r][6], acc[r][7]);
      }
    }
  }
  if (OUT_MODE == 0) {
    float cs[8], cq[8];
    #pragma unroll
    for (int c = 0; c < 8; ++c) {
      float s = 0.f, q = 0.f;
      #pragma unroll
      for (int r = 0; r < 6; ++r) {
        s += acc[r][c];
        q = fmaf(acc[r][c], acc[r][c], q);
      }
      cs[c] = s;
      cq[c] = q;
    }
    #pragma unroll
    for (int c = 0; c < 8; ++c) {
      cs[c] += __shfl_xor(cs[c], 16);
      cq[c] += __shfl_xor(cq[c], 16);
      cs[c] += __shfl_xor(cs[c], 32);
      cq[c] += __shfl_xor(cq[c], 32);
    }
    if ((ty & 3) == 0) {
      #pragma unroll
      for (int c = 0; c < 8; ++c) {
        atomicAdd(&stats[tx * 8 + c], cs[c]);
        atomicAdd(&stats[HID + tx * 8 + c], cq[c]);
      }
    }
  }
}

// ---------------- BN finalize: a = g*rsqrt(var+eps), c = b - mean*a ----------------
__global__ __launch_bounds__(128) void k_bnfin(const float* __restrict__ st,
                                               const float* __restrict__ g,
                                               const float* __restrict__ b,
                                               float* __restrict__ a,
                                               float* __restrict__ c) {
  const int t = threadIdx.x;
  const float inv_n = 1.0f / (float)NN;
  const float mean = st[t] * inv_n;
  float var = st[HID + t] * inv_n - mean * mean;
  var = fmaxf(var, 0.f);
  const float rs = rsqrtf(var + BN_EPS);
  const float av = g[t] * rs;
  a[t] = av;
  c[t] = b[t] - mean * av;
}

// ---------------- apply BN2 + ELU in place ----------------
__global__ __launch_bounds__(256) void k_postact(float* __restrict__ u,
                                                 const float* __restrict__ a,
                                                 const float* __restrict__ c) {
  const int total = NN * 32;
  for (int i = blockIdx.x * blockDim.x + threadIdx.x; i < total;
       i += gridDim.x * blockDim.x) {
    const int node = i >> 5, q = i & 31;
    float4 v = *(const float4*)(u + (size_t)node * HID + q * 4);
    const float4 a4 = ((const float4*)a)[q];
    const float4 c4 = ((const float4*)c)[q];
    float z;
    z = fmaf(v.x, a4.x, c4.x); v.x = z > 0.f ? z : expm1f(z);
    z = fmaf(v.y, a4.y, c4.y); v.y = z > 0.f ? z : expm1f(z);
    z = fmaf(v.z, a4.z, c4.z); v.z = z > 0.f ? z : expm1f(z);
    z = fmaf(v.w, a4.w, c4.w); v.w = z > 0.f ? z : expm1f(z);
    *(float4*)(u + (size_t)node * HID + q * 4) = v;
  }
}

// ---------------- readout: out[n] = relu(R[n,:] + rb1) . rW2 + rb2 ----------------
__global__ __launch_bounds__(256) void k_readout(const float* __restrict__ R,
                                                 const float* __restrict__ rb1,
                                                 const float* __restrict__ rW2,
                                                 const float* __restrict__ rb2,
                                                 float* __restrict__ out) {
  const int wid = blockIdx.x * 4 + (threadIdx.x >> 6);
  const int lane = threadIdx.x & 63;
  if (wid >= NN) return;
  const float2 v = *(const float2*)(R + (size_t)wid * HID + lane * 2);
  const float2 b = *(const float2*)(rb1 + lane * 2);
  const float2 w = *(const float2*)(rW2 + lane * 2);
  float p = fmaxf(v.x + b.x, 0.f) * w.x + fmaxf(v.y + b.y, 0.f) * w.y;
  p += __shfl_xor(p, 1);
  p += __shfl_xor(p, 2);
  p += __shfl_xor(p, 4);
  p += __shfl_xor(p, 8);
  p += __shfl_xor(p, 16);
  p += __shfl_xor(p, 32);
  if (lane == 0) out[wid] = p + rb2[0];
}

// ---------------- launcher ----------------
extern "C" void kernel_launch(void* const* d_in, const int* in_sizes, int n_in,
                              void* d_out, int out_size, void* d_ws,
                              size_t ws_size, hipStream_t stream) {
  if (ws_size < WS_NEEDED) return;  // diagnostic guard: clean fail, no fault

  const int* x = (const int*)d_in[0];
  const int* E = (const int*)d_in[1];
  const float* emb = (const float*)d_in[2];
  const float* W1 = (const float*)d_in[3];
  const float* W2 = (const float*)d_in[4];
  const float* bn1g = (const float*)d_in[5];
  const float* bn1b = (const float*)d_in[6];
  const float* bn2g = (const float*)d_in[7];
  const float* bn2b = (const float*)d_in[8];
  const float* rW1 = (const float*)d_in[9];
  const float* rb1 = (const float*)d_in[10];
  const float* rW2 = (const float*)d_in[11];
  const float* rb2 = (const float*)d_in[12];
  float* outp = (float*)d_out;

  char* ws = (char*)d_ws;
  float* P = (float*)(ws + OFF_P);
  float* Q = (float*)(ws + OFF_Q);
  float* R = (float*)(ws + OFF_R);
  int* csr = (int*)(ws + OFF_CSR);
  int* rp = (int*)(ws + OFF_RP);
  int* cnt = (int*)(ws + OFF_CNT);
  int* bs = (int*)(ws + OFF_BS);
  float* stats = (float*)(ws + OFF_ST);
  int* flag = (int*)(ws + OFF_FLG);
  float* ac = (float*)(ws + OFF_AC);

  hipMemsetAsync(ws + OFF_ZZ, 0, ZZ_BYTES, stream);
  k_detect<<<1, 64, 0, stream>>>(E, flag);
  k_embed<<<2048, 256, 0, stream>>>(x, emb, P);
  k_hist<<<2048, 256, 0, stream>>>(E, flag, cnt);
  k_scan1<<<NB_SCAN, 256, 0, stream>>>(cnt, rp, bs);
  k_scan2<<<1, 128, 0, stream>>>(bs);
  k_scan3<<<NB_SCAN, 256, 0, stream>>>(rp, bs, cnt);
  k_scatter<<<2048, 256, 0, stream>>>(E, flag, cnt, csr);

  const int gemm_blocks = (NN + BM - 1) / BM;  // 1042

  // R = h0 @ rW1[0:128,:]
  k_gemm<0, 1><<<gemm_blocks, 256, 0, stream>>>(P, rW1, nullptr, nullptr, R, nullptr);

  float* h = P;
  float* w = Q;
  for (int i = 0; i < 3; ++i) {
    float* s1 = stats + (2 * i) * 256;
    float* s2 = stats + (2 * i + 1) * 256;
    float* a1 = ac + (2 * i) * 256, *c1 = a1 + HID;
    float* a2 = ac + (2 * i + 1) * 256, *c2 = a2 + HID;

    k_agg<<<NN / 4, 256, 0, stream>>>(h, rp, csr, w);
    k_gemm<0, 0><<<gemm_blocks, 256, 0, stream>>>(
        w, W1 + (size_t)i * HID * HID, nullptr, nullptr, w, s1);
    k_bnfin<<<1, 128, 0, stream>>>(s1, bn1g + i * HID, bn1b + i * HID, a1, c1);
    k_gemm<1, 0><<<gemm_blocks, 256, 0, stream>>>(
        w, W2 + (size_t)i * HID * HID, a1, c1, w, s2);
    k_bnfin<<<1, 128, 0, stream>>>(s2, bn2g + i * HID, bn2b + i * HID, a2, c2);
    k_postact<<<2048, 256, 0, stream>>>(w, a2, c2);
    // R += h_{i+1} @ rW1[(i+1)*128 : (i+2)*128, :]
    k_gemm<0, 2><<<gemm_blocks, 256, 0, stream>>>(
        w, rW1 + (size_t)(i + 1) * HID * HID, nullptr, nullptr, R, nullptr);
    // swap ping-pong
    float* t = h; h = w; w = t;
  }

  k_readout<<<NN / 4, 256, 0, stream>>>(R, rb1, rW2, rb2, outp);
}

// Round 3
// 1924.391 us; speedup vs baseline: 3.1367x; 3.1367x over previous
//
#include <hip/hip_runtime.h>
#include <cstdint>
#include <cstddef>

#define NN 100000
#define NE 1600000
#define HID 128
#define BN_EPS 1e-5f
#define NB_SCAN 98  // ceil(100000/1024)
#define BM 96
#define KTT 64
#define AS_LD 68
#define NBLK ((NN + BM - 1) / BM)  // 1042 gemm blocks

// ---------------- workspace layout (bytes) ----------------
static constexpr size_t SZ_NODE = (size_t)NN * HID * 4;            // 51.2 MB
static constexpr size_t OFF_P   = 0;                               // h ping
static constexpr size_t OFF_Q   = SZ_NODE;                         // h pong / work
static constexpr size_t OFF_R   = 2 * SZ_NODE;                     // readout accumulator
static constexpr size_t OFF_CSR = 3 * SZ_NODE;                     // [NE] int32
static constexpr size_t OFF_RP  = OFF_CSR + (size_t)NE * 4;        // [NN+1] int32
static constexpr size_t OFF_ZZ  = ((OFF_RP + (size_t)(NN + 1) * 4 + 255) / 256) * 256;
static constexpr size_t OFF_CNT = OFF_ZZ;                          // [NN] int32
static constexpr size_t OFF_BS  = OFF_CNT + (((size_t)NN * 4 + 255) / 256) * 256;
static constexpr size_t OFF_ST  = OFF_BS + 512;                    // (unused now, kept)
static constexpr size_t OFF_FLG = OFF_ST + 6 * 256 * 4;            // int flag
static constexpr size_t ZZ_END  = ((OFF_FLG + 4 + 255) / 256) * 256;
static constexpr size_t ZZ_BYTES = ZZ_END - OFF_ZZ;
static constexpr size_t OFF_AC  = ZZ_END;                          // 6 x 256 f32
static constexpr size_t WS_NEEDED = OFF_AC + 6 * 256 * 4;          // ~160.8 MB

// edge accessor: f==1 -> data is int64 little-endian, take low word
__device__ __forceinline__ int edge_at(const int* __restrict__ E, int f, int idx) {
  return f ? E[2 * (long long)idx] : E[idx];
}

// ---------------- dtype detection ----------------
__global__ void k_detect(const int* __restrict__ E, int* __restrict__ flag) {
  if (threadIdx.x == 0 && blockIdx.x == 0) {
    int f = 1;
    for (int i = 1; i < 256; i += 2)
      if (E[i] != 0) { f = 0; break; }
    *flag = f;
  }
}

// ---------------- embedding: h[n] = emb[x[n]] ----------------
__global__ __launch_bounds__(256) void k_embed(const int* __restrict__ x,
                                               const float* __restrict__ emb,
                                               float* __restrict__ h) {
  const int total = NN * 32;  // float4s
  for (int i = blockIdx.x * blockDim.x + threadIdx.x; i < total;
       i += gridDim.x * blockDim.x) {
    const int node = i >> 5, q = i & 31;
    const int xv = x[node] & 1;
    const float4 v = ((const float4*)emb)[(xv << 5) + q];
    ((float4*)(h + (size_t)node * HID))[q] = v;
  }
}

// ---------------- CSR build ----------------
__global__ __launch_bounds__(256) void k_hist(const int* __restrict__ E,
                                              const int* __restrict__ flag,
                                              int* __restrict__ cnt) {
  const int f = *flag;
  for (int e = blockIdx.x * blockDim.x + threadIdx.x; e < NE;
       e += gridDim.x * blockDim.x) {
    int d = edge_at(E, f, NE + e);
    d = min(max(d, 0), NN - 1);
    atomicAdd(&cnt[d], 1);
  }
}

__global__ __launch_bounds__(256) void k_scan1(const int* __restrict__ cnt,
                                               int* __restrict__ rp,
                                               int* __restrict__ bs) {
  __shared__ int s[256];
  const int tid = threadIdx.x;
  const int base = blockIdx.x * 1024 + tid * 4;
  int v0 = 0, v1 = 0, v2 = 0, v3 = 0;
  if (base + 0 < NN) v0 = cnt[base + 0];
  if (base + 1 < NN) v1 = cnt[base + 1];
  if (base + 2 < NN) v2 = cnt[base + 2];
  if (base + 3 < NN) v3 = cnt[base + 3];
  const int t0 = v0, t1 = t0 + v1, t2 = t1 + v2, t3 = t2 + v3;
  s[tid] = t3;
  __syncthreads();
  for (int off = 1; off < 256; off <<= 1) {
    int xv = 0;
    if (tid >= off) xv = s[tid - off];
    __syncthreads();
    if (tid >= off) s[tid] += xv;
    __syncthreads();
  }
  const int excl = tid ? s[tid - 1] : 0;
  if (base + 0 < NN) rp[base + 0] = excl;
  if (base + 1 < NN) rp[base + 1] = excl + t0;
  if (base + 2 < NN) rp[base + 2] = excl + t1;
  if (base + 3 < NN) rp[base + 3] = excl + t2;
  if (tid == 255) bs[blockIdx.x] = s[255];
}

__global__ __launch_bounds__(128) void k_scan2(int* __restrict__ bs) {
  __shared__ int s[128];
  const int tid = threadIdx.x;
  s[tid] = (tid < NB_SCAN) ? bs[tid] : 0;
  __syncthreads();
  for (int off = 1; off < 128; off <<= 1) {
    int xv = 0;
    if (tid >= off) xv = s[tid - off];
    __syncthreads();
    if (tid >= off) s[tid] += xv;
    __syncthreads();
  }
  if (tid < NB_SCAN) bs[tid] = tid ? s[tid - 1] : 0;  // exclusive block offsets
}

__global__ __launch_bounds__(256) void k_scan3(int* __restrict__ rp,
                                               const int* __restrict__ bs,
                                               int* __restrict__ cursor) {
  const int off = bs[blockIdx.x];
  const int base = blockIdx.x * 1024 + threadIdx.x * 4;
  #pragma unroll
  for (int j = 0; j < 4; ++j) {
    const int i = base + j;
    if (i < NN) {
      const int v = rp[i] + off;
      rp[i] = v;
      cursor[i] = v;
    }
  }
  if (blockIdx.x == 0 && threadIdx.x == 0) rp[NN] = NE;
}

__global__ __launch_bounds__(256) void k_scatter(const int* __restrict__ E,
                                                 const int* __restrict__ flag,
                                                 int* __restrict__ cursor,
                                                 int* __restrict__ csr) {
  const int f = *flag;
  for (int e = blockIdx.x * blockDim.x + threadIdx.x; e < NE;
       e += gridDim.x * blockDim.x) {
    int s = edge_at(E, f, e);
    int d = edge_at(E, f, NE + e);
    s = min(max(s, 0), NN - 1);
    d = min(max(d, 0), NN - 1);
    const int pos = atomicAdd(&cursor[d], 1);
    if ((unsigned)pos < (unsigned)NE) csr[pos] = s;
  }
}

// ---------------- aggregation: z[n] = h[n] + sum_{src in row n} h[src] ----------------
__global__ __launch_bounds__(256) void k_agg(const float* __restrict__ h,
                                             const int* __restrict__ rp,
                                             const int* __restrict__ csr,
                                             float* __restrict__ z) {
  const int wid = blockIdx.x * 4 + (threadIdx.x >> 6);
  const int lane = threadIdx.x & 63;
  if (wid >= NN) return;
  const int beg = rp[wid], end = rp[wid + 1];
  float2 acc = *(const float2*)(h + (size_t)wid * HID + lane * 2);
  for (int j = beg; j < end; j += 64) {
    const int cnt = min(64, end - j);
    int idx = (lane < cnt) ? csr[j + lane] : 0;
    idx = min(max(idx, 0), NN - 1);
    int k = 0;
    for (; k + 4 <= cnt; k += 4) {
      const int s0 = __shfl(idx, k + 0), s1 = __shfl(idx, k + 1);
      const int s2 = __shfl(idx, k + 2), s3 = __shfl(idx, k + 3);
      const float2 v0 = *(const float2*)(h + (size_t)s0 * HID + lane * 2);
      const float2 v1 = *(const float2*)(h + (size_t)s1 * HID + lane * 2);
      const float2 v2 = *(const float2*)(h + (size_t)s2 * HID + lane * 2);
      const float2 v3 = *(const float2*)(h + (size_t)s3 * HID + lane * 2);
      acc.x += (v0.x + v1.x) + (v2.x + v3.x);
      acc.y += (v0.y + v1.y) + (v2.y + v3.y);
    }
    for (; k < cnt; ++k) {
      const int s = __shfl(idx, k);
      const float2 v = *(const float2*)(h + (size_t)s * HID + lane * 2);
      acc.x += v.x;
      acc.y += v.y;
    }
  }
  *(float2*)(z + (size_t)wid * HID + lane * 2) = acc;
}

// ---------------- fused GEMM: out[n,:] (+)= act(A[n,:]) @ W  (K = HID) ----------------
// IN_ACT: 0 = identity, 1 = relu(A*ina + inc) applied at LDS staging
// OUT_MODE: 0 = store + per-block column partial stats (NO atomics), 1 = store, 2 = accumulate
template <int IN_ACT, int OUT_MODE>
__global__ __launch_bounds__(256, 2) void k_gemm(
    const float* __restrict__ A, const float* __restrict__ W,
    const float* __restrict__ ina, const float* __restrict__ inc,
    float* __restrict__ out, float* __restrict__ part) {
  __shared__ __align__(16) float As[BM * AS_LD];
  __shared__ __align__(16) float Ws[KTT * HID];
  const int tid = threadIdx.x;
  const int tx = tid & 15, ty = tid >> 4;
  const int m0 = blockIdx.x * BM;

  float acc[6][8];
  #pragma unroll
  for (int r = 0; r < 6; ++r)
    #pragma unroll
    for (int c = 0; c < 8; ++c) acc[r][c] = 0.f;

  for (int kt = 0; kt < HID; kt += KTT) {
    if (kt) __syncthreads();
    // stage A tile [BM][KTT]
    #pragma unroll
    for (int p = 0; p < 6; ++p) {
      const int flat = p * 256 + tid;
      const int m = flat >> 4, kq = flat & 15;
      const int gm = m0 + m, gk = kt + kq * 4;
      float4 v = make_float4(0.f, 0.f, 0.f, 0.f);
      if (gm < NN) {
        v = *(const float4*)(A + (size_t)gm * HID + gk);
        if (IN_ACT == 1) {
          const float4 a4 = *(const float4*)(ina + gk);
          const float4 c4 = *(const float4*)(inc + gk);
          v.x = fmaxf(fmaf(v.x, a4.x, c4.x), 0.f);
          v.y = fmaxf(fmaf(v.y, a4.y, c4.y), 0.f);
          v.z = fmaxf(fmaf(v.z, a4.z, c4.z), 0.f);
          v.w = fmaxf(fmaf(v.w, a4.w, c4.w), 0.f);
        }
      }
      *(float4*)(&As[m * AS_LD + kq * 4]) = v;
    }
    // stage W tile [KTT][HID]
    #pragma unroll
    for (int p = 0; p < 8; ++p) {
      const int flat = p * 256 + tid;
      const int kk = flat >> 5, fq = flat & 31;
      *(float4*)(&Ws[kk * HID + fq * 4]) =
          *(const float4*)(W + (size_t)(kt + kk) * HID + fq * 4);
    }
    __syncthreads();
    #pragma unroll
    for (int k0 = 0; k0 < KTT; k0 += 4) {
      float4 af[6];
      #pragma unroll
      for (int r = 0; r < 6; ++r)
        af[r] = *(const float4*)(&As[(ty + 16 * r) * AS_LD + k0]);
      #pragma unroll
      for (int kk = 0; kk < 4; ++kk) {
        const float4 w0 = *(const float4*)(&Ws[(k0 + kk) * HID + tx * 8]);
        const float4 w1 = *(const float4*)(&Ws[(k0 + kk) * HID + tx * 8 + 4]);
        #pragma unroll
        for (int r = 0; r < 6; ++r) {
          const float a = kk == 0 ? af[r].x
                        : kk == 1 ? af[r].y
                        : kk == 2 ? af[r].z : af[r].w;
          acc[r][0] = fmaf(a, w0.x, acc[r][0]);
          acc[r][1] = fmaf(a, w0.y, acc[r][1]);
          acc[r][2] = fmaf(a, w0.z, acc[r][2]);
          acc[r][3] = fmaf(a, w0.w, acc[r][3]);
          acc[r][4] = fmaf(a, w1.x, acc[r][4]);
          acc[r][5] = fmaf(a, w1.y, acc[r][5]);
          acc[r][6] = fmaf(a, w1.z, acc[r][6]);
          acc[r][7] = fmaf(a, w1.w, acc[r][7]);
        }
      }
    }
  }

  // epilogue: stores
  #pragma unroll
  for (int r = 0; r < 6; ++r) {
    const int gm = m0 + ty + 16 * r;
    if (gm < NN) {
      float* op = out + (size_t)gm * HID + tx * 8;
      if (OUT_MODE == 2) {
        float4 o0 = *(const float4*)(op);
        float4 o1 = *(const float4*)(op + 4);
        o0.x += acc[r][0]; o0.y += acc[r][1]; o0.z += acc[r][2]; o0.w += acc[r][3];
        o1.x += acc[r][4]; o1.y += acc[r][5]; o1.z += acc[r][6]; o1.w += acc[r][7];
        *(float4*)(op) = o0;
        *(float4*)(op + 4) = o1;
      } else {
        *(float4*)(op) = make_float4(acc[r][0], acc[r][1], acc[r][2], acc[r][3]);
        *(float4*)(op + 4) = make_float4(acc[r][4], acc[r][5], acc[r][6], acc[r][7]);
      }
    }
  }
  if (OUT_MODE == 0) {
    // per-thread column partials (out-of-range rows staged as zeros -> contribute 0)
    float cs[8], cq[8];
    #pragma unroll
    for (int c = 0; c < 8; ++c) {
      float s = 0.f, q = 0.f;
      #pragma unroll
      for (int r = 0; r < 6; ++r) {
        s += acc[r][c];
        q = fmaf(acc[r][c], acc[r][c], q);
      }
      cs[c] = s;
      cq[c] = q;
    }
    // wave reduce across the 4 ty-groups of each wave
    #pragma unroll
    for (int c = 0; c < 8; ++c) {
      cs[c] += __shfl_xor(cs[c], 16);
      cq[c] += __shfl_xor(cq[c], 16);
      cs[c] += __shfl_xor(cs[c], 32);
      cq[c] += __shfl_xor(cq[c], 32);
    }
    // cross-wave reduce in LDS (reuse As), then ONE coalesced 1KB store per block
    __syncthreads();  // all waves done reading As
    float* red = As;  // [4 waves][256] : 0..127 = sum, 128..255 = sumsq
    const int wv = tid >> 6;
    if ((ty & 3) == 0) {  // 16 lanes per wave hold the wave totals, tx = 0..15
      #pragma unroll
      for (int c = 0; c < 8; ++c) {
        red[wv * 256 + tx * 8 + c] = cs[c];
        red[wv * 256 + 128 + tx * 8 + c] = cq[c];
      }
    }
    __syncthreads();
    part[(size_t)blockIdx.x * 256 + tid] =
        red[tid] + red[256 + tid] + red[512 + tid] + red[768 + tid];
  }
}

// ---------------- reduce partials + BN finalize: a = g*rsqrt(var+eps), c = b - mean*a
__global__ __launch_bounds__(1024) void k_bnred(const float* __restrict__ part,
                                                const float* __restrict__ g,
                                                const float* __restrict__ b,
                                                float* __restrict__ a,
                                                float* __restrict__ c) {
  __shared__ float s[1024];
  const int t = threadIdx.x;
  const int col = t & 255, q = t >> 8;
  float acc = 0.f;
  for (int blk = q; blk < NBLK; blk += 4)
    acc += part[(size_t)blk * 256 + col];
  s[t] = acc;
  __syncthreads();
  if (t < 256) s[t] = s[t] + s[t + 256] + s[t + 512] + s[t + 768];
  __syncthreads();
  if (t < 128) {
    const float inv_n = 1.0f / (float)NN;
    const float mean = s[t] * inv_n;
    float var = s[t + 128] * inv_n - mean * mean;
    var = fmaxf(var, 0.f);
    const float rs = rsqrtf(var + BN_EPS);
    const float av = g[t] * rs;
    a[t] = av;
    c[t] = b[t] - mean * av;
  }
}

// ---------------- apply BN2 + ELU in place ----------------
__global__ __launch_bounds__(256) void k_postact(float* __restrict__ u,
                                                 const float* __restrict__ a,
                                                 const float* __restrict__ c) {
  const int total = NN * 32;
  for (int i = blockIdx.x * blockDim.x + threadIdx.x; i < total;
       i += gridDim.x * blockDim.x) {
    const int node = i >> 5, q = i & 31;
    float4 v = *(const float4*)(u + (size_t)node * HID + q * 4);
    const float4 a4 = ((const float4*)a)[q];
    const float4 c4 = ((const float4*)c)[q];
    float z;
    z = fmaf(v.x, a4.x, c4.x); v.x = z > 0.f ? z : expm1f(z);
    z = fmaf(v.y, a4.y, c4.y); v.y = z > 0.f ? z : expm1f(z);
    z = fmaf(v.z, a4.z, c4.z); v.z = z > 0.f ? z : expm1f(z);
    z = fmaf(v.w, a4.w, c4.w); v.w = z > 0.f ? z : expm1f(z);
    *(float4*)(u + (size_t)node * HID + q * 4) = v;
  }
}

// ---------------- readout: out[n] = relu(R[n,:] + rb1) . rW2 + rb2 ----------------
__global__ __launch_bounds__(256) void k_readout(const float* __restrict__ R,
                                                 const float* __restrict__ rb1,
                                                 const float* __restrict__ rW2,
                                                 const float* __restrict__ rb2,
                                                 float* __restrict__ out) {
  const int wid = blockIdx.x * 4 + (threadIdx.x >> 6);
  const int lane = threadIdx.x & 63;
  if (wid >= NN) return;
  const float2 v = *(const float2*)(R + (size_t)wid * HID + lane * 2);
  const float2 b = *(const float2*)(rb1 + lane * 2);
  const float2 w = *(const float2*)(rW2 + lane * 2);
  float p = fmaxf(v.x + b.x, 0.f) * w.x + fmaxf(v.y + b.y, 0.f) * w.y;
  p += __shfl_xor(p, 1);
  p += __shfl_xor(p, 2);
  p += __shfl_xor(p, 4);
  p += __shfl_xor(p, 8);
  p += __shfl_xor(p, 16);
  p += __shfl_xor(p, 32);
  if (lane == 0) out[wid] = p + rb2[0];
}

// ---------------- launcher ----------------
extern "C" void kernel_launch(void* const* d_in, const int* in_sizes, int n_in,
                              void* d_out, int out_size, void* d_ws,
                              size_t ws_size, hipStream_t stream) {
  if (ws_size < WS_NEEDED) return;  // diagnostic guard: clean fail, no fault

  const int* x = (const int*)d_in[0];
  const int* E = (const int*)d_in[1];
  const float* emb = (const float*)d_in[2];
  const float* W1 = (const float*)d_in[3];
  const float* W2 = (const float*)d_in[4];
  const float* bn1g = (const float*)d_in[5];
  const float* bn1b = (const float*)d_in[6];
  const float* bn2g = (const float*)d_in[7];
  const float* bn2b = (const float*)d_in[8];
  const float* rW1 = (const float*)d_in[9];
  const float* rb1 = (const float*)d_in[10];
  const float* rW2 = (const float*)d_in[11];
  const float* rb2 = (const float*)d_in[12];
  float* outp = (float*)d_out;

  char* ws = (char*)d_ws;
  float* P = (float*)(ws + OFF_P);
  float* Q = (float*)(ws + OFF_Q);
  float* R = (float*)(ws + OFF_R);
  int* csr = (int*)(ws + OFF_CSR);
  int* rp = (int*)(ws + OFF_RP);
  int* cnt = (int*)(ws + OFF_CNT);
  int* bs = (int*)(ws + OFF_BS);
  int* flag = (int*)(ws + OFF_FLG);
  float* ac = (float*)(ws + OFF_AC);

  hipMemsetAsync(ws + OFF_ZZ, 0, ZZ_BYTES, stream);
  k_detect<<<1, 64, 0, stream>>>(E, flag);
  k_embed<<<2048, 256, 0, stream>>>(x, emb, P);
  k_hist<<<2048, 256, 0, stream>>>(E, flag, cnt);
  k_scan1<<<NB_SCAN, 256, 0, stream>>>(cnt, rp, bs);
  k_scan2<<<1, 128, 0, stream>>>(bs);
  k_scan3<<<NB_SCAN, 256, 0, stream>>>(rp, bs, cnt);
  k_scatter<<<2048, 256, 0, stream>>>(E, flag, cnt, csr);

  // R = h0 @ rW1[0:128,:]   (P still live here)
  k_gemm<0, 1><<<NBLK, 256, 0, stream>>>(P, rW1, nullptr, nullptr, R, nullptr);

  float* h = P;
  float* w = Q;
  for (int i = 0; i < 3; ++i) {
    float* a1 = ac + (2 * i) * 256, *c1 = a1 + HID;
    float* a2 = ac + (2 * i + 1) * 256, *c2 = a2 + HID;

    k_agg<<<NN / 4, 256, 0, stream>>>(h, rp, csr, w);
    // `h` is dead from here until the swap -> reuse it as the stats partials buffer
    float* part = h;
    k_gemm<0, 0><<<NBLK, 256, 0, stream>>>(
        w, W1 + (size_t)i * HID * HID, nullptr, nullptr, w, part);
    k_bnred<<<1, 1024, 0, stream>>>(part, bn1g + i * HID, bn1b + i * HID, a1, c1);
    k_gemm<1, 0><<<NBLK, 256, 0, stream>>>(
        w, W2 + (size_t)i * HID * HID, a1, c1, w, part);
    k_bnred<<<1, 1024, 0, stream>>>(part, bn2g + i * HID, bn2b + i * HID, a2, c2);
    k_postact<<<2048, 256, 0, stream>>>(w, a2, c2);
    // R += h_{i+1} @ rW1[(i+1)*128 : (i+2)*128, :]
    k_gemm<0, 2><<<NBLK, 256, 0, stream>>>(
        w, rW1 + (size_t)(i + 1) * HID * HID, nullptr, nullptr, R, nullptr);
    // swap ping-pong (old h's partials junk is fully overwritten by next k_agg)
    float* t = h; h = w; w = t;
  }

  k_readout<<<NN / 4, 256, 0, stream>>>(R, rb1, rW2, rb2, outp);
}

// Round 4
// 1356.541 us; speedup vs baseline: 4.4497x; 1.4186x over previous
//
#include <hip/hip_runtime.h>
#include <cstdint>
#include <cstddef>

#define NN 100000
#define NE 1600000
#define HID 128
#define BN_EPS 1e-5f
#define NB_SCAN 98  // ceil(100000/1024)
#define BM 96
#define NBLK ((NN + BM - 1) / BM)  // 1042 gemm blocks
#define SA 72   // LDS stride (bf16 elems): 144B row = 16B-aligned, 36 dw = 4 mod 32 bank rotation

typedef __attribute__((ext_vector_type(8))) short bf16x8;
typedef __attribute__((ext_vector_type(4))) float f32x4;
typedef __attribute__((ext_vector_type(4))) unsigned short u16x4;

// ---------------- workspace layout (bytes) ----------------
static constexpr size_t SZ_NODE = (size_t)NN * HID * 4;            // 51.2 MB
static constexpr size_t OFF_P   = 0;                               // h ping
static constexpr size_t OFF_Q   = SZ_NODE;                         // h pong / work
static constexpr size_t OFF_R   = 2 * SZ_NODE;                     // readout accumulator
static constexpr size_t OFF_CSR = 3 * SZ_NODE;                     // [NE] int32
static constexpr size_t OFF_RP  = OFF_CSR + (size_t)NE * 4;        // [NN+1] int32
static constexpr size_t OFF_ZZ  = ((OFF_RP + (size_t)(NN + 1) * 4 + 255) / 256) * 256;
static constexpr size_t OFF_CNT = OFF_ZZ;                          // [NN] int32
static constexpr size_t OFF_BS  = OFF_CNT + (((size_t)NN * 4 + 255) / 256) * 256;
static constexpr size_t OFF_ST  = OFF_BS + 512;                    // (unused, kept)
static constexpr size_t OFF_FLG = OFF_ST + 6 * 256 * 4;            // int flag
static constexpr size_t ZZ_END  = ((OFF_FLG + 4 + 255) / 256) * 256;
static constexpr size_t ZZ_BYTES = ZZ_END - OFF_ZZ;
static constexpr size_t OFF_AC  = ZZ_END;                          // 6 x 256 f32
static constexpr size_t WS_NEEDED = OFF_AC + 6 * 256 * 4;          // ~160.8 MB

// ---------------- bf16 helpers (RTNE) ----------------
__device__ __forceinline__ unsigned short f2bf(float f) {
  unsigned u = __float_as_uint(f);
  unsigned r = (u + 0x7fffu + ((u >> 16) & 1u)) >> 16;
  return (unsigned short)r;
}
__device__ __forceinline__ float bf2f(unsigned short b) {
  return __uint_as_float(((unsigned)b) << 16);
}

// edge accessor: f==1 -> data is int64 little-endian, take low word
__device__ __forceinline__ int edge_at(const int* __restrict__ E, int f, int idx) {
  return f ? E[2 * (long long)idx] : E[idx];
}

// ---------------- dtype detection ----------------
__global__ void k_detect(const int* __restrict__ E, int* __restrict__ flag) {
  if (threadIdx.x == 0 && blockIdx.x == 0) {
    int f = 1;
    for (int i = 1; i < 256; i += 2)
      if (E[i] != 0) { f = 0; break; }
    *flag = f;
  }
}

// ---------------- embedding: h[n] = emb[x[n]] ----------------
__global__ __launch_bounds__(256) void k_embed(const int* __restrict__ x,
                                               const float* __restrict__ emb,
                                               float* __restrict__ h) {
  const int total = NN * 32;  // float4s
  for (int i = blockIdx.x * blockDim.x + threadIdx.x; i < total;
       i += gridDim.x * blockDim.x) {
    const int node = i >> 5, q = i & 31;
    const int xv = x[node] & 1;
    const float4 v = ((const float4*)emb)[(xv << 5) + q];
    ((float4*)(h + (size_t)node * HID))[q] = v;
  }
}

// ---------------- CSR build ----------------
__global__ __launch_bounds__(256) void k_hist(const int* __restrict__ E,
                                              const int* __restrict__ flag,
                                              int* __restrict__ cnt) {
  const int f = *flag;
  for (int e = blockIdx.x * blockDim.x + threadIdx.x; e < NE;
       e += gridDim.x * blockDim.x) {
    int d = edge_at(E, f, NE + e);
    d = min(max(d, 0), NN - 1);
    atomicAdd(&cnt[d], 1);
  }
}

__global__ __launch_bounds__(256) void k_scan1(const int* __restrict__ cnt,
                                               int* __restrict__ rp,
                                               int* __restrict__ bs) {
  __shared__ int s[256];
  const int tid = threadIdx.x;
  const int base = blockIdx.x * 1024 + tid * 4;
  int v0 = 0, v1 = 0, v2 = 0, v3 = 0;
  if (base + 0 < NN) v0 = cnt[base + 0];
  if (base + 1 < NN) v1 = cnt[base + 1];
  if (base + 2 < NN) v2 = cnt[base + 2];
  if (base + 3 < NN) v3 = cnt[base + 3];
  const int t0 = v0, t1 = t0 + v1, t2 = t1 + v2, t3 = t2 + v3;
  s[tid] = t3;
  __syncthreads();
  for (int off = 1; off < 256; off <<= 1) {
    int xv = 0;
    if (tid >= off) xv = s[tid - off];
    __syncthreads();
    if (tid >= off) s[tid] += xv;
    __syncthreads();
  }
  const int excl = tid ? s[tid - 1] : 0;
  if (base + 0 < NN) rp[base + 0] = excl;
  if (base + 1 < NN) rp[base + 1] = excl + t0;
  if (base + 2 < NN) rp[base + 2] = excl + t1;
  if (base + 3 < NN) rp[base + 3] = excl + t2;
  if (tid == 255) bs[blockIdx.x] = s[255];
}

__global__ __launch_bounds__(128) void k_scan2(int* __restrict__ bs) {
  __shared__ int s[128];
  const int tid = threadIdx.x;
  s[tid] = (tid < NB_SCAN) ? bs[tid] : 0;
  __syncthreads();
  for (int off = 1; off < 128; off <<= 1) {
    int xv = 0;
    if (tid >= off) xv = s[tid - off];
    __syncthreads();
    if (tid >= off) s[tid] += xv;
    __syncthreads();
  }
  if (tid < NB_SCAN) bs[tid] = tid ? s[tid - 1] : 0;  // exclusive block offsets
}

__global__ __launch_bounds__(256) void k_scan3(int* __restrict__ rp,
                                               const int* __restrict__ bs,
                                               int* __restrict__ cursor) {
  const int off = bs[blockIdx.x];
  const int base = blockIdx.x * 1024 + threadIdx.x * 4;
  #pragma unroll
  for (int j = 0; j < 4; ++j) {
    const int i = base + j;
    if (i < NN) {
      const int v = rp[i] + off;
      rp[i] = v;
      cursor[i] = v;
    }
  }
  if (blockIdx.x == 0 && threadIdx.x == 0) rp[NN] = NE;
}

__global__ __launch_bounds__(256) void k_scatter(const int* __restrict__ E,
                                                 const int* __restrict__ flag,
                                                 int* __restrict__ cursor,
                                                 int* __restrict__ csr) {
  const int f = *flag;
  for (int e = blockIdx.x * blockDim.x + threadIdx.x; e < NE;
       e += gridDim.x * blockDim.x) {
    int s = edge_at(E, f, e);
    int d = edge_at(E, f, NE + e);
    s = min(max(s, 0), NN - 1);
    d = min(max(d, 0), NN - 1);
    const int pos = atomicAdd(&cursor[d], 1);
    if ((unsigned)pos < (unsigned)NE) csr[pos] = s;
  }
}

// ---------------- aggregation: z[n] = h[n] + sum_{src in row n} h[src] ----------------
__global__ __launch_bounds__(256) void k_agg(const float* __restrict__ h,
                                             const int* __restrict__ rp,
                                             const int* __restrict__ csr,
                                             float* __restrict__ z) {
  const int wid = blockIdx.x * 4 + (threadIdx.x >> 6);
  const int lane = threadIdx.x & 63;
  if (wid >= NN) return;
  const int beg = rp[wid], end = rp[wid + 1];
  float2 acc = *(const float2*)(h + (size_t)wid * HID + lane * 2);
  for (int j = beg; j < end; j += 64) {
    const int cnt = min(64, end - j);
    int idx = (lane < cnt) ? csr[j + lane] : 0;
    idx = min(max(idx, 0), NN - 1);
    int k = 0;
    for (; k + 4 <= cnt; k += 4) {
      const int s0 = __shfl(idx, k + 0), s1 = __shfl(idx, k + 1);
      const int s2 = __shfl(idx, k + 2), s3 = __shfl(idx, k + 3);
      const float2 v0 = *(const float2*)(h + (size_t)s0 * HID + lane * 2);
      const float2 v1 = *(const float2*)(h + (size_t)s1 * HID + lane * 2);
      const float2 v2 = *(const float2*)(h + (size_t)s2 * HID + lane * 2);
      const float2 v3 = *(const float2*)(h + (size_t)s3 * HID + lane * 2);
      acc.x += (v0.x + v1.x) + (v2.x + v3.x);
      acc.y += (v0.y + v1.y) + (v2.y + v3.y);
    }
    for (; k < cnt; ++k) {
      const int s = __shfl(idx, k);
      const float2 v = *(const float2*)(h + (size_t)s * HID + lane * 2);
      acc.x += v.x;
      acc.y += v.y;
    }
  }
  *(float2*)(z + (size_t)wid * HID + lane * 2) = acc;
}

// ---------------- split-bf16 MFMA GEMM: out[n,:] (+)= act(A[n,:]) @ W ----------------
// a = ah+al, w = wh+wl (bf16 + bf16 residual); z = ah*wh + ah*wl + al*wh  (err ~2^-17)
// Tile: BM=96 x N=128, K-tile 64. 4 waves, each 96 rows x 32 cols (6 M-frag x 2 N-frag).
// Fragment pattern == learn_hip m92-verified: row/col = lane&15, k = kc + (lane>>4)*8 + j.
// IN_ACT: 0 identity, 1 relu(a*ina+inc) at staging
// OUT_MODE: 0 store + per-block column stats (no atomics), 1 store, 2 accumulate
template <int IN_ACT, int OUT_MODE>
__global__ __launch_bounds__(256, 2) void k_gemm(
    const float* __restrict__ A, const float* __restrict__ Wg,
    const float* __restrict__ ina, const float* __restrict__ inc,
    float* __restrict__ out, float* __restrict__ part) {
  __shared__ short Ah[BM * SA];     // 13824 B
  __shared__ short Al[BM * SA];     // 13824 B
  __shared__ short Wh[HID * SA];    // 18432 B
  __shared__ short Wl[HID * SA];    // 18432 B  -> total 64512 B
  const int tid = threadIdx.x;
  const int lane = tid & 63, wv = tid >> 6;
  const int tq = lane >> 4, tl = lane & 15;
  const int wc = wv * 32;           // wave's column base
  const int m0 = blockIdx.x * BM;

  f32x4 acc[6][2];
  #pragma unroll
  for (int i = 0; i < 6; ++i)
    #pragma unroll
    for (int j = 0; j < 2; ++j) acc[i][j] = (f32x4)(0.f);

  for (int kt = 0; kt < HID; kt += 64) {
    if (kt) __syncthreads();
    // ---- stage A[96][kt:kt+64] -> Ah/Al (hi/lo bf16) ----
    #pragma unroll
    for (int p = 0; p < 6; ++p) {
      const int flat = p * 256 + tid;      // 1536 = 96 rows * 16 quads
      const int m = flat >> 4, kq = flat & 15;
      const int gm = m0 + m, gk = kt + kq * 4;
      float vv[4] = {0.f, 0.f, 0.f, 0.f};
      if (gm < NN) {
        const float4 v = *(const float4*)(A + (size_t)gm * HID + gk);
        vv[0] = v.x; vv[1] = v.y; vv[2] = v.z; vv[3] = v.w;
        if (IN_ACT == 1) {
          const float4 a4 = *(const float4*)(ina + gk);
          const float4 c4 = *(const float4*)(inc + gk);
          vv[0] = fmaxf(fmaf(vv[0], a4.x, c4.x), 0.f);
          vv[1] = fmaxf(fmaf(vv[1], a4.y, c4.y), 0.f);
          vv[2] = fmaxf(fmaf(vv[2], a4.z, c4.z), 0.f);
          vv[3] = fmaxf(fmaf(vv[3], a4.w, c4.w), 0.f);
        }
      }
      u16x4 hh, ll;
      #pragma unroll
      for (int j = 0; j < 4; ++j) {
        const unsigned short hb = f2bf(vv[j]);
        hh[j] = hb;
        ll[j] = f2bf(vv[j] - bf2f(hb));
      }
      *(u16x4*)(&Ah[m * SA + kq * 4]) = hh;
      *(u16x4*)(&Al[m * SA + kq * 4]) = ll;
    }
    // ---- stage W[kt:kt+64][0:128] -> Wh/Wl transposed [n][k] ----
    #pragma unroll
    for (int p = 0; p < 8; ++p) {
      const int flat = p * 256 + tid;      // 2048 = 64 k * 32 quads
      const int k = flat >> 5, n4 = flat & 31;
      const float4 v = *(const float4*)(Wg + (size_t)(kt + k) * HID + n4 * 4);
      const float vv[4] = {v.x, v.y, v.z, v.w};
      #pragma unroll
      for (int j = 0; j < 4; ++j) {
        const unsigned short hb = f2bf(vv[j]);
        Wh[(n4 * 4 + j) * SA + k] = (short)hb;
        Wl[(n4 * 4 + j) * SA + k] = (short)f2bf(vv[j] - bf2f(hb));
      }
    }
    __syncthreads();
    // ---- MFMA over this K-tile ----
    #pragma unroll
    for (int kc = 0; kc < 64; kc += 32) {
      const int ko = kc + tq * 8;
      bf16x8 wh[2], wl[2];
      #pragma unroll
      for (int fn = 0; fn < 2; ++fn) {
        const int c = (wc + fn * 16 + tl) * SA + ko;
        wh[fn] = *(const bf16x8*)(&Wh[c]);
        wl[fn] = *(const bf16x8*)(&Wl[c]);
      }
      #pragma unroll
      for (int fm = 0; fm < 6; ++fm) {
        const int r = (fm * 16 + tl) * SA + ko;
        const bf16x8 ah = *(const bf16x8*)(&Ah[r]);
        const bf16x8 al = *(const bf16x8*)(&Al[r]);
        #pragma unroll
        for (int fn = 0; fn < 2; ++fn) {
          acc[fm][fn] = __builtin_amdgcn_mfma_f32_16x16x32_bf16(ah, wh[fn], acc[fm][fn], 0, 0, 0);
          acc[fm][fn] = __builtin_amdgcn_mfma_f32_16x16x32_bf16(ah, wl[fn], acc[fm][fn], 0, 0, 0);
          acc[fm][fn] = __builtin_amdgcn_mfma_f32_16x16x32_bf16(al, wh[fn], acc[fm][fn], 0, 0, 0);
        }
      }
    }
  }

  // ---- epilogue: C/D layout col=lane&15, row=(lane>>4)*4+reg (m89-verified) ----
  #pragma unroll
  for (int fm = 0; fm < 6; ++fm) {
    #pragma unroll
    for (int reg = 0; reg < 4; ++reg) {
      const int row = m0 + fm * 16 + tq * 4 + reg;
      if (row < NN) {
        float* op = out + (size_t)row * HID + wc + tl;
        #pragma unroll
        for (int fn = 0; fn < 2; ++fn) {
          if (OUT_MODE == 2)
            op[fn * 16] += acc[fm][fn][reg];
          else
            op[fn * 16] = acc[fm][fn][reg];
        }
      }
    }
  }
  if (OUT_MODE == 0) {
    // column partials: each wave owns disjoint cols -> no LDS needed
    #pragma unroll
    for (int fn = 0; fn < 2; ++fn) {
      float s = 0.f, q = 0.f;
      #pragma unroll
      for (int fm = 0; fm < 6; ++fm)
        #pragma unroll
        for (int reg = 0; reg < 4; ++reg) {
          const float v = acc[fm][fn][reg];
          s += v;
          q = fmaf(v, v, q);
        }
      s += __shfl_xor(s, 16); q += __shfl_xor(q, 16);
      s += __shfl_xor(s, 32); q += __shfl_xor(q, 32);
      if (lane < 16) {
        const int col = wc + fn * 16 + lane;
        part[(size_t)blockIdx.x * 256 + col] = s;
        part[(size_t)blockIdx.x * 256 + 128 + col] = q;
      }
    }
  }
}

// ---------------- 2-stage stats reduce + BN finalize ----------------
__global__ __launch_bounds__(256) void k_bnred1(const float* __restrict__ part,
                                                float* __restrict__ part2) {
  const int tid = threadIdx.x, b = blockIdx.x;
  float acc = 0.f;
  for (int r = b; r < NBLK; r += 64) acc += part[(size_t)r * 256 + tid];
  part2[(size_t)b * 256 + tid] = acc;
}

__global__ __launch_bounds__(256) void k_bnred2(const float* __restrict__ part2,
                                                const float* __restrict__ g,
                                                const float* __restrict__ b,
                                                float* __restrict__ a,
                                                float* __restrict__ c) {
  __shared__ float s[256];
  const int t = threadIdx.x;
  float acc = 0.f;
  for (int r = 0; r < 64; ++r) acc += part2[(size_t)r * 256 + t];
  s[t] = acc;
  __syncthreads();
  if (t < 128) {
    const float inv_n = 1.0f / (float)NN;
    const float mean = s[t] * inv_n;
    float var = s[t + 128] * inv_n - mean * mean;
    var = fmaxf(var, 0.f);
    const float rs = rsqrtf(var + BN_EPS);
    const float av = g[t] * rs;
    a[t] = av;
    c[t] = b[t] - mean * av;
  }
}

// ---------------- apply BN2 + ELU in place ----------------
__global__ __launch_bounds__(256) void k_postact(float* __restrict__ u,
                                                 const float* __restrict__ a,
                                                 const float* __restrict__ c) {
  const int total = NN * 32;
  for (int i = blockIdx.x * blockDim.x + threadIdx.x; i < total;
       i += gridDim.x * blockDim.x) {
    const int node = i >> 5, q = i & 31;
    float4 v = *(const float4*)(u + (size_t)node * HID + q * 4);
    const float4 a4 = ((const float4*)a)[q];
    const float4 c4 = ((const float4*)c)[q];
    float z;
    z = fmaf(v.x, a4.x, c4.x); v.x = z > 0.f ? z : expm1f(z);
    z = fmaf(v.y, a4.y, c4.y); v.y = z > 0.f ? z : expm1f(z);
    z = fmaf(v.z, a4.z, c4.z); v.z = z > 0.f ? z : expm1f(z);
    z = fmaf(v.w, a4.w, c4.w); v.w = z > 0.f ? z : expm1f(z);
    *(float4*)(u + (size_t)node * HID + q * 4) = v;
  }
}

// ---------------- readout: out[n] = relu(R[n,:] + rb1) . rW2 + rb2 ----------------
__global__ __launch_bounds__(256) void k_readout(const float* __restrict__ R,
                                                 const float* __restrict__ rb1,
                                                 const float* __restrict__ rW2,
                                                 const float* __restrict__ rb2,
                                                 float* __restrict__ out) {
  const int wid = blockIdx.x * 4 + (threadIdx.x >> 6);
  const int lane = threadIdx.x & 63;
  if (wid >= NN) return;
  const float2 v = *(const float2*)(R + (size_t)wid * HID + lane * 2);
  const float2 b = *(const float2*)(rb1 + lane * 2);
  const float2 w = *(const float2*)(rW2 + lane * 2);
  float p = fmaxf(v.x + b.x, 0.f) * w.x + fmaxf(v.y + b.y, 0.f) * w.y;
  p += __shfl_xor(p, 1);
  p += __shfl_xor(p, 2);
  p += __shfl_xor(p, 4);
  p += __shfl_xor(p, 8);
  p += __shfl_xor(p, 16);
  p += __shfl_xor(p, 32);
  if (lane == 0) out[wid] = p + rb2[0];
}

// ---------------- launcher ----------------
extern "C" void kernel_launch(void* const* d_in, const int* in_sizes, int n_in,
                              void* d_out, int out_size, void* d_ws,
                              size_t ws_size, hipStream_t stream) {
  if (ws_size < WS_NEEDED) return;  // diagnostic guard: clean fail, no fault

  const int* x = (const int*)d_in[0];
  const int* E = (const int*)d_in[1];
  const float* emb = (const float*)d_in[2];
  const float* W1 = (const float*)d_in[3];
  const float* W2 = (const float*)d_in[4];
  const float* bn1g = (const float*)d_in[5];
  const float* bn1b = (const float*)d_in[6];
  const float* bn2g = (const float*)d_in[7];
  const float* bn2b = (const float*)d_in[8];
  const float* rW1 = (const float*)d_in[9];
  const float* rb1 = (const float*)d_in[10];
  const float* rW2 = (const float*)d_in[11];
  const float* rb2 = (const float*)d_in[12];
  float* outp = (float*)d_out;

  char* ws = (char*)d_ws;
  float* P = (float*)(ws + OFF_P);
  float* Q = (float*)(ws + OFF_Q);
  float* R = (float*)(ws + OFF_R);
  int* csr = (int*)(ws + OFF_CSR);
  int* rp = (int*)(ws + OFF_RP);
  int* cnt = (int*)(ws + OFF_CNT);
  int* bs = (int*)(ws + OFF_BS);
  int* flag = (int*)(ws + OFF_FLG);
  float* ac = (float*)(ws + OFF_AC);

  hipMemsetAsync(ws + OFF_ZZ, 0, ZZ_BYTES, stream);
  k_detect<<<1, 64, 0, stream>>>(E, flag);
  k_embed<<<2048, 256, 0, stream>>>(x, emb, P);
  k_hist<<<2048, 256, 0, stream>>>(E, flag, cnt);
  k_scan1<<<NB_SCAN, 256, 0, stream>>>(cnt, rp, bs);
  k_scan2<<<1, 128, 0, stream>>>(bs);
  k_scan3<<<NB_SCAN, 256, 0, stream>>>(rp, bs, cnt);
  k_scatter<<<2048, 256, 0, stream>>>(E, flag, cnt, csr);

  // R = h0 @ rW1[0:128,:]   (P still live here)
  k_gemm<0, 1><<<NBLK, 256, 0, stream>>>(P, rW1, nullptr, nullptr, R, nullptr);

  float* h = P;
  float* w = Q;
  for (int i = 0; i < 3; ++i) {
    float* a1 = ac + (2 * i) * 256, *c1 = a1 + HID;
    float* a2 = ac + (2 * i + 1) * 256, *c2 = a2 + HID;

    k_agg<<<NN / 4, 256, 0, stream>>>(h, rp, csr, w);
    // `h` is dead from here until the swap -> reuse as stats partial buffers
    float* part = h;
    float* part2 = h + (size_t)NBLK * 256;
    k_gemm<0, 0><<<NBLK, 256, 0, stream>>>(
        w, W1 + (size_t)i * HID * HID, nullptr, nullptr, w, part);
    k_bnred1<<<64, 256, 0, stream>>>(part, part2);
    k_bnred2<<<1, 256, 0, stream>>>(part2, bn1g + i * HID, bn1b + i * HID, a1, c1);
    k_gemm<1, 0><<<NBLK, 256, 0, stream>>>(
        w, W2 + (size_t)i * HID * HID, a1, c1, w, part);
    k_bnred1<<<64, 256, 0, stream>>>(part, part2);
    k_bnred2<<<1, 256, 0, stream>>>(part2, bn2g + i * HID, bn2b + i * HID, a2, c2);
    k_postact<<<2048, 256, 0, stream>>>(w, a2, c2);
    // R += h_{i+1} @ rW1[(i+1)*128 : (i+2)*128, :]
    k_gemm<0, 2><<<NBLK, 256, 0, stream>>>(
        w, rW1 + (size_t)(i + 1) * HID * HID, nullptr, nullptr, R, nullptr);
    // swap ping-pong (old h's partials junk is fully overwritten by next k_agg)
    float* t = h; h = w; w = t;
  }

  k_readout<<<NN / 4, 256, 0, stream>>>(R, rb1, rW2, rb2, outp);
}

// Round 5
// 1137.728 us; speedup vs baseline: 5.3055x; 1.1923x over previous
//
#include <hip/hip_runtime.h>
#include <cstdint>
#include <cstddef>

#define NN 100000
#define NE 1600000
#define HID 128
#define BN_EPS 1e-5f
#define NB_SCAN 98  // ceil(100000/1024)
#define BM 96
#define NBLK ((NN + BM - 1) / BM)   // 1042 gemm blocks
#define NBC  ((NN + 255) / 256)     // 391 count blocks
#define SA 72   // LDS stride (bf16 elems): 144B row = 16B-aligned, bank rotation 4

typedef __attribute__((ext_vector_type(8))) short bf16x8;
typedef __attribute__((ext_vector_type(4))) float f32x4;
typedef __attribute__((ext_vector_type(4))) unsigned short u16x4;

// ---------------- workspace layout (bytes) ----------------
static constexpr size_t SZ_NODE = (size_t)NN * HID * 4;            // 51.2 MB
static constexpr size_t OFF_P   = 0;                               // ping (scratch L1, z/v L2+)
static constexpr size_t OFF_Q   = SZ_NODE;                         // pong (u1/h1 L1, ...)
static constexpr size_t OFF_R   = 2 * SZ_NODE;                     // readout accumulator
static constexpr size_t OFF_CSR = 3 * SZ_NODE;                     // [NE] int32
static constexpr size_t OFF_RP  = OFF_CSR + (size_t)NE * 4;        // [NN+1] int32
static constexpr size_t OFF_ZZ  = ((OFF_RP + (size_t)(NN + 1) * 4 + 255) / 256) * 256;
static constexpr size_t OFF_CNT = OFF_ZZ;                          // [NN] int32
static constexpr size_t OFF_BS  = OFF_CNT + (((size_t)NN * 4 + 255) / 256) * 256;
static constexpr size_t OFF_FLG = OFF_BS + 512;                    // int flag
static constexpr size_t ZZ_END  = ((OFF_FLG + 4 + 255) / 256) * 256;
static constexpr size_t ZZ_BYTES = ZZ_END - OFF_ZZ;
static constexpr size_t OFF_AC  = ZZ_END;                          // 6 x 256 f32 (bn a/c)
static constexpr size_t OFF_E   = OFF_AC + 6 * 256 * 4;            // ee: e0,e1,r0,r1 = 512 f32
static constexpr size_t WS_NEEDED = OFF_E + 512 * 4;               // ~160.8 MB

// ---------------- bf16 helpers (RTNE) ----------------
__device__ __forceinline__ unsigned short f2bf(float f) {
  unsigned u = __float_as_uint(f);
  unsigned r = (u + 0x7fffu + ((u >> 16) & 1u)) >> 16;
  return (unsigned short)r;
}
__device__ __forceinline__ float bf2f(unsigned short b) {
  return __uint_as_float(((unsigned)b) << 16);
}

// edge accessor: f==1 -> data is int64 little-endian, take low word
__device__ __forceinline__ int edge_at(const int* __restrict__ E, int f, int idx) {
  return f ? E[2 * (long long)idx] : E[idx];
}

// ---------------- dtype detection ----------------
__global__ void k_detect(const int* __restrict__ E, int* __restrict__ flag) {
  if (threadIdx.x == 0 && blockIdx.x == 0) {
    int f = 1;
    for (int i = 1; i < 256; i += 2)
      if (E[i] != 0) { f = 0; break; }
    *flag = f;
  }
}

// ---------------- CSR build ----------------
__global__ __launch_bounds__(256) void k_hist(const int* __restrict__ E,
                                              const int* __restrict__ flag,
                                              int* __restrict__ cnt) {
  const int f = *flag;
  for (int e = blockIdx.x * blockDim.x + threadIdx.x; e < NE;
       e += gridDim.x * blockDim.x) {
    int d = edge_at(E, f, NE + e);
    d = min(max(d, 0), NN - 1);
    atomicAdd(&cnt[d], 1);
  }
}

__global__ __launch_bounds__(256) void k_scan1(const int* __restrict__ cnt,
                                               int* __restrict__ rp,
                                               int* __restrict__ bs) {
  __shared__ int s[256];
  const int tid = threadIdx.x;
  const int base = blockIdx.x * 1024 + tid * 4;
  int v0 = 0, v1 = 0, v2 = 0, v3 = 0;
  if (base + 0 < NN) v0 = cnt[base + 0];
  if (base + 1 < NN) v1 = cnt[base + 1];
  if (base + 2 < NN) v2 = cnt[base + 2];
  if (base + 3 < NN) v3 = cnt[base + 3];
  const int t0 = v0, t1 = t0 + v1, t2 = t1 + v2, t3 = t2 + v3;
  s[tid] = t3;
  __syncthreads();
  for (int off = 1; off < 256; off <<= 1) {
    int xv = 0;
    if (tid >= off) xv = s[tid - off];
    __syncthreads();
    if (tid >= off) s[tid] += xv;
    __syncthreads();
  }
  const int excl = tid ? s[tid - 1] : 0;
  if (base + 0 < NN) rp[base + 0] = excl;
  if (base + 1 < NN) rp[base + 1] = excl + t0;
  if (base + 2 < NN) rp[base + 2] = excl + t1;
  if (base + 3 < NN) rp[base + 3] = excl + t2;
  if (tid == 255) bs[blockIdx.x] = s[255];
}

__global__ __launch_bounds__(128) void k_scan2(int* __restrict__ bs) {
  __shared__ int s[128];
  const int tid = threadIdx.x;
  s[tid] = (tid < NB_SCAN) ? bs[tid] : 0;
  __syncthreads();
  for (int off = 1; off < 128; off <<= 1) {
    int xv = 0;
    if (tid >= off) xv = s[tid - off];
    __syncthreads();
    if (tid >= off) s[tid] += xv;
    __syncthreads();
  }
  if (tid < NB_SCAN) bs[tid] = tid ? s[tid - 1] : 0;  // exclusive block offsets
}

__global__ __launch_bounds__(256) void k_scan3(int* __restrict__ rp,
                                               const int* __restrict__ bs,
                                               int* __restrict__ cursor) {
  const int off = bs[blockIdx.x];
  const int base = blockIdx.x * 1024 + threadIdx.x * 4;
  #pragma unroll
  for (int j = 0; j < 4; ++j) {
    const int i = base + j;
    if (i < NN) {
      const int v = rp[i] + off;
      rp[i] = v;
      cursor[i] = v;
    }
  }
  if (blockIdx.x == 0 && threadIdx.x == 0) rp[NN] = NE;
}

__global__ __launch_bounds__(256) void k_scatter(const int* __restrict__ E,
                                                 const int* __restrict__ flag,
                                                 int* __restrict__ cursor,
                                                 int* __restrict__ csr) {
  const int f = *flag;
  for (int e = blockIdx.x * blockDim.x + threadIdx.x; e < NE;
       e += gridDim.x * blockDim.x) {
    int s = edge_at(E, f, e);
    int d = edge_at(E, f, NE + e);
    s = min(max(s, 0), NN - 1);
    d = min(max(d, 0), NN - 1);
    const int pos = atomicAdd(&cursor[d], 1);
    if ((unsigned)pos < (unsigned)NE) csr[pos] = s;
  }
}

// ---------------- layer-1 rank-2 shortcut ----------------
// e0 = emb0@W1_0, e1 = emb1@W1_0, r0 = emb0@rW1[0:128], r1 = emb1@rW1[0:128]
__global__ __launch_bounds__(256) void k_prep(const float* __restrict__ emb,
                                              const float* __restrict__ W1,
                                              const float* __restrict__ rW1,
                                              float* __restrict__ ee) {
  const int t = threadIdx.x;
  const int f = t & 127;
  const float* er = emb + (t >> 7) * HID;  // emb0 or emb1
  float se = 0.f, sr = 0.f;
  for (int k = 0; k < HID; ++k) {
    const float ev = er[k];
    se = fmaf(ev, W1[k * HID + f], se);
    sr = fmaf(ev, rW1[k * HID + f], sr);
  }
  ee[t] = se;        // [0:128]=e0, [128:256]=e1
  ee[256 + t] = sr;  // [256:384]=r0, [384:512]=r1
}

// per-node class counts a0,a1 + block partial moments (S0,S1,S00,S11,S01)
__global__ __launch_bounds__(256) void k_cnt(const int* __restrict__ x,
                                             const int* __restrict__ rp,
                                             const int* __restrict__ csr,
                                             int* __restrict__ a01,
                                             float* __restrict__ momp) {
  const int n = blockIdx.x * 256 + threadIdx.x;
  float m[5] = {0.f, 0.f, 0.f, 0.f, 0.f};
  if (n < NN) {
    const int beg = rp[n], end = rp[n + 1];
    int c1 = 0;
    for (int j = beg; j < end; ++j) c1 += x[csr[j]] & 1;
    const int a1 = c1 + (x[n] & 1);
    const int a0 = (end - beg + 1) - a1;
    a01[n] = a0 | (a1 << 16);
    m[0] = (float)a0;
    m[1] = (float)a1;
    m[2] = (float)a0 * (float)a0;
    m[3] = (float)a1 * (float)a1;
    m[4] = (float)a0 * (float)a1;
  }
  #pragma unroll
  for (int j = 0; j < 5; ++j)
    #pragma unroll
    for (int off = 1; off < 64; off <<= 1) m[j] += __shfl_xor(m[j], off);
  __shared__ float sm[5][4];
  const int lane = threadIdx.x & 63, wv = threadIdx.x >> 6;
  if (lane == 0)
    #pragma unroll
    for (int j = 0; j < 5; ++j) sm[j][wv] = m[j];
  __syncthreads();
  if (threadIdx.x == 0)
    #pragma unroll
    for (int j = 0; j < 5; ++j)
      momp[j * NBC + blockIdx.x] = sm[j][0] + sm[j][1] + sm[j][2] + sm[j][3];
}

// bn1 (layer 1) a/c from moments: mean/var of u1 = a0*e0 + a1*e1 per column
__global__ __launch_bounds__(128) void k_bnmom(const float* __restrict__ momp,
                                               const float* __restrict__ ee,
                                               const float* __restrict__ g,
                                               const float* __restrict__ b,
                                               float* __restrict__ a,
                                               float* __restrict__ c) {
  __shared__ float red[5][128];
  const int t = threadIdx.x;
  float s[5] = {0.f, 0.f, 0.f, 0.f, 0.f};
  for (int i = t; i < NBC; i += 128)
    #pragma unroll
    for (int j = 0; j < 5; ++j) s[j] += momp[j * NBC + i];
  #pragma unroll
  for (int j = 0; j < 5; ++j) red[j][t] = s[j];
  __syncthreads();
  for (int off = 64; off; off >>= 1) {
    if (t < off)
      #pragma unroll
      for (int j = 0; j < 5; ++j) red[j][t] += red[j][t + off];
    __syncthreads();
  }
  const float S0 = red[0][0], S1 = red[1][0];
  const float S00 = red[2][0], S11 = red[3][0], S01 = red[4][0];
  const float inv_n = 1.0f / (float)NN;
  const float e0 = ee[t], e1 = ee[128 + t];
  const float mean = (S0 * e0 + S1 * e1) * inv_n;
  const float msq = (S00 * e0 * e0 + 2.f * S01 * e0 * e1 + S11 * e1 * e1) * inv_n;
  float var = fmaxf(msq - mean * mean, 0.f);
  const float rs = rsqrtf(var + BN_EPS);
  const float av = g[t] * rs;
  a[t] = av;
  c[t] = b[t] - mean * av;
}

// u1[n] = a0*e0 + a1*e1 ; R[n] = x[n] ? r1 : r0
__global__ __launch_bounds__(256) void k_l1expand(const int* __restrict__ x,
                                                  const int* __restrict__ a01,
                                                  const float* __restrict__ ee,
                                                  float* __restrict__ u1,
                                                  float* __restrict__ R) {
  const int total = NN * 32;
  for (int i = blockIdx.x * blockDim.x + threadIdx.x; i < total;
       i += gridDim.x * blockDim.x) {
    const int node = i >> 5, q = i & 31;
    const int p = a01[node];
    const float a0 = (float)(p & 0xffff), a1 = (float)(p >> 16);
    const float4 e0q = ((const float4*)ee)[q];
    const float4 e1q = ((const float4*)ee)[32 + q];
    float4 u;
    u.x = a0 * e0q.x + a1 * e1q.x;
    u.y = a0 * e0q.y + a1 * e1q.y;
    u.z = a0 * e0q.z + a1 * e1q.z;
    u.w = a0 * e0q.w + a1 * e1q.w;
    ((float4*)(u1 + (size_t)node * HID))[q] = u;
    const float4 rq = (x[node] & 1) ? ((const float4*)ee)[96 + q]
                                    : ((const float4*)ee)[64 + q];
    ((float4*)(R + (size_t)node * HID))[q] = rq;
  }
}

// ---------------- aggregation: z[n] = h[n] + sum_{src in row n} h[src] ----------------
__global__ __launch_bounds__(256) void k_agg(const float* __restrict__ h,
                                             const int* __restrict__ rp,
                                             const int* __restrict__ csr,
                                             float* __restrict__ z) {
  const int wid = blockIdx.x * 4 + (threadIdx.x >> 6);
  const int lane = threadIdx.x & 63;
  if (wid >= NN) return;
  const int beg = rp[wid], end = rp[wid + 1];
  float2 acc = *(const float2*)(h + (size_t)wid * HID + lane * 2);
  for (int j = beg; j < end; j += 64) {
    const int cnt = min(64, end - j);
    int idx = (lane < cnt) ? csr[j + lane] : 0;
    idx = min(max(idx, 0), NN - 1);
    int k = 0;
    for (; k + 4 <= cnt; k += 4) {
      const int s0 = __shfl(idx, k + 0), s1 = __shfl(idx, k + 1);
      const int s2 = __shfl(idx, k + 2), s3 = __shfl(idx, k + 3);
      const float2 v0 = *(const float2*)(h + (size_t)s0 * HID + lane * 2);
      const float2 v1 = *(const float2*)(h + (size_t)s1 * HID + lane * 2);
      const float2 v2 = *(const float2*)(h + (size_t)s2 * HID + lane * 2);
      const float2 v3 = *(const float2*)(h + (size_t)s3 * HID + lane * 2);
      acc.x += (v0.x + v1.x) + (v2.x + v3.x);
      acc.y += (v0.y + v1.y) + (v2.y + v3.y);
    }
    for (; k < cnt; ++k) {
      const int s = __shfl(idx, k);
      const float2 v = *(const float2*)(h + (size_t)s * HID + lane * 2);
      acc.x += v.x;
      acc.y += v.y;
    }
  }
  *(float2*)(z + (size_t)wid * HID + lane * 2) = acc;
}

// ---------------- split-bf16 MFMA GEMM: out[n,:] (+)= act(A[n,:]) @ W ----------------
// a = ah+al, w = wh+wl (bf16 + bf16 residual); z = ah*wh + ah*wl + al*wh
// IN_ACT: 0 identity, 1 relu(a*ina+inc), 2 elu(a*ina+inc)+WRITE-BACK to A, 3 elu (no wb)
// OUT_MODE: 0 store + per-block column stats, 2 accumulate (+=)
template <int IN_ACT, int OUT_MODE>
__global__ __launch_bounds__(256, 2) void k_gemm(
    float* A, const float* __restrict__ Wg,
    const float* __restrict__ ina, const float* __restrict__ inc,
    float* __restrict__ out, float* __restrict__ part) {
  __shared__ short Ah[BM * SA];
  __shared__ short Al[BM * SA];
  __shared__ short Wh[HID * SA];
  __shared__ short Wl[HID * SA];
  const int tid = threadIdx.x;
  const int lane = tid & 63, wv = tid >> 6;
  const int tq = lane >> 4, tl = lane & 15;
  const int wc = wv * 32;  // wave's column base
  const int m0 = blockIdx.x * BM;

  f32x4 acc[6][2];
  #pragma unroll
  for (int i = 0; i < 6; ++i)
    #pragma unroll
    for (int j = 0; j < 2; ++j) acc[i][j] = (f32x4)(0.f);

  for (int kt = 0; kt < HID; kt += 64) {
    if (kt) __syncthreads();
    // ---- stage A[96][kt:kt+64] -> Ah/Al, optional activation (+write-back) ----
    #pragma unroll
    for (int p = 0; p < 6; ++p) {
      const int flat = p * 256 + tid;  // 1536 = 96 rows * 16 quads
      const int m = flat >> 4, kq = flat & 15;
      const int gm = m0 + m, gk = kt + kq * 4;
      float vv[4] = {0.f, 0.f, 0.f, 0.f};
      if (gm < NN) {
        const float4 v = *(const float4*)(A + (size_t)gm * HID + gk);
        vv[0] = v.x; vv[1] = v.y; vv[2] = v.z; vv[3] = v.w;
        if (IN_ACT >= 1) {
          const float4 a4 = *(const float4*)(ina + gk);
          const float4 c4 = *(const float4*)(inc + gk);
          const float aa[4] = {a4.x, a4.y, a4.z, a4.w};
          const float cc[4] = {c4.x, c4.y, c4.z, c4.w};
          #pragma unroll
          for (int j = 0; j < 4; ++j) {
            float z = fmaf(vv[j], aa[j], cc[j]);
            if (IN_ACT == 1) vv[j] = fmaxf(z, 0.f);
            else vv[j] = z > 0.f ? z : expm1f(z);
          }
        }
        if (IN_ACT == 2)
          *(float4*)(A + (size_t)gm * HID + gk) =
              make_float4(vv[0], vv[1], vv[2], vv[3]);
      }
      u16x4 hh, ll;
      #pragma unroll
      for (int j = 0; j < 4; ++j) {
        const unsigned short hb = f2bf(vv[j]);
        hh[j] = hb;
        ll[j] = f2bf(vv[j] - bf2f(hb));
      }
      *(u16x4*)(&Ah[m * SA + kq * 4]) = hh;
      *(u16x4*)(&Al[m * SA + kq * 4]) = ll;
    }
    // ---- stage W[kt:kt+64][0:128] -> Wh/Wl transposed [n][k] ----
    #pragma unroll
    for (int p = 0; p < 8; ++p) {
      const int flat = p * 256 + tid;
      const int k = flat >> 5, n4 = flat & 31;
      const float4 v = *(const float4*)(Wg + (size_t)(kt + k) * HID + n4 * 4);
      const float vv[4] = {v.x, v.y, v.z, v.w};
      #pragma unroll
      for (int j = 0; j < 4; ++j) {
        const unsigned short hb = f2bf(vv[j]);
        Wh[(n4 * 4 + j) * SA + k] = (short)hb;
        Wl[(n4 * 4 + j) * SA + k] = (short)f2bf(vv[j] - bf2f(hb));
      }
    }
    __syncthreads();
    // ---- MFMA over this K-tile ----
    #pragma unroll
    for (int kc = 0; kc < 64; kc += 32) {
      const int ko = kc + tq * 8;
      bf16x8 wh[2], wl[2];
      #pragma unroll
      for (int fn = 0; fn < 2; ++fn) {
        const int c = (wc + fn * 16 + tl) * SA + ko;
        wh[fn] = *(const bf16x8*)(&Wh[c]);
        wl[fn] = *(const bf16x8*)(&Wl[c]);
      }
      #pragma unroll
      for (int fm = 0; fm < 6; ++fm) {
        const int r = (fm * 16 + tl) * SA + ko;
        const bf16x8 ah = *(const bf16x8*)(&Ah[r]);
        const bf16x8 al = *(const bf16x8*)(&Al[r]);
        #pragma unroll
        for (int fn = 0; fn < 2; ++fn) {
          acc[fm][fn] = __builtin_amdgcn_mfma_f32_16x16x32_bf16(ah, wh[fn], acc[fm][fn], 0, 0, 0);
          acc[fm][fn] = __builtin_amdgcn_mfma_f32_16x16x32_bf16(ah, wl[fn], acc[fm][fn], 0, 0, 0);
          acc[fm][fn] = __builtin_amdgcn_mfma_f32_16x16x32_bf16(al, wh[fn], acc[fm][fn], 0, 0, 0);
        }
      }
    }
  }

  // ---- epilogue: C/D layout col=lane&15, row=(lane>>4)*4+reg (m89-verified) ----
  #pragma unroll
  for (int fm = 0; fm < 6; ++fm) {
    #pragma unroll
    for (int reg = 0; reg < 4; ++reg) {
      const int row = m0 + fm * 16 + tq * 4 + reg;
      if (row < NN) {
        float* op = out + (size_t)row * HID + wc + tl;
        #pragma unroll
        for (int fn = 0; fn < 2; ++fn) {
          if (OUT_MODE == 2)
            op[fn * 16] += acc[fm][fn][reg];
          else
            op[fn * 16] = acc[fm][fn][reg];
        }
      }
    }
  }
  if (OUT_MODE == 0) {
    #pragma unroll
    for (int fn = 0; fn < 2; ++fn) {
      float s = 0.f, q = 0.f;
      #pragma unroll
      for (int fm = 0; fm < 6; ++fm)
        #pragma unroll
        for (int reg = 0; reg < 4; ++reg) {
          const float v = acc[fm][fn][reg];
          s += v;
          q = fmaf(v, v, q);
        }
      s += __shfl_xor(s, 16); q += __shfl_xor(q, 16);
      s += __shfl_xor(s, 32); q += __shfl_xor(q, 32);
      if (lane < 16) {
        const int col = wc + fn * 16 + lane;
        part[(size_t)blockIdx.x * 256 + col] = s;
        part[(size_t)blockIdx.x * 256 + 128 + col] = q;
      }
    }
  }
}

// ---------------- 2-stage stats reduce + BN finalize ----------------
__global__ __launch_bounds__(256) void k_bnred1(const float* __restrict__ part,
                                                float* __restrict__ part2) {
  const int tid = threadIdx.x, b = blockIdx.x;
  float acc = 0.f;
  for (int r = b; r < NBLK; r += 64) acc += part[(size_t)r * 256 + tid];
  part2[(size_t)b * 256 + tid] = acc;
}

__global__ __launch_bounds__(256) void k_bnred2(const float* __restrict__ part2,
                                                const float* __restrict__ g,
                                                const float* __restrict__ b,
                                                float* __restrict__ a,
                                                float* __restrict__ c) {
  __shared__ float s[256];
  const int t = threadIdx.x;
  float acc = 0.f;
  for (int r = 0; r < 64; ++r) acc += part2[(size_t)r * 256 + t];
  s[t] = acc;
  __syncthreads();
  if (t < 128) {
    const float inv_n = 1.0f / (float)NN;
    const float mean = s[t] * inv_n;
    float var = s[t + 128] * inv_n - mean * mean;
    var = fmaxf(var, 0.f);
    const float rs = rsqrtf(var + BN_EPS);
    const float av = g[t] * rs;
    a[t] = av;
    c[t] = b[t] - mean * av;
  }
}

// ---------------- readout: out[n] = relu(R[n,:] + rb1) . rW2 + rb2 ----------------
__global__ __launch_bounds__(256) void k_readout(const float* __restrict__ R,
                                                 const float* __restrict__ rb1,
                                                 const float* __restrict__ rW2,
                                                 const float* __restrict__ rb2,
                                                 float* __restrict__ out) {
  const int wid = blockIdx.x * 4 + (threadIdx.x >> 6);
  const int lane = threadIdx.x & 63;
  if (wid >= NN) return;
  const float2 v = *(const float2*)(R + (size_t)wid * HID + lane * 2);
  const float2 b = *(const float2*)(rb1 + lane * 2);
  const float2 w = *(const float2*)(rW2 + lane * 2);
  float p = fmaxf(v.x + b.x, 0.f) * w.x + fmaxf(v.y + b.y, 0.f) * w.y;
  p += __shfl_xor(p, 1);
  p += __shfl_xor(p, 2);
  p += __shfl_xor(p, 4);
  p += __shfl_xor(p, 8);
  p += __shfl_xor(p, 16);
  p += __shfl_xor(p, 32);
  if (lane == 0) out[wid] = p + rb2[0];
}

// ---------------- launcher ----------------
extern "C" void kernel_launch(void* const* d_in, const int* in_sizes, int n_in,
                              void* d_out, int out_size, void* d_ws,
                              size_t ws_size, hipStream_t stream) {
  if (ws_size < WS_NEEDED) return;  // diagnostic guard: clean fail, no fault

  const int* x = (const int*)d_in[0];
  const int* E = (const int*)d_in[1];
  const float* emb = (const float*)d_in[2];
  const float* W1 = (const float*)d_in[3];
  const float* W2 = (const float*)d_in[4];
  const float* bn1g = (const float*)d_in[5];
  const float* bn1b = (const float*)d_in[6];
  const float* bn2g = (const float*)d_in[7];
  const float* bn2b = (const float*)d_in[8];
  const float* rW1 = (const float*)d_in[9];
  const float* rb1 = (const float*)d_in[10];
  const float* rW2 = (const float*)d_in[11];
  const float* rb2 = (const float*)d_in[12];
  float* outp = (float*)d_out;

  char* ws = (char*)d_ws;
  float* P = (float*)(ws + OFF_P);
  float* Q = (float*)(ws + OFF_Q);
  float* R = (float*)(ws + OFF_R);
  int* csr = (int*)(ws + OFF_CSR);
  int* rp = (int*)(ws + OFF_RP);
  int* cnt = (int*)(ws + OFF_CNT);
  int* bs = (int*)(ws + OFF_BS);
  int* flag = (int*)(ws + OFF_FLG);
  float* ac = (float*)(ws + OFF_AC);
  float* ee = (float*)(ws + OFF_E);
  // layer-1 scratch inside P (dead until layer-1 stats): part at +0, a01 at +4MB, momp at +8MB
  int* a01 = (int*)((char*)P + (4 << 20));
  float* momp = (float*)((char*)P + (8 << 20));

  hipMemsetAsync(ws + OFF_ZZ, 0, ZZ_BYTES, stream);
  k_detect<<<1, 64, 0, stream>>>(E, flag);
  k_hist<<<2048, 256, 0, stream>>>(E, flag, cnt);
  k_scan1<<<NB_SCAN, 256, 0, stream>>>(cnt, rp, bs);
  k_scan2<<<1, 128, 0, stream>>>(bs);
  k_scan3<<<NB_SCAN, 256, 0, stream>>>(rp, bs, cnt);
  k_scatter<<<2048, 256, 0, stream>>>(E, flag, cnt, csr);
  k_prep<<<1, 256, 0, stream>>>(emb, W1, rW1, ee);

  float* a1 = ac + 0 * 256, *c1 = a1 + HID;
  float* a2 = ac + 1 * 256, *c2 = a2 + HID;

  // ---- layer 1 via rank-2 shortcut ----
  k_cnt<<<NBC, 256, 0, stream>>>(x, rp, csr, a01, momp);
  k_bnmom<<<1, 128, 0, stream>>>(momp, ee, bn1g, bn1b, a1, c1);
  k_l1expand<<<2048, 256, 0, stream>>>(x, a01, ee, Q, R);  // u1 -> Q, R init
  k_gemm<1, 0><<<NBLK, 256, 0, stream>>>(Q, W2, a1, c1, Q, P);       // v1 -> Q
  k_bnred1<<<64, 256, 0, stream>>>(P, P + (size_t)NBLK * 256);
  k_bnred2<<<1, 256, 0, stream>>>(P + (size_t)NBLK * 256, bn2g, bn2b, a2, c2);
  // R += elu(bn2(v1)) @ rW1[128:256]; h1 written back into Q
  k_gemm<2, 2><<<NBLK, 256, 0, stream>>>(Q, rW1 + (size_t)HID * HID, a2, c2, R, nullptr);

  // ---- layers 2,3 ----
  float* h = Q;
  float* w = P;
  for (int i = 1; i < 3; ++i) {
    float* b1a = ac + (2 * i) * 256, *b1c = b1a + HID;
    float* b2a = ac + (2 * i + 1) * 256, *b2c = b2a + HID;
    k_agg<<<NN / 4, 256, 0, stream>>>(h, rp, csr, w);
    float* part = h;                                  // h dead after agg
    float* part2 = h + (size_t)NBLK * 256;
    k_gemm<0, 0><<<NBLK, 256, 0, stream>>>(
        w, W1 + (size_t)i * HID * HID, nullptr, nullptr, w, part);
    k_bnred1<<<64, 256, 0, stream>>>(part, part2);
    k_bnred2<<<1, 256, 0, stream>>>(part2, bn1g + i * HID, bn1b + i * HID, b1a, b1c);
    k_gemm<1, 0><<<NBLK, 256, 0, stream>>>(
        w, W2 + (size_t)i * HID * HID, b1a, b1c, w, part);
    k_bnred1<<<64, 256, 0, stream>>>(part, part2);
    k_bnred2<<<1, 256, 0, stream>>>(part2, bn2g + i * HID, bn2b + i * HID, b2a, b2c);
    if (i < 2) {
      // R += h2 @ rW1 slice, h2 written back in place (needed by next agg)
      k_gemm<2, 2><<<NBLK, 256, 0, stream>>>(
          w, rW1 + (size_t)(i + 1) * HID * HID, b2a, b2c, R, nullptr);
    } else {
      // last layer: h3 only feeds R -> no write-back
      k_gemm<3, 2><<<NBLK, 256, 0, stream>>>(
          w, rW1 + (size_t)(i + 1) * HID * HID, b2a, b2c, R, nullptr);
    }
    float* t = h; h = w; w = t;
  }

  k_readout<<<NN / 4, 256, 0, stream>>>(R, rb1, rW2, rb2, outp);
}

// Round 6
// 919.090 us; speedup vs baseline: 6.5675x; 1.2379x over previous
//
#include <hip/hip_runtime.h>
#include <cstdint>
#include <cstddef>

#define NN 100000
#define NE 1600000
#define HID 128
#define BN_EPS 1e-5f
#define NB_SCAN 98  // ceil(100000/1024)
#define BM 96
#define NBLK ((NN + BM - 1) / BM)   // 1042 gemm blocks
#define NBC  ((NN + 255) / 256)     // 391 count blocks
#define SA 72   // LDS stride (bf16 elems): 144B row = 16B-aligned, bank rotation 4
#define SC_CHUNKS 256
#define SC_RANGE (NN / 8)           // 12500 (exact)
#define SC_EPC (NE / SC_CHUNKS)     // 6250 edges per chunk (exact)

typedef __attribute__((ext_vector_type(8))) short bf16x8;
typedef __attribute__((ext_vector_type(4))) float f32x4;
typedef __attribute__((ext_vector_type(4))) unsigned short u16x4;

// ---------------- workspace layout (bytes) ----------------
static constexpr size_t SZ_NODE = (size_t)NN * HID * 4;            // 51.2 MB
static constexpr size_t OFF_P   = 0;                               // ping
static constexpr size_t OFF_Q   = SZ_NODE;                         // pong
static constexpr size_t OFF_R   = 2 * SZ_NODE;                     // readout accumulator
static constexpr size_t OFF_CSR = 3 * SZ_NODE;                     // [NE] int32
static constexpr size_t OFF_RP  = OFF_CSR + (size_t)NE * 4;        // [NN+1] int32
static constexpr size_t OFF_ZZ  = ((OFF_RP + (size_t)(NN + 1) * 4 + 255) / 256) * 256;
static constexpr size_t OFF_CNT = OFF_ZZ;                          // [NN] int32
static constexpr size_t OFF_BS  = OFF_CNT + (((size_t)NN * 4 + 255) / 256) * 256;
static constexpr size_t OFF_FLG = OFF_BS + 512;                    // int flag
static constexpr size_t OFF_SS  = OFF_FLG + 256;                   // 5 x 256 f32 atomic sums
static constexpr size_t OFF_SCT = OFF_SS + 5 * 256 * 4;            // 5 int counters
static constexpr size_t ZZ_END  = ((OFF_SCT + 5 * 4 + 255) / 256) * 256;
static constexpr size_t ZZ_BYTES = ZZ_END - OFF_ZZ;
static constexpr size_t OFF_AC  = ZZ_END;                          // 6 x 256 f32 (bn a/c)
static constexpr size_t OFF_E   = OFF_AC + 6 * 256 * 4;            // ee: 512 f32
static constexpr size_t OFF_WSP = OFF_E + 512 * 4;                 // 8 mats x [2][128][128] shorts
static constexpr size_t WS_NEEDED = OFF_WSP + (size_t)8 * 2 * HID * HID * 2;

// ---------------- bf16 helpers (RTNE) ----------------
__device__ __forceinline__ unsigned short f2bf(float f) {
  unsigned u = __float_as_uint(f);
  unsigned r = (u + 0x7fffu + ((u >> 16) & 1u)) >> 16;
  return (unsigned short)r;
}
__device__ __forceinline__ float bf2f(unsigned short b) {
  return __uint_as_float(((unsigned)b) << 16);
}

// edge accessor: f==1 -> data is int64 little-endian, take low word
__device__ __forceinline__ int edge_at(const int* __restrict__ E, int f, int idx) {
  return f ? E[2 * (long long)idx] : E[idx];
}

// ---------------- dtype detection ----------------
__global__ void k_detect(const int* __restrict__ E, int* __restrict__ flag) {
  if (threadIdx.x == 0 && blockIdx.x == 0) {
    int f = 1;
    for (int i = 1; i < 256; i += 2)
      if (E[i] != 0) { f = 0; break; }
    *flag = f;
  }
}

// ---------------- CSR build ----------------
__global__ __launch_bounds__(256) void k_hist(const int* __restrict__ E,
                                              const int* __restrict__ flag,
                                              int* __restrict__ cnt) {
  const int f = *flag;
  for (int e = blockIdx.x * blockDim.x + threadIdx.x; e < NE;
       e += gridDim.x * blockDim.x) {
    int d = edge_at(E, f, NE + e);
    d = min(max(d, 0), NN - 1);
    atomicAdd(&cnt[d], 1);
  }
}

__global__ __launch_bounds__(256) void k_scan1(const int* __restrict__ cnt,
                                               int* __restrict__ rp,
                                               int* __restrict__ bs) {
  __shared__ int s[256];
  const int tid = threadIdx.x;
  const int base = blockIdx.x * 1024 + tid * 4;
  int v0 = 0, v1 = 0, v2 = 0, v3 = 0;
  if (base + 0 < NN) v0 = cnt[base + 0];
  if (base + 1 < NN) v1 = cnt[base + 1];
  if (base + 2 < NN) v2 = cnt[base + 2];
  if (base + 3 < NN) v3 = cnt[base + 3];
  const int t0 = v0, t1 = t0 + v1, t2 = t1 + v2, t3 = t2 + v3;
  s[tid] = t3;
  __syncthreads();
  for (int off = 1; off < 256; off <<= 1) {
    int xv = 0;
    if (tid >= off) xv = s[tid - off];
    __syncthreads();
    if (tid >= off) s[tid] += xv;
    __syncthreads();
  }
  const int excl = tid ? s[tid - 1] : 0;
  if (base + 0 < NN) rp[base + 0] = excl;
  if (base + 1 < NN) rp[base + 1] = excl + t0;
  if (base + 2 < NN) rp[base + 2] = excl + t1;
  if (base + 3 < NN) rp[base + 3] = excl + t2;
  if (tid == 255) bs[blockIdx.x] = s[255];
}

__global__ __launch_bounds__(128) void k_scan2(int* __restrict__ bs) {
  __shared__ int s[128];
  const int tid = threadIdx.x;
  s[tid] = (tid < NB_SCAN) ? bs[tid] : 0;
  __syncthreads();
  for (int off = 1; off < 128; off <<= 1) {
    int xv = 0;
    if (tid >= off) xv = s[tid - off];
    __syncthreads();
    if (tid >= off) s[tid] += xv;
    __syncthreads();
  }
  if (tid < NB_SCAN) bs[tid] = tid ? s[tid - 1] : 0;  // exclusive block offsets
}

__global__ __launch_bounds__(256) void k_scan3(int* __restrict__ rp,
                                               const int* __restrict__ bs,
                                               int* __restrict__ cursor) {
  const int off = bs[blockIdx.x];
  const int base = blockIdx.x * 1024 + threadIdx.x * 4;
  #pragma unroll
  for (int j = 0; j < 4; ++j) {
    const int i = base + j;
    if (i < NN) {
      const int v = rp[i] + off;
      rp[i] = v;
      cursor[i] = v;
    }
  }
  if (blockIdx.x == 0 && threadIdx.x == 0) rp[NN] = NE;
}

// XCD-bucketed scatter: blocks with same (blockIdx&7) handle one dst-range and
// (by round-robin dispatch) sit on one XCD -> csr lines fill within one L2.
__global__ __launch_bounds__(256) void k_scatter(const int* __restrict__ E,
                                                 const int* __restrict__ flag,
                                                 int* __restrict__ cursor,
                                                 int* __restrict__ csr) {
  const int f = *flag;
  const int r = blockIdx.x & 7;
  const int chunk = blockIdx.x >> 3;           // 0..255
  const int lo = r * SC_RANGE, hi = lo + SC_RANGE;
  const int ebeg = chunk * SC_EPC, eend = ebeg + SC_EPC;
  for (int e = ebeg + threadIdx.x; e < eend; e += 256) {
    int d = edge_at(E, f, NE + e);
    d = min(max(d, 0), NN - 1);
    if (d >= lo && d < hi) {
      int s = edge_at(E, f, e);
      s = min(max(s, 0), NN - 1);
      const int pos = atomicAdd(&cursor[d], 1);
      if ((unsigned)pos < (unsigned)NE) csr[pos] = s;
    }
  }
}

// ---------------- weight pre-split: W[k][n] fp32 -> [n][k] bf16 hi/lo ----------------
__global__ __launch_bounds__(256) void k_prepw(const float* __restrict__ W1,
                                               const float* __restrict__ W2,
                                               const float* __restrict__ rW1,
                                               short* __restrict__ wsp) {
  const int g = blockIdx.x * 256 + threadIdx.x;  // 8*16384 total
  const int m = g >> 14, idx = g & 16383;
  const int k = idx >> 7, n = idx & 127;
  const float* src;
  switch (m) {
    case 0: src = W2; break;
    case 1: src = rW1 + 1 * HID * HID; break;
    case 2: src = W1 + 1 * HID * HID; break;
    case 3: src = W2 + 1 * HID * HID; break;
    case 4: src = rW1 + 2 * HID * HID; break;
    case 5: src = W1 + 2 * HID * HID; break;
    case 6: src = W2 + 2 * HID * HID; break;
    default: src = rW1 + 3 * HID * HID; break;
  }
  const float v = src[k * HID + n];
  const unsigned short hb = f2bf(v);
  short* dst = wsp + (size_t)m * 32768;
  dst[n * HID + k] = (short)hb;
  dst[16384 + n * HID + k] = (short)f2bf(v - bf2f(hb));
}

// ---------------- layer-1 rank-2 shortcut ----------------
__global__ __launch_bounds__(256) void k_prep(const float* __restrict__ emb,
                                              const float* __restrict__ W1,
                                              const float* __restrict__ rW1,
                                              float* __restrict__ ee) {
  const int t = threadIdx.x;
  const int f = t & 127;
  const float* er = emb + (t >> 7) * HID;  // emb0 or emb1
  float se = 0.f, sr = 0.f;
  for (int k = 0; k < HID; ++k) {
    const float ev = er[k];
    se = fmaf(ev, W1[k * HID + f], se);
    sr = fmaf(ev, rW1[k * HID + f], sr);
  }
  ee[t] = se;        // [0:128]=e0, [128:256]=e1
  ee[256 + t] = sr;  // [256:384]=r0, [384:512]=r1
}

// per-node class counts a0,a1 + block partial moments (S0,S1,S00,S11,S01)
__global__ __launch_bounds__(256) void k_cnt(const int* __restrict__ x,
                                             const int* __restrict__ rp,
                                             const int* __restrict__ csr,
                                             int* __restrict__ a01,
                                             float* __restrict__ momp) {
  const int n = blockIdx.x * 256 + threadIdx.x;
  float m[5] = {0.f, 0.f, 0.f, 0.f, 0.f};
  if (n < NN) {
    const int beg = rp[n], end = rp[n + 1];
    int c1 = 0;
    for (int j = beg; j < end; ++j) c1 += x[csr[j]] & 1;
    const int a1 = c1 + (x[n] & 1);
    const int a0 = (end - beg + 1) - a1;
    a01[n] = a0 | (a1 << 16);
    m[0] = (float)a0;
    m[1] = (float)a1;
    m[2] = (float)a0 * (float)a0;
    m[3] = (float)a1 * (float)a1;
    m[4] = (float)a0 * (float)a1;
  }
  #pragma unroll
  for (int j = 0; j < 5; ++j)
    #pragma unroll
    for (int off = 1; off < 64; off <<= 1) m[j] += __shfl_xor(m[j], off);
  __shared__ float sm[5][4];
  const int lane = threadIdx.x & 63, wv = threadIdx.x >> 6;
  if (lane == 0)
    #pragma unroll
    for (int j = 0; j < 5; ++j) sm[j][wv] = m[j];
  __syncthreads();
  if (threadIdx.x == 0)
    #pragma unroll
    for (int j = 0; j < 5; ++j)
      momp[j * NBC + blockIdx.x] = sm[j][0] + sm[j][1] + sm[j][2] + sm[j][3];
}

// bn1 (layer 1) a/c from moments
__global__ __launch_bounds__(128) void k_bnmom(const float* __restrict__ momp,
                                               const float* __restrict__ ee,
                                               const float* __restrict__ g,
                                               const float* __restrict__ b,
                                               float* __restrict__ a,
                                               float* __restrict__ c) {
  __shared__ float red[5][128];
  const int t = threadIdx.x;
  float s[5] = {0.f, 0.f, 0.f, 0.f, 0.f};
  for (int i = t; i < NBC; i += 128)
    #pragma unroll
    for (int j = 0; j < 5; ++j) s[j] += momp[j * NBC + i];
  #pragma unroll
  for (int j = 0; j < 5; ++j) red[j][t] = s[j];
  __syncthreads();
  for (int off = 64; off; off >>= 1) {
    if (t < off)
      #pragma unroll
      for (int j = 0; j < 5; ++j) red[j][t] += red[j][t + off];
    __syncthreads();
  }
  const float S0 = red[0][0], S1 = red[1][0];
  const float S00 = red[2][0], S11 = red[3][0], S01 = red[4][0];
  const float inv_n = 1.0f / (float)NN;
  const float e0 = ee[t], e1 = ee[128 + t];
  const float mean = (S0 * e0 + S1 * e1) * inv_n;
  const float msq = (S00 * e0 * e0 + 2.f * S01 * e0 * e1 + S11 * e1 * e1) * inv_n;
  float var = fmaxf(msq - mean * mean, 0.f);
  const float rs = rsqrtf(var + BN_EPS);
  const float av = g[t] * rs;
  a[t] = av;
  c[t] = b[t] - mean * av;
}

// u1[n] = a0*e0 + a1*e1 ; R[n] = x[n] ? r1 : r0
__global__ __launch_bounds__(256) void k_l1expand(const int* __restrict__ x,
                                                  const int* __restrict__ a01,
                                                  const float* __restrict__ ee,
                                                  float* __restrict__ u1,
                                                  float* __restrict__ R) {
  const int total = NN * 32;
  for (int i = blockIdx.x * blockDim.x + threadIdx.x; i < total;
       i += gridDim.x * blockDim.x) {
    const int node = i >> 5, q = i & 31;
    const int p = a01[node];
    const float a0 = (float)(p & 0xffff), a1 = (float)(p >> 16);
    const float4 e0q = ((const float4*)ee)[q];
    const float4 e1q = ((const float4*)ee)[32 + q];
    float4 u;
    u.x = a0 * e0q.x + a1 * e1q.x;
    u.y = a0 * e0q.y + a1 * e1q.y;
    u.z = a0 * e0q.z + a1 * e1q.z;
    u.w = a0 * e0q.w + a1 * e1q.w;
    ((float4*)(u1 + (size_t)node * HID))[q] = u;
    const float4 rq = (x[node] & 1) ? ((const float4*)ee)[96 + q]
                                    : ((const float4*)ee)[64 + q];
    ((float4*)(R + (size_t)node * HID))[q] = rq;
  }
}

// ---------------- aggregation: z[n] = h[n] + sum_{src in row n} h[src] ----------------
__global__ __launch_bounds__(256) void k_agg(const float* __restrict__ h,
                                             const int* __restrict__ rp,
                                             const int* __restrict__ csr,
                                             float* __restrict__ z) {
  const int wid = blockIdx.x * 4 + (threadIdx.x >> 6);
  const int lane = threadIdx.x & 63;
  if (wid >= NN) return;
  const int beg = rp[wid], end = rp[wid + 1];
  float2 acc = *(const float2*)(h + (size_t)wid * HID + lane * 2);
  for (int j = beg; j < end; j += 64) {
    const int cnt = min(64, end - j);
    int idx = (lane < cnt) ? csr[j + lane] : 0;
    idx = min(max(idx, 0), NN - 1);
    int k = 0;
    for (; k + 4 <= cnt; k += 4) {
      const int s0 = __shfl(idx, k + 0), s1 = __shfl(idx, k + 1);
      const int s2 = __shfl(idx, k + 2), s3 = __shfl(idx, k + 3);
      const float2 v0 = *(const float2*)(h + (size_t)s0 * HID + lane * 2);
      const float2 v1 = *(const float2*)(h + (size_t)s1 * HID + lane * 2);
      const float2 v2 = *(const float2*)(h + (size_t)s2 * HID + lane * 2);
      const float2 v3 = *(const float2*)(h + (size_t)s3 * HID + lane * 2);
      acc.x += (v0.x + v1.x) + (v2.x + v3.x);
      acc.y += (v0.y + v1.y) + (v2.y + v3.y);
    }
    for (; k < cnt; ++k) {
      const int s = __shfl(idx, k);
      const float2 v = *(const float2*)(h + (size_t)s * HID + lane * 2);
      acc.x += v.x;
      acc.y += v.y;
    }
  }
  *(float2*)(z + (size_t)wid * HID + lane * 2) = acc;
}

// ---------------- split-bf16 MFMA GEMM (pre-split W): out (+)= act(A) @ W ----------------
// IN_ACT: 0 identity, 1 relu(a*ina+inc), 2 elu(a*ina+inc)+write-back, 3 elu (no wb)
// OUT_MODE: 0 store + per-block column stats, 2 accumulate (+=)
template <int IN_ACT, int OUT_MODE>
__global__ __launch_bounds__(256, 2) void k_gemm(
    float* A, const short* __restrict__ Wsp,
    const float* __restrict__ ina, const float* __restrict__ inc,
    float* __restrict__ out, float* __restrict__ part) {
  __shared__ short Ah[BM * SA];
  __shared__ short Al[BM * SA];
  __shared__ short Wh[HID * SA];
  __shared__ short Wl[HID * SA];
  const int tid = threadIdx.x;
  const int lane = tid & 63, wv = tid >> 6;
  const int tq = lane >> 4, tl = lane & 15;
  const int wc = wv * 32;  // wave's column base
  const int m0 = blockIdx.x * BM;

  f32x4 acc[6][2];
  #pragma unroll
  for (int i = 0; i < 6; ++i)
    #pragma unroll
    for (int j = 0; j < 2; ++j) acc[i][j] = (f32x4)(0.f);

  for (int kt = 0; kt < HID; kt += 64) {
    if (kt) __syncthreads();
    // ---- stage A[96][kt:kt+64] -> Ah/Al, optional activation (+write-back) ----
    #pragma unroll
    for (int p = 0; p < 6; ++p) {
      const int flat = p * 256 + tid;  // 1536 = 96 rows * 16 quads
      const int m = flat >> 4, kq = flat & 15;
      const int gm = m0 + m, gk = kt + kq * 4;
      float vv[4] = {0.f, 0.f, 0.f, 0.f};
      if (gm < NN) {
        const float4 v = *(const float4*)(A + (size_t)gm * HID + gk);
        vv[0] = v.x; vv[1] = v.y; vv[2] = v.z; vv[3] = v.w;
        if (IN_ACT >= 1) {
          const float4 a4 = *(const float4*)(ina + gk);
          const float4 c4 = *(const float4*)(inc + gk);
          const float aa[4] = {a4.x, a4.y, a4.z, a4.w};
          const float cc[4] = {c4.x, c4.y, c4.z, c4.w};
          #pragma unroll
          for (int j = 0; j < 4; ++j) {
            float z = fmaf(vv[j], aa[j], cc[j]);
            if (IN_ACT == 1) vv[j] = fmaxf(z, 0.f);
            else vv[j] = z > 0.f ? z : expm1f(z);
          }
        }
        if (IN_ACT == 2)
          *(float4*)(A + (size_t)gm * HID + gk) =
              make_float4(vv[0], vv[1], vv[2], vv[3]);
      }
      u16x4 hh, ll;
      #pragma unroll
      for (int j = 0; j < 4; ++j) {
        const unsigned short hb = f2bf(vv[j]);
        hh[j] = hb;
        ll[j] = f2bf(vv[j] - bf2f(hb));
      }
      *(u16x4*)(&Ah[m * SA + kq * 4]) = hh;
      *(u16x4*)(&Al[m * SA + kq * 4]) = ll;
    }
    // ---- stage pre-split W tile: Wsp is [n][k] hi at +0, lo at +16384 ----
    #pragma unroll
    for (int p = 0; p < 8; ++p) {
      const int flat = p * 256 + tid;  // 2048 = 128 n * 16 kq
      const int n = flat >> 4, kq = flat & 15;
      const u16x4 hh = *(const u16x4*)(Wsp + n * HID + kt + kq * 4);
      const u16x4 ll = *(const u16x4*)(Wsp + 16384 + n * HID + kt + kq * 4);
      *(u16x4*)(&Wh[n * SA + kq * 4]) = hh;
      *(u16x4*)(&Wl[n * SA + kq * 4]) = ll;
    }
    __syncthreads();
    // ---- MFMA over this K-tile ----
    #pragma unroll
    for (int kc = 0; kc < 64; kc += 32) {
      const int ko = kc + tq * 8;
      bf16x8 wh[2], wl[2];
      #pragma unroll
      for (int fn = 0; fn < 2; ++fn) {
        const int c = (wc + fn * 16 + tl) * SA + ko;
        wh[fn] = *(const bf16x8*)(&Wh[c]);
        wl[fn] = *(const bf16x8*)(&Wl[c]);
      }
      #pragma unroll
      for (int fm = 0; fm < 6; ++fm) {
        const int r = (fm * 16 + tl) * SA + ko;
        const bf16x8 ah = *(const bf16x8*)(&Ah[r]);
        const bf16x8 al = *(const bf16x8*)(&Al[r]);
        #pragma unroll
        for (int fn = 0; fn < 2; ++fn) {
          acc[fm][fn] = __builtin_amdgcn_mfma_f32_16x16x32_bf16(ah, wh[fn], acc[fm][fn], 0, 0, 0);
          acc[fm][fn] = __builtin_amdgcn_mfma_f32_16x16x32_bf16(ah, wl[fn], acc[fm][fn], 0, 0, 0);
          acc[fm][fn] = __builtin_amdgcn_mfma_f32_16x16x32_bf16(al, wh[fn], acc[fm][fn], 0, 0, 0);
        }
      }
    }
  }

  // ---- epilogue: C/D layout col=lane&15, row=(lane>>4)*4+reg (m89-verified) ----
  #pragma unroll
  for (int fm = 0; fm < 6; ++fm) {
    #pragma unroll
    for (int reg = 0; reg < 4; ++reg) {
      const int row = m0 + fm * 16 + tq * 4 + reg;
      if (row < NN) {
        float* op = out + (size_t)row * HID + wc + tl;
        #pragma unroll
        for (int fn = 0; fn < 2; ++fn) {
          if (OUT_MODE == 2)
            op[fn * 16] += acc[fm][fn][reg];
          else
            op[fn * 16] = acc[fm][fn][reg];
        }
      }
    }
  }
  if (OUT_MODE == 0) {
    #pragma unroll
    for (int fn = 0; fn < 2; ++fn) {
      float s = 0.f, q = 0.f;
      #pragma unroll
      for (int fm = 0; fm < 6; ++fm)
        #pragma unroll
        for (int reg = 0; reg < 4; ++reg) {
          const float v = acc[fm][fn][reg];
          s += v;
          q = fmaf(v, v, q);
        }
      s += __shfl_xor(s, 16); q += __shfl_xor(q, 16);
      s += __shfl_xor(s, 32); q += __shfl_xor(q, 32);
      if (lane < 16) {
        const int col = wc + fn * 16 + lane;
        part[(size_t)blockIdx.x * 256 + col] = s;
        part[(size_t)blockIdx.x * 256 + 128 + col] = q;
      }
    }
  }
}

// ---------------- fused stats reduce + BN finalize (single kernel, 64 blocks) ----------
// Partials summed via atomicAdd into S (coherent point); last block finalizes a/c.
__global__ __launch_bounds__(256) void k_bnstat(const float* __restrict__ part,
                                                const float* __restrict__ g,
                                                const float* __restrict__ b,
                                                float* __restrict__ a,
                                                float* __restrict__ c,
                                                float* __restrict__ S,
                                                int* __restrict__ ctr) {
  const int tid = threadIdx.x;
  float acc = 0.f;
  for (int r = blockIdx.x; r < NBLK; r += 64) acc += part[(size_t)r * 256 + tid];
  atomicAdd(&S[tid], acc);
  __syncthreads();           // all 256 S-adds of this block issued
  __threadfence();           // release: S-adds visible before counter bump
  __shared__ int last;
  if (tid == 0) last = (atomicAdd(ctr, 1) == 63);
  __syncthreads();
  if (!last) return;
  __threadfence();           // acquire side
  const float tot = atomicAdd(&S[tid], 0.f);  // coherent read of final sum
  __shared__ float sm[256];
  sm[tid] = tot;
  __syncthreads();
  if (tid < 128) {
    const float inv_n = 1.0f / (float)NN;
    const float mean = sm[tid] * inv_n;
    float var = fmaxf(sm[tid + 128] * inv_n - mean * mean, 0.f);
    const float rs = rsqrtf(var + BN_EPS);
    const float av = g[tid] * rs;
    a[tid] = av;
    c[tid] = b[tid] - mean * av;
  }
}

// ---------------- readout: out[n] = relu(R[n,:] + rb1) . rW2 + rb2 ----------------
__global__ __launch_bounds__(256) void k_readout(const float* __restrict__ R,
                                                 const float* __restrict__ rb1,
                                                 const float* __restrict__ rW2,
                                                 const float* __restrict__ rb2,
                                                 float* __restrict__ out) {
  const int wid = blockIdx.x * 4 + (threadIdx.x >> 6);
  const int lane = threadIdx.x & 63;
  if (wid >= NN) return;
  const float2 v = *(const float2*)(R + (size_t)wid * HID + lane * 2);
  const float2 b = *(const float2*)(rb1 + lane * 2);
  const float2 w = *(const float2*)(rW2 + lane * 2);
  float p = fmaxf(v.x + b.x, 0.f) * w.x + fmaxf(v.y + b.y, 0.f) * w.y;
  p += __shfl_xor(p, 1);
  p += __shfl_xor(p, 2);
  p += __shfl_xor(p, 4);
  p += __shfl_xor(p, 8);
  p += __shfl_xor(p, 16);
  p += __shfl_xor(p, 32);
  if (lane == 0) out[wid] = p + rb2[0];
}

// ---------------- launcher ----------------
extern "C" void kernel_launch(void* const* d_in, const int* in_sizes, int n_in,
                              void* d_out, int out_size, void* d_ws,
                              size_t ws_size, hipStream_t stream) {
  if (ws_size < WS_NEEDED) return;  // diagnostic guard: clean fail, no fault

  const int* x = (const int*)d_in[0];
  const int* E = (const int*)d_in[1];
  const float* emb = (const float*)d_in[2];
  const float* W1 = (const float*)d_in[3];
  const float* W2 = (const float*)d_in[4];
  const float* bn1g = (const float*)d_in[5];
  const float* bn1b = (const float*)d_in[6];
  const float* bn2g = (const float*)d_in[7];
  const float* bn2b = (const float*)d_in[8];
  const float* rW1 = (const float*)d_in[9];
  const float* rb1 = (const float*)d_in[10];
  const float* rW2 = (const float*)d_in[11];
  const float* rb2 = (const float*)d_in[12];
  float* outp = (float*)d_out;

  char* ws = (char*)d_ws;
  float* P = (float*)(ws + OFF_P);
  float* Q = (float*)(ws + OFF_Q);
  float* R = (float*)(ws + OFF_R);
  int* csr = (int*)(ws + OFF_CSR);
  int* rp = (int*)(ws + OFF_RP);
  int* cnt = (int*)(ws + OFF_CNT);
  int* bs = (int*)(ws + OFF_BS);
  int* flag = (int*)(ws + OFF_FLG);
  float* SS = (float*)(ws + OFF_SS);
  int* SCT = (int*)(ws + OFF_SCT);
  float* ac = (float*)(ws + OFF_AC);
  float* ee = (float*)(ws + OFF_E);
  short* wsp = (short*)(ws + OFF_WSP);
  // layer-1 scratch inside P (dead until layer-1 stats): a01 at +4MB, momp at +8MB
  int* a01 = (int*)((char*)P + (4 << 20));
  float* momp = (float*)((char*)P + (8 << 20));

  hipMemsetAsync(ws + OFF_ZZ, 0, ZZ_BYTES, stream);
  k_detect<<<1, 64, 0, stream>>>(E, flag);
  k_hist<<<2048, 256, 0, stream>>>(E, flag, cnt);
  k_scan1<<<NB_SCAN, 256, 0, stream>>>(cnt, rp, bs);
  k_scan2<<<1, 128, 0, stream>>>(bs);
  k_scan3<<<NB_SCAN, 256, 0, stream>>>(rp, bs, cnt);
  k_scatter<<<SC_CHUNKS * 8, 256, 0, stream>>>(E, flag, cnt, csr);
  k_prep<<<1, 256, 0, stream>>>(emb, W1, rW1, ee);
  k_prepw<<<512, 256, 0, stream>>>(W1, W2, rW1, wsp);

  float* a1 = ac + 0 * 256, *c1 = a1 + HID;
  float* a2 = ac + 1 * 256, *c2 = a2 + HID;

  // ---- layer 1 via rank-2 shortcut ----
  k_cnt<<<NBC, 256, 0, stream>>>(x, rp, csr, a01, momp);
  k_bnmom<<<1, 128, 0, stream>>>(momp, ee, bn1g, bn1b, a1, c1);
  k_l1expand<<<2048, 256, 0, stream>>>(x, a01, ee, Q, R);  // u1 -> Q, R init
  k_gemm<1, 0><<<NBLK, 256, 0, stream>>>(Q, wsp + 0 * 32768, a1, c1, Q, P);
  k_bnstat<<<64, 256, 0, stream>>>(P, bn2g, bn2b, a2, c2, SS + 0 * 256, SCT + 0);
  // R += elu(bn2(v1)) @ rW1[128:256]; h1 written back into Q
  k_gemm<2, 2><<<NBLK, 256, 0, stream>>>(Q, wsp + 1 * 32768, a2, c2, R, nullptr);

  // ---- layers 2,3 ----
  float* h = Q;
  float* w = P;
  int inst = 1;
  for (int i = 1; i < 3; ++i) {
    float* b1a = ac + (2 * i) * 256, *b1c = b1a + HID;
    float* b2a = ac + (2 * i + 1) * 256, *b2c = b2a + HID;
    const int mbase = (i == 1) ? 2 : 5;  // W1[i], W2[i], rW1[i+1] mat indices
    k_agg<<<NN / 4, 256, 0, stream>>>(h, rp, csr, w);
    float* part = h;  // h dead after agg
    k_gemm<0, 0><<<NBLK, 256, 0, stream>>>(
        w, wsp + (size_t)mbase * 32768, nullptr, nullptr, w, part);
    k_bnstat<<<64, 256, 0, stream>>>(part, bn1g + i * HID, bn1b + i * HID, b1a,
                                     b1c, SS + inst * 256, SCT + inst);
    ++inst;
    k_gemm<1, 0><<<NBLK, 256, 0, stream>>>(
        w, wsp + (size_t)(mbase + 1) * 32768, b1a, b1c, w, part);
    k_bnstat<<<64, 256, 0, stream>>>(part, bn2g + i * HID, bn2b + i * HID, b2a,
                                     b2c, SS + inst * 256, SCT + inst);
    ++inst;
    if (i < 2) {
      k_gemm<2, 2><<<NBLK, 256, 0, stream>>>(
          w, wsp + (size_t)(mbase + 2) * 32768, b2a, b2c, R, nullptr);
    } else {
      k_gemm<3, 2><<<NBLK, 256, 0, stream>>>(
          w, wsp + (size_t)(mbase + 2) * 32768, b2a, b2c, R, nullptr);
    }
    float* t = h; h = w; w = t;
  }

  k_readout<<<NN / 4, 256, 0, stream>>>(R, rb1, rW2, rb2, outp);
}

// Round 7
// 738.565 us; speedup vs baseline: 8.1728x; 1.2444x over previous
//
#include <hip/hip_runtime.h>
#include <hip/hip_fp16.h>
#include <cstdint>
#include <cstddef>

#define NN 100000
#define NE 1600000
#define HID 128
#define BN_EPS 1e-5f
#define NB_SCAN 98  // ceil(100000/1024)
#define BM 96
#define NBLK ((NN + BM - 1) / BM)   // 1042 gemm blocks
#define NBC  ((NN + 255) / 256)     // 391 count blocks
#define SA 72   // LDS stride (bf16 elems)
#define SC_CHUNKS 256
#define SC_RANGE (NN / 8)           // 12500
#define SC_EPC (NE / SC_CHUNKS)     // 6250

typedef __attribute__((ext_vector_type(8))) short bf16x8;
typedef __attribute__((ext_vector_type(4))) float f32x4;
typedef __attribute__((ext_vector_type(4))) unsigned short u16x4;

// ---------------- workspace layout (bytes) ----------------
static constexpr size_t SZ_NODE = (size_t)NN * HID * 4;            // 51.2 MB
static constexpr size_t SZ_H16  = (size_t)NN * HID * 2;            // 25.6 MB
static constexpr size_t OFF_P   = 0;                               // h1 fp16 [0,25.6M) + h2 fp16 [25.6M,51.2M)
static constexpr size_t OFF_Q   = SZ_NODE;                         // z/u/v in-place chain (fp32)
static constexpr size_t OFF_R   = 2 * SZ_NODE;                     // part (1.07MB) then h3 fp16
static constexpr size_t OFF_CSR = 3 * SZ_NODE;
static constexpr size_t OFF_RP  = OFF_CSR + (size_t)NE * 4;
static constexpr size_t OFF_ZZ  = ((OFF_RP + (size_t)(NN + 1) * 4 + 255) / 256) * 256;
static constexpr size_t OFF_CNT = OFF_ZZ;
static constexpr size_t OFF_BS  = OFF_CNT + (((size_t)NN * 4 + 255) / 256) * 256;
static constexpr size_t OFF_FLG = OFF_BS + 512;
static constexpr size_t OFF_SS  = OFF_FLG + 256;                   // 5 x 256 f32 atomic sums
static constexpr size_t OFF_SCT = OFF_SS + 5 * 256 * 4;            // 5 int counters
static constexpr size_t ZZ_END  = ((OFF_SCT + 5 * 4 + 255) / 256) * 256;
static constexpr size_t ZZ_BYTES = ZZ_END - OFF_ZZ;
static constexpr size_t OFF_AC  = ZZ_END;                          // 6 x 256 f32 (bn a/c)
static constexpr size_t OFF_E   = OFF_AC + 6 * 256 * 4;            // ee: e0,e1,r0,r1 = 512 f32
static constexpr size_t OFF_WSP = OFF_E + 512 * 4;                 // 8 mats x [2][128][128] shorts
static constexpr size_t WS_NEEDED = OFF_WSP + (size_t)8 * 2 * HID * HID * 2;

// ---------------- helpers ----------------
__device__ __forceinline__ unsigned short f2bf(float f) {
  unsigned u = __float_as_uint(f);
  unsigned r = (u + 0x7fffu + ((u >> 16) & 1u)) >> 16;
  return (unsigned short)r;
}
__device__ __forceinline__ float bf2f(unsigned short b) {
  return __uint_as_float(((unsigned)b) << 16);
}
__device__ __forceinline__ int edge_at(const int* __restrict__ E, int f, int idx) {
  return f ? E[2 * (long long)idx] : E[idx];
}

// ---------------- dtype detection ----------------
__global__ void k_detect(const int* __restrict__ E, int* __restrict__ flag) {
  if (threadIdx.x == 0 && blockIdx.x == 0) {
    int f = 1;
    for (int i = 1; i < 256; i += 2)
      if (E[i] != 0) { f = 0; break; }
    *flag = f;
  }
}

// ---------------- CSR build ----------------
__global__ __launch_bounds__(256) void k_hist(const int* __restrict__ E,
                                              const int* __restrict__ flag,
                                              int* __restrict__ cnt) {
  const int f = *flag;
  for (int e = blockIdx.x * blockDim.x + threadIdx.x; e < NE;
       e += gridDim.x * blockDim.x) {
    int d = edge_at(E, f, NE + e);
    d = min(max(d, 0), NN - 1);
    atomicAdd(&cnt[d], 1);
  }
}

__global__ __launch_bounds__(256) void k_scan1(const int* __restrict__ cnt,
                                               int* __restrict__ rp,
                                               int* __restrict__ bs) {
  __shared__ int s[256];
  const int tid = threadIdx.x;
  const int base = blockIdx.x * 1024 + tid * 4;
  int v0 = 0, v1 = 0, v2 = 0, v3 = 0;
  if (base + 0 < NN) v0 = cnt[base + 0];
  if (base + 1 < NN) v1 = cnt[base + 1];
  if (base + 2 < NN) v2 = cnt[base + 2];
  if (base + 3 < NN) v3 = cnt[base + 3];
  const int t0 = v0, t1 = t0 + v1, t2 = t1 + v2, t3 = t2 + v3;
  s[tid] = t3;
  __syncthreads();
  for (int off = 1; off < 256; off <<= 1) {
    int xv = 0;
    if (tid >= off) xv = s[tid - off];
    __syncthreads();
    if (tid >= off) s[tid] += xv;
    __syncthreads();
  }
  const int excl = tid ? s[tid - 1] : 0;
  if (base + 0 < NN) rp[base + 0] = excl;
  if (base + 1 < NN) rp[base + 1] = excl + t0;
  if (base + 2 < NN) rp[base + 2] = excl + t1;
  if (base + 3 < NN) rp[base + 3] = excl + t2;
  if (tid == 255) bs[blockIdx.x] = s[255];
}

__global__ __launch_bounds__(128) void k_scan2(int* __restrict__ bs) {
  __shared__ int s[128];
  const int tid = threadIdx.x;
  s[tid] = (tid < NB_SCAN) ? bs[tid] : 0;
  __syncthreads();
  for (int off = 1; off < 128; off <<= 1) {
    int xv = 0;
    if (tid >= off) xv = s[tid - off];
    __syncthreads();
    if (tid >= off) s[tid] += xv;
    __syncthreads();
  }
  if (tid < NB_SCAN) bs[tid] = tid ? s[tid - 1] : 0;
}

__global__ __launch_bounds__(256) void k_scan3(int* __restrict__ rp,
                                               const int* __restrict__ bs,
                                               int* __restrict__ cursor) {
  const int off = bs[blockIdx.x];
  const int base = blockIdx.x * 1024 + threadIdx.x * 4;
  #pragma unroll
  for (int j = 0; j < 4; ++j) {
    const int i = base + j;
    if (i < NN) {
      const int v = rp[i] + off;
      rp[i] = v;
      cursor[i] = v;
    }
  }
  if (blockIdx.x == 0 && threadIdx.x == 0) rp[NN] = NE;
}

// XCD-bucketed scatter (round-6 verified win)
__global__ __launch_bounds__(256) void k_scatter(const int* __restrict__ E,
                                                 const int* __restrict__ flag,
                                                 int* __restrict__ cursor,
                                                 int* __restrict__ csr) {
  const int f = *flag;
  const int r = blockIdx.x & 7;
  const int chunk = blockIdx.x >> 3;
  const int lo = r * SC_RANGE, hi = lo + SC_RANGE;
  const int ebeg = chunk * SC_EPC, eend = ebeg + SC_EPC;
  for (int e = ebeg + threadIdx.x; e < eend; e += 256) {
    int d = edge_at(E, f, NE + e);
    d = min(max(d, 0), NN - 1);
    if (d >= lo && d < hi) {
      int s = edge_at(E, f, e);
      s = min(max(s, 0), NN - 1);
      const int pos = atomicAdd(&cursor[d], 1);
      if ((unsigned)pos < (unsigned)NE) csr[pos] = s;
    }
  }
}

// ---------------- weight pre-split: fp32 [k][n] -> [n][k] bf16 hi/lo ----------------
// slots: 0=W2[0] 1=W1[1] 2=W2[1] 3=W1[2] 4=W2[2] 5=rW1[1] 6=rW1[2] 7=rW1[3]
__global__ __launch_bounds__(256) void k_prepw(const float* __restrict__ W1,
                                               const float* __restrict__ W2,
                                               const float* __restrict__ rW1,
                                               short* __restrict__ wsp) {
  const int g = blockIdx.x * 256 + threadIdx.x;
  const int m = g >> 14, idx = g & 16383;
  const int k = idx >> 7, n = idx & 127;
  const float* src;
  switch (m) {
    case 0: src = W2; break;
    case 1: src = W1 + 1 * HID * HID; break;
    case 2: src = W2 + 1 * HID * HID; break;
    case 3: src = W1 + 2 * HID * HID; break;
    case 4: src = W2 + 2 * HID * HID; break;
    case 5: src = rW1 + 1 * HID * HID; break;
    case 6: src = rW1 + 2 * HID * HID; break;
    default: src = rW1 + 3 * HID * HID; break;
  }
  const float v = src[k * HID + n];
  const unsigned short hb = f2bf(v);
  short* dst = wsp + (size_t)m * 32768;
  dst[n * HID + k] = (short)hb;
  dst[16384 + n * HID + k] = (short)f2bf(v - bf2f(hb));
}

// ---------------- layer-1 rank-2 shortcut ----------------
__global__ __launch_bounds__(256) void k_prep(const float* __restrict__ emb,
                                              const float* __restrict__ W1,
                                              const float* __restrict__ rW1,
                                              float* __restrict__ ee) {
  const int t = threadIdx.x;
  const int f = t & 127;
  const float* er = emb + (t >> 7) * HID;
  float se = 0.f, sr = 0.f;
  for (int k = 0; k < HID; ++k) {
    const float ev = er[k];
    se = fmaf(ev, W1[k * HID + f], se);
    sr = fmaf(ev, rW1[k * HID + f], sr);
  }
  ee[t] = se;        // e0,e1
  ee[256 + t] = sr;  // r0,r1
}

__global__ __launch_bounds__(256) void k_cnt(const int* __restrict__ x,
                                             const int* __restrict__ rp,
                                             const int* __restrict__ csr,
                                             int* __restrict__ a01,
                                             float* __restrict__ momp) {
  const int n = blockIdx.x * 256 + threadIdx.x;
  float m[5] = {0.f, 0.f, 0.f, 0.f, 0.f};
  if (n < NN) {
    const int beg = rp[n], end = rp[n + 1];
    int c1 = 0;
    for (int j = beg; j < end; ++j) c1 += x[csr[j]] & 1;
    const int a1 = c1 + (x[n] & 1);
    const int a0 = (end - beg + 1) - a1;
    a01[n] = a0 | (a1 << 16);
    m[0] = (float)a0;
    m[1] = (float)a1;
    m[2] = (float)a0 * (float)a0;
    m[3] = (float)a1 * (float)a1;
    m[4] = (float)a0 * (float)a1;
  }
  #pragma unroll
  for (int j = 0; j < 5; ++j)
    #pragma unroll
    for (int off = 1; off < 64; off <<= 1) m[j] += __shfl_xor(m[j], off);
  __shared__ float sm[5][4];
  const int lane = threadIdx.x & 63, wv = threadIdx.x >> 6;
  if (lane == 0)
    #pragma unroll
    for (int j = 0; j < 5; ++j) sm[j][wv] = m[j];
  __syncthreads();
  if (threadIdx.x == 0)
    #pragma unroll
    for (int j = 0; j < 5; ++j)
      momp[j * NBC + blockIdx.x] = sm[j][0] + sm[j][1] + sm[j][2] + sm[j][3];
}

__global__ __launch_bounds__(128) void k_bnmom(const float* __restrict__ momp,
                                               const float* __restrict__ ee,
                                               const float* __restrict__ g,
                                               const float* __restrict__ b,
                                               float* __restrict__ a,
                                               float* __restrict__ c) {
  __shared__ float red[5][128];
  const int t = threadIdx.x;
  float s[5] = {0.f, 0.f, 0.f, 0.f, 0.f};
  for (int i = t; i < NBC; i += 128)
    #pragma unroll
    for (int j = 0; j < 5; ++j) s[j] += momp[j * NBC + i];
  #pragma unroll
  for (int j = 0; j < 5; ++j) red[j][t] = s[j];
  __syncthreads();
  for (int off = 64; off; off >>= 1) {
    if (t < off)
      #pragma unroll
      for (int j = 0; j < 5; ++j) red[j][t] += red[j][t + off];
    __syncthreads();
  }
  const float S0 = red[0][0], S1 = red[1][0];
  const float S00 = red[2][0], S11 = red[3][0], S01 = red[4][0];
  const float inv_n = 1.0f / (float)NN;
  const float e0 = ee[t], e1 = ee[128 + t];
  const float mean = (S0 * e0 + S1 * e1) * inv_n;
  const float msq = (S00 * e0 * e0 + 2.f * S01 * e0 * e1 + S11 * e1 * e1) * inv_n;
  float var = fmaxf(msq - mean * mean, 0.f);
  const float rs = rsqrtf(var + BN_EPS);
  const float av = g[t] * rs;
  a[t] = av;
  c[t] = b[t] - mean * av;
}

// u1[n] = a0*e0 + a1*e1 (R init removed — deferred to rdgemm)
__global__ __launch_bounds__(256) void k_l1expand(const int* __restrict__ a01,
                                                  const float* __restrict__ ee,
                                                  float* __restrict__ u1) {
  const int total = NN * 32;
  for (int i = blockIdx.x * blockDim.x + threadIdx.x; i < total;
       i += gridDim.x * blockDim.x) {
    const int node = i >> 5, q = i & 31;
    const int p = a01[node];
    const float a0 = (float)(p & 0xffff), a1 = (float)(p >> 16);
    const float4 e0q = ((const float4*)ee)[q];
    const float4 e1q = ((const float4*)ee)[32 + q];
    float4 u;
    u.x = a0 * e0q.x + a1 * e1q.x;
    u.y = a0 * e0q.y + a1 * e1q.y;
    u.z = a0 * e0q.z + a1 * e1q.z;
    u.w = a0 * e0q.w + a1 * e1q.w;
    ((float4*)(u1 + (size_t)node * HID))[q] = u;
  }
}

// ---------------- aggregation (fp16 reps): z[n] = h[n] + sum h[src], fp32 out ----------
__global__ __launch_bounds__(256) void k_agg(const __half* __restrict__ h,
                                             const int* __restrict__ rp,
                                             const int* __restrict__ csr,
                                             float* __restrict__ z) {
  const int wid = blockIdx.x * 4 + (threadIdx.x >> 6);
  const int lane = threadIdx.x & 63;
  if (wid >= NN) return;
  const int beg = rp[wid], end = rp[wid + 1];
  float2 acc = __half22float2(*((const __half2*)(h + (size_t)wid * HID) + lane));
  for (int j = beg; j < end; j += 64) {
    const int cnt = min(64, end - j);
    int idx = (lane < cnt) ? csr[j + lane] : 0;
    idx = min(max(idx, 0), NN - 1);
    int k = 0;
    for (; k + 4 <= cnt; k += 4) {
      const int s0 = __shfl(idx, k + 0), s1 = __shfl(idx, k + 1);
      const int s2 = __shfl(idx, k + 2), s3 = __shfl(idx, k + 3);
      const float2 v0 = __half22float2(*((const __half2*)(h + (size_t)s0 * HID) + lane));
      const float2 v1 = __half22float2(*((const __half2*)(h + (size_t)s1 * HID) + lane));
      const float2 v2 = __half22float2(*((const __half2*)(h + (size_t)s2 * HID) + lane));
      const float2 v3 = __half22float2(*((const __half2*)(h + (size_t)s3 * HID) + lane));
      acc.x += (v0.x + v1.x) + (v2.x + v3.x);
      acc.y += (v0.y + v1.y) + (v2.y + v3.y);
    }
    for (; k < cnt; ++k) {
      const int s = __shfl(idx, k);
      const float2 v = __half22float2(*((const __half2*)(h + (size_t)s * HID) + lane));
      acc.x += v.x;
      acc.y += v.y;
    }
  }
  *(float2*)(z + (size_t)wid * HID + lane * 2) = acc;
}

// ---------------- split-bf16 MFMA GEMM (pre-split W): out = act(A) @ W ----------------
// IN_ACT: 0 identity, 1 relu(a*ina+inc)
// OUT_MODE: 0 store + per-block column stats
template <int IN_ACT, int OUT_MODE>
__global__ __launch_bounds__(256, 2) void k_gemm(
    float* A, const short* __restrict__ Wsp,
    const float* __restrict__ ina, const float* __restrict__ inc,
    float* __restrict__ out, float* __restrict__ part) {
  __shared__ short Ah[BM * SA];
  __shared__ short Al[BM * SA];
  __shared__ short Wh[HID * SA];
  __shared__ short Wl[HID * SA];
  const int tid = threadIdx.x;
  const int lane = tid & 63, wv = tid >> 6;
  const int tq = lane >> 4, tl = lane & 15;
  const int wc = wv * 32;
  const int m0 = blockIdx.x * BM;

  f32x4 acc[6][2];
  #pragma unroll
  for (int i = 0; i < 6; ++i)
    #pragma unroll
    for (int j = 0; j < 2; ++j) acc[i][j] = (f32x4)(0.f);

  for (int kt = 0; kt < HID; kt += 64) {
    if (kt) __syncthreads();
    #pragma unroll
    for (int p = 0; p < 6; ++p) {
      const int flat = p * 256 + tid;
      const int m = flat >> 4, kq = flat & 15;
      const int gm = m0 + m, gk = kt + kq * 4;
      float vv[4] = {0.f, 0.f, 0.f, 0.f};
      if (gm < NN) {
        const float4 v = *(const float4*)(A + (size_t)gm * HID + gk);
        vv[0] = v.x; vv[1] = v.y; vv[2] = v.z; vv[3] = v.w;
        if (IN_ACT == 1) {
          const float4 a4 = *(const float4*)(ina + gk);
          const float4 c4 = *(const float4*)(inc + gk);
          vv[0] = fmaxf(fmaf(vv[0], a4.x, c4.x), 0.f);
          vv[1] = fmaxf(fmaf(vv[1], a4.y, c4.y), 0.f);
          vv[2] = fmaxf(fmaf(vv[2], a4.z, c4.z), 0.f);
          vv[3] = fmaxf(fmaf(vv[3], a4.w, c4.w), 0.f);
        }
      }
      u16x4 hh, ll;
      #pragma unroll
      for (int j = 0; j < 4; ++j) {
        const unsigned short hb = f2bf(vv[j]);
        hh[j] = hb;
        ll[j] = f2bf(vv[j] - bf2f(hb));
      }
      *(u16x4*)(&Ah[m * SA + kq * 4]) = hh;
      *(u16x4*)(&Al[m * SA + kq * 4]) = ll;
    }
    #pragma unroll
    for (int p = 0; p < 8; ++p) {
      const int flat = p * 256 + tid;
      const int n = flat >> 4, kq = flat & 15;
      const u16x4 hh = *(const u16x4*)(Wsp + n * HID + kt + kq * 4);
      const u16x4 ll = *(const u16x4*)(Wsp + 16384 + n * HID + kt + kq * 4);
      *(u16x4*)(&Wh[n * SA + kq * 4]) = hh;
      *(u16x4*)(&Wl[n * SA + kq * 4]) = ll;
    }
    __syncthreads();
    #pragma unroll
    for (int kc = 0; kc < 64; kc += 32) {
      const int ko = kc + tq * 8;
      bf16x8 wh[2], wl[2];
      #pragma unroll
      for (int fn = 0; fn < 2; ++fn) {
        const int c = (wc + fn * 16 + tl) * SA + ko;
        wh[fn] = *(const bf16x8*)(&Wh[c]);
        wl[fn] = *(const bf16x8*)(&Wl[c]);
      }
      #pragma unroll
      for (int fm = 0; fm < 6; ++fm) {
        const int r = (fm * 16 + tl) * SA + ko;
        const bf16x8 ah = *(const bf16x8*)(&Ah[r]);
        const bf16x8 al = *(const bf16x8*)(&Al[r]);
        #pragma unroll
        for (int fn = 0; fn < 2; ++fn) {
          acc[fm][fn] = __builtin_amdgcn_mfma_f32_16x16x32_bf16(ah, wh[fn], acc[fm][fn], 0, 0, 0);
          acc[fm][fn] = __builtin_amdgcn_mfma_f32_16x16x32_bf16(ah, wl[fn], acc[fm][fn], 0, 0, 0);
          acc[fm][fn] = __builtin_amdgcn_mfma_f32_16x16x32_bf16(al, wh[fn], acc[fm][fn], 0, 0, 0);
        }
      }
    }
  }

  #pragma unroll
  for (int fm = 0; fm < 6; ++fm) {
    #pragma unroll
    for (int reg = 0; reg < 4; ++reg) {
      const int row = m0 + fm * 16 + tq * 4 + reg;
      if (row < NN) {
        float* op = out + (size_t)row * HID + wc + tl;
        op[0] = acc[fm][0][reg];
        op[16] = acc[fm][1][reg];
      }
    }
  }
  if (OUT_MODE == 0) {
    #pragma unroll
    for (int fn = 0; fn < 2; ++fn) {
      float s = 0.f, q = 0.f;
      #pragma unroll
      for (int fm = 0; fm < 6; ++fm)
        #pragma unroll
        for (int reg = 0; reg < 4; ++reg) {
          const float v = acc[fm][fn][reg];
          s += v;
          q = fmaf(v, v, q);
        }
      s += __shfl_xor(s, 16); q += __shfl_xor(q, 16);
      s += __shfl_xor(s, 32); q += __shfl_xor(q, 32);
      if (lane < 16) {
        const int col = wc + fn * 16 + lane;
        part[(size_t)blockIdx.x * 256 + col] = s;
        part[(size_t)blockIdx.x * 256 + 128 + col] = q;
      }
    }
  }
}

// ---------------- readout GEMM: out[n] = relu(sum_i h_i@rW1_i + sel + rb1).rW2 + rb2 ----
__global__ __launch_bounds__(256, 2) void k_rdgemm(
    const __half* __restrict__ h1, const __half* __restrict__ h2,
    const __half* __restrict__ h3, const short* __restrict__ wsp,
    const int* __restrict__ x, const float* __restrict__ ee,
    const float* __restrict__ rb1, const float* __restrict__ rW2,
    const float* __restrict__ rb2, float* __restrict__ out) {
  __shared__ short Ah[BM * SA];
  __shared__ short Al[BM * SA];
  __shared__ short Wh[HID * SA];
  __shared__ short Wl[HID * SA];
  const int tid = threadIdx.x;
  const int lane = tid & 63, wv = tid >> 6;
  const int tq = lane >> 4, tl = lane & 15;
  const int wc = wv * 32;
  const int m0 = blockIdx.x * BM;

  f32x4 acc[6][2];
  #pragma unroll
  for (int i = 0; i < 6; ++i)
    #pragma unroll
    for (int j = 0; j < 2; ++j) acc[i][j] = (f32x4)(0.f);

  for (int t6 = 0; t6 < 6; ++t6) {  // K=384: {h1,h2,h3} x {0,64}
    const __half* hsrc = (t6 < 2) ? h1 : (t6 < 4) ? h2 : h3;
    const short* Ws = wsp + (size_t)(t6 >> 1) * 32768;
    const int kt = (t6 & 1) * 64;
    if (t6) __syncthreads();
    #pragma unroll
    for (int p = 0; p < 6; ++p) {
      const int flat = p * 256 + tid;
      const int m = flat >> 4, kq = flat & 15;
      const int gm = m0 + m, gk = kt + kq * 4;
      float vv[4] = {0.f, 0.f, 0.f, 0.f};
      if (gm < NN) {
        const __half2 x0 = *(const __half2*)(hsrc + (size_t)gm * HID + gk);
        const __half2 x1 = *(const __half2*)(hsrc + (size_t)gm * HID + gk + 2);
        const float2 f0 = __half22float2(x0);
        const float2 f1 = __half22float2(x1);
        vv[0] = f0.x; vv[1] = f0.y; vv[2] = f1.x; vv[3] = f1.y;
      }
      u16x4 hh, ll;
      #pragma unroll
      for (int j = 0; j < 4; ++j) {
        const unsigned short hb = f2bf(vv[j]);
        hh[j] = hb;
        ll[j] = f2bf(vv[j] - bf2f(hb));
      }
      *(u16x4*)(&Ah[m * SA + kq * 4]) = hh;
      *(u16x4*)(&Al[m * SA + kq * 4]) = ll;
    }
    #pragma unroll
    for (int p = 0; p < 8; ++p) {
      const int flat = p * 256 + tid;
      const int n = flat >> 4, kq = flat & 15;
      const u16x4 hh = *(const u16x4*)(Ws + n * HID + kt + kq * 4);
      const u16x4 ll = *(const u16x4*)(Ws + 16384 + n * HID + kt + kq * 4);
      *(u16x4*)(&Wh[n * SA + kq * 4]) = hh;
      *(u16x4*)(&Wl[n * SA + kq * 4]) = ll;
    }
    __syncthreads();
    #pragma unroll
    for (int kc = 0; kc < 64; kc += 32) {
      const int ko = kc + tq * 8;
      bf16x8 wh[2], wl[2];
      #pragma unroll
      for (int fn = 0; fn < 2; ++fn) {
        const int c = (wc + fn * 16 + tl) * SA + ko;
        wh[fn] = *(const bf16x8*)(&Wh[c]);
        wl[fn] = *(const bf16x8*)(&Wl[c]);
      }
      #pragma unroll
      for (int fm = 0; fm < 6; ++fm) {
        const int r = (fm * 16 + tl) * SA + ko;
        const bf16x8 ah = *(const bf16x8*)(&Ah[r]);
        const bf16x8 al = *(const bf16x8*)(&Al[r]);
        #pragma unroll
        for (int fn = 0; fn < 2; ++fn) {
          acc[fm][fn] = __builtin_amdgcn_mfma_f32_16x16x32_bf16(ah, wh[fn], acc[fm][fn], 0, 0, 0);
          acc[fm][fn] = __builtin_amdgcn_mfma_f32_16x16x32_bf16(ah, wl[fn], acc[fm][fn], 0, 0, 0);
          acc[fm][fn] = __builtin_amdgcn_mfma_f32_16x16x32_bf16(al, wh[fn], acc[fm][fn], 0, 0, 0);
        }
      }
    }
  }

  // epilogue: + rb1 + (x ? r1 : r0), relu, dot rW2, reduce 128 cols per row
  const int c0 = wc + tl, c1 = wc + 16 + tl;
  const float rb_0 = rb1[c0], rb_1 = rb1[c1];
  const float w2_0 = rW2[c0], w2_1 = rW2[c1];
  const float r0_0 = ee[256 + c0], r0_1 = ee[256 + c1];
  const float r1_0 = ee[384 + c0], r1_1 = ee[384 + c1];
  __syncthreads();                 // done reading Ah -> reuse as reduction buffer
  float* rs = (float*)Ah;          // [96][4]
  #pragma unroll
  for (int fm = 0; fm < 6; ++fm) {
    #pragma unroll
    for (int reg = 0; reg < 4; ++reg) {
      const int row = fm * 16 + tq * 4 + reg;
      const int grow = m0 + row;
      const int xv = (grow < NN) ? (x[grow] & 1) : 0;
      const float g0 = acc[fm][0][reg] + rb_0 + (xv ? r1_0 : r0_0);
      const float g1 = acc[fm][1][reg] + rb_1 + (xv ? r1_1 : r0_1);
      float p = fmaxf(g0, 0.f) * w2_0 + fmaxf(g1, 0.f) * w2_1;
      p += __shfl_xor(p, 1);
      p += __shfl_xor(p, 2);
      p += __shfl_xor(p, 4);
      p += __shfl_xor(p, 8);
      if (tl == 0) rs[row * 4 + wv] = p;
    }
  }
  __syncthreads();
  if (tid < BM) {
    const int grow = m0 + tid;
    if (grow < NN)
      out[grow] = rs[tid * 4 + 0] + rs[tid * 4 + 1] + rs[tid * 4 + 2] +
                  rs[tid * 4 + 3] + rb2[0];
  }
}

// ---------------- fused stats reduce + BN finalize ----------------
__global__ __launch_bounds__(256) void k_bnstat(const float* __restrict__ part,
                                                const float* __restrict__ g,
                                                const float* __restrict__ b,
                                                float* __restrict__ a,
                                                float* __restrict__ c,
                                                float* __restrict__ S,
                                                int* __restrict__ ctr) {
  const int tid = threadIdx.x;
  float acc = 0.f;
  for (int r = blockIdx.x; r < NBLK; r += 64) acc += part[(size_t)r * 256 + tid];
  atomicAdd(&S[tid], acc);
  __syncthreads();
  __threadfence();
  __shared__ int last;
  if (tid == 0) last = (atomicAdd(ctr, 1) == 63);
  __syncthreads();
  if (!last) return;
  __threadfence();
  const float tot = atomicAdd(&S[tid], 0.f);
  __shared__ float sm[256];
  sm[tid] = tot;
  __syncthreads();
  if (tid < 128) {
    const float inv_n = 1.0f / (float)NN;
    const float mean = sm[tid] * inv_n;
    float var = fmaxf(sm[tid + 128] * inv_n - mean * mean, 0.f);
    const float rs = rsqrtf(var + BN_EPS);
    const float av = g[tid] * rs;
    a[tid] = av;
    c[tid] = b[tid] - mean * av;
  }
}

// ---------------- elementwise: h = elu(v*a + c) -> fp16 ----------------
__global__ __launch_bounds__(256) void k_act(const float* __restrict__ v,
                                             const float* __restrict__ a,
                                             const float* __restrict__ c,
                                             __half* __restrict__ h) {
  const int total = NN * 32;
  for (int i = blockIdx.x * blockDim.x + threadIdx.x; i < total;
       i += gridDim.x * blockDim.x) {
    const int node = i >> 5, q = i & 31;
    const float4 vv = *(const float4*)(v + (size_t)node * HID + q * 4);
    const float4 a4 = ((const float4*)a)[q];
    const float4 c4 = ((const float4*)c)[q];
    float z;
    float o0, o1, o2, o3;
    z = fmaf(vv.x, a4.x, c4.x); o0 = z > 0.f ? z : expm1f(z);
    z = fmaf(vv.y, a4.y, c4.y); o1 = z > 0.f ? z : expm1f(z);
    z = fmaf(vv.z, a4.z, c4.z); o2 = z > 0.f ? z : expm1f(z);
    z = fmaf(vv.w, a4.w, c4.w); o3 = z > 0.f ? z : expm1f(z);
    const __half2 p0 = __floats2half2_rn(o0, o1);
    const __half2 p1 = __floats2half2_rn(o2, o3);
    uint2 u;
    u.x = *reinterpret_cast<const unsigned*>(&p0);
    u.y = *reinterpret_cast<const unsigned*>(&p1);
    *(uint2*)(h + (size_t)node * HID + q * 4) = u;
  }
}

// ---------------- launcher ----------------
extern "C" void kernel_launch(void* const* d_in, const int* in_sizes, int n_in,
                              void* d_out, int out_size, void* d_ws,
                              size_t ws_size, hipStream_t stream) {
  if (ws_size < WS_NEEDED) return;

  const int* x = (const int*)d_in[0];
  const int* E = (const int*)d_in[1];
  const float* emb = (const float*)d_in[2];
  const float* W1 = (const float*)d_in[3];
  const float* W2 = (const float*)d_in[4];
  const float* bn1g = (const float*)d_in[5];
  const float* bn1b = (const float*)d_in[6];
  const float* bn2g = (const float*)d_in[7];
  const float* bn2b = (const float*)d_in[8];
  const float* rW1 = (const float*)d_in[9];
  const float* rb1 = (const float*)d_in[10];
  const float* rW2 = (const float*)d_in[11];
  const float* rb2 = (const float*)d_in[12];
  float* outp = (float*)d_out;

  char* ws = (char*)d_ws;
  float* P = (float*)(ws + OFF_P);
  float* Q = (float*)(ws + OFF_Q);
  float* R = (float*)(ws + OFF_R);
  int* csr = (int*)(ws + OFF_CSR);
  int* rp = (int*)(ws + OFF_RP);
  int* cnt = (int*)(ws + OFF_CNT);
  int* bs = (int*)(ws + OFF_BS);
  int* flag = (int*)(ws + OFF_FLG);
  float* SS = (float*)(ws + OFF_SS);
  int* SCT = (int*)(ws + OFF_SCT);
  float* ac = (float*)(ws + OFF_AC);
  float* ee = (float*)(ws + OFF_E);
  short* wsp = (short*)(ws + OFF_WSP);
  __half* h1 = (__half*)P;                         // [0, 25.6M)
  __half* h2 = (__half*)((char*)P + SZ_H16);       // [25.6M, 51.2M)
  __half* h3 = (__half*)R;                         // after stats done
  float* part = R;                                 // 1.07 MB, time-shared with h3
  // layer-1 scratch (dead before h1 is written)
  int* a01 = (int*)((char*)P + (4 << 20));
  float* momp = (float*)((char*)P + (8 << 20));

  hipMemsetAsync(ws + OFF_ZZ, 0, ZZ_BYTES, stream);
  k_detect<<<1, 64, 0, stream>>>(E, flag);
  k_hist<<<2048, 256, 0, stream>>>(E, flag, cnt);
  k_scan1<<<NB_SCAN, 256, 0, stream>>>(cnt, rp, bs);
  k_scan2<<<1, 128, 0, stream>>>(bs);
  k_scan3<<<NB_SCAN, 256, 0, stream>>>(rp, bs, cnt);
  k_scatter<<<SC_CHUNKS * 8, 256, 0, stream>>>(E, flag, cnt, csr);
  k_prep<<<1, 256, 0, stream>>>(emb, W1, rW1, ee);
  k_prepw<<<512, 256, 0, stream>>>(W1, W2, rW1, wsp);

  float* a1 = ac + 0 * 256, *c1 = a1 + HID;   // bn1 L1 (from moments)
  float* a2 = ac + 1 * 256, *c2 = a2 + HID;   // bn2 L1

  // ---- layer 1 (rank-2 shortcut) ----
  k_cnt<<<NBC, 256, 0, stream>>>(x, rp, csr, a01, momp);
  k_bnmom<<<1, 128, 0, stream>>>(momp, ee, bn1g, bn1b, a1, c1);
  k_l1expand<<<2048, 256, 0, stream>>>(a01, ee, Q);                 // u1 -> Q
  k_gemm<1, 0><<<NBLK, 256, 0, stream>>>(Q, wsp + 0 * 32768, a1, c1, Q, part);
  k_bnstat<<<64, 256, 0, stream>>>(part, bn2g, bn2b, a2, c2, SS + 0 * 256, SCT + 0);
  k_act<<<2048, 256, 0, stream>>>(Q, a2, c2, h1);                   // h1 fp16

  // ---- layers 2,3 ----
  int inst = 1;
  for (int i = 1; i < 3; ++i) {
    float* b1a = ac + (2 * i) * 256, *b1c = b1a + HID;
    float* b2a = ac + (2 * i + 1) * 256, *b2c = b2a + HID;
    const int s1 = (i == 1) ? 1 : 3;  // W1[i] slot
    const __half* hin = (i == 1) ? h1 : h2;
    k_agg<<<NN / 4, 256, 0, stream>>>(hin, rp, csr, Q);             // z -> Q
    k_gemm<0, 0><<<NBLK, 256, 0, stream>>>(Q, wsp + (size_t)s1 * 32768,
                                           nullptr, nullptr, Q, part);
    k_bnstat<<<64, 256, 0, stream>>>(part, bn1g + i * HID, bn1b + i * HID, b1a,
                                     b1c, SS + inst * 256, SCT + inst);
    ++inst;
    k_gemm<1, 0><<<NBLK, 256, 0, stream>>>(Q, wsp + (size_t)(s1 + 1) * 32768,
                                           b1a, b1c, Q, part);
    k_bnstat<<<64, 256, 0, stream>>>(part, bn2g + i * HID, bn2b + i * HID, b2a,
                                     b2c, SS + inst * 256, SCT + inst);
    ++inst;
    k_act<<<2048, 256, 0, stream>>>(Q, b2a, b2c, (i == 1) ? h2 : h3);
  }

  // ---- fused readout GEMM over [h1|h2|h3] + rank-2 rep0 bias ----
  k_rdgemm<<<NBLK, 256, 0, stream>>>(h1, h2, h3, wsp + (size_t)5 * 32768, x, ee,
                                     rb1, rW2, rb2, outp);
}

// Round 8
// 719.487 us; speedup vs baseline: 8.3895x; 1.0265x over previous
//
#include <hip/hip_runtime.h>
#include <hip/hip_fp16.h>
#include <cstdint>
#include <cstddef>

#define NN 100000
#define NE 1600000
#define HID 128
#define BN_EPS 1e-5f
#define NB_SCAN 98  // ceil(100000/1024)
#define BM 96
#define NBLK ((NN + BM - 1) / BM)   // 1042 gemm blocks
#define NBC  ((NN + 255) / 256)     // 391 count blocks
#define SA 72   // LDS stride (bf16 elems)
#define SC_CHUNKS 256
#define SC_RANGE (NN / 8)           // 12500
#define SC_EPC (NE / SC_CHUNKS)     // 6250

typedef __attribute__((ext_vector_type(8))) short bf16x8;
typedef __attribute__((ext_vector_type(4))) float f32x4;
typedef __attribute__((ext_vector_type(4))) unsigned short u16x4;

// ---------------- workspace layout (bytes) ----------------
static constexpr size_t SZ_NODE = (size_t)NN * HID * 4;            // 51.2 MB
static constexpr size_t SZ_H16  = (size_t)NN * HID * 2;            // 25.6 MB
static constexpr size_t OFF_P   = 0;                               // h1 fp16 + h2 fp16
static constexpr size_t OFF_Q   = SZ_NODE;                         // z/u/v in-place chain (fp32)
static constexpr size_t OFF_R   = 2 * SZ_NODE;                     // part (1.07MB) then h3 fp16
static constexpr size_t OFF_CSR = 3 * SZ_NODE;
static constexpr size_t OFF_RP  = OFF_CSR + (size_t)NE * 4;
static constexpr size_t OFF_ZZ  = ((OFF_RP + (size_t)(NN + 1) * 4 + 255) / 256) * 256;
static constexpr size_t OFF_CNT = OFF_ZZ;
static constexpr size_t OFF_BS  = OFF_CNT + (((size_t)NN * 4 + 255) / 256) * 256;
static constexpr size_t OFF_FLG = OFF_BS + 512;
static constexpr size_t OFF_SS  = OFF_FLG + 256;                   // 5 x 256 f32 atomic sums
static constexpr size_t OFF_SCT = OFF_SS + 5 * 256 * 4;            // 5 int counters
static constexpr size_t ZZ_END  = ((OFF_SCT + 5 * 4 + 255) / 256) * 256;
static constexpr size_t ZZ_BYTES = ZZ_END - OFF_ZZ;
static constexpr size_t OFF_AC  = ZZ_END;                          // 6 x 256 f32 (bn a/c)
static constexpr size_t OFF_E   = OFF_AC + 6 * 256 * 4;            // ee: e0,e1,r0,r1 = 512 f32
static constexpr size_t OFF_WSP = OFF_E + 512 * 4;                 // 8 mats x [2][128][128] shorts
static constexpr size_t WS_NEEDED = OFF_WSP + (size_t)8 * 2 * HID * HID * 2;

// ---------------- helpers ----------------
__device__ __forceinline__ unsigned short f2bf(float f) {
  unsigned u = __float_as_uint(f);
  unsigned r = (u + 0x7fffu + ((u >> 16) & 1u)) >> 16;
  return (unsigned short)r;
}
__device__ __forceinline__ float bf2f(unsigned short b) {
  return __uint_as_float(((unsigned)b) << 16);
}
__device__ __forceinline__ int edge_at(const int* __restrict__ E, int f, int idx) {
  return f ? E[2 * (long long)idx] : E[idx];
}

// ---------------- dtype detection ----------------
__global__ void k_detect(const int* __restrict__ E, int* __restrict__ flag) {
  if (threadIdx.x == 0 && blockIdx.x == 0) {
    int f = 1;
    for (int i = 1; i < 256; i += 2)
      if (E[i] != 0) { f = 0; break; }
    *flag = f;
  }
}

// ---------------- CSR build ----------------
// XCD-bucketed histogram (same mechanism as k_scatter's round-6 win):
// all writers of a cnt-range co-locate on one XCD -> no cross-XCD line ping-pong.
__global__ __launch_bounds__(256) void k_hist(const int* __restrict__ E,
                                              const int* __restrict__ flag,
                                              int* __restrict__ cnt) {
  const int f = *flag;
  const int r = blockIdx.x & 7;
  const int chunk = blockIdx.x >> 3;
  const int lo = r * SC_RANGE, hi = lo + SC_RANGE;
  const int ebeg = chunk * SC_EPC, eend = ebeg + SC_EPC;
  for (int e = ebeg + threadIdx.x; e < eend; e += 256) {
    int d = edge_at(E, f, NE + e);
    d = min(max(d, 0), NN - 1);
    if (d >= lo && d < hi) atomicAdd(&cnt[d], 1);
  }
}

__global__ __launch_bounds__(256) void k_scan1(const int* __restrict__ cnt,
                                               int* __restrict__ rp,
                                               int* __restrict__ bs) {
  __shared__ int s[256];
  const int tid = threadIdx.x;
  const int base = blockIdx.x * 1024 + tid * 4;
  int v0 = 0, v1 = 0, v2 = 0, v3 = 0;
  if (base + 0 < NN) v0 = cnt[base + 0];
  if (base + 1 < NN) v1 = cnt[base + 1];
  if (base + 2 < NN) v2 = cnt[base + 2];
  if (base + 3 < NN) v3 = cnt[base + 3];
  const int t0 = v0, t1 = t0 + v1, t2 = t1 + v2, t3 = t2 + v3;
  s[tid] = t3;
  __syncthreads();
  for (int off = 1; off < 256; off <<= 1) {
    int xv = 0;
    if (tid >= off) xv = s[tid - off];
    __syncthreads();
    if (tid >= off) s[tid] += xv;
    __syncthreads();
  }
  const int excl = tid ? s[tid - 1] : 0;
  if (base + 0 < NN) rp[base + 0] = excl;
  if (base + 1 < NN) rp[base + 1] = excl + t0;
  if (base + 2 < NN) rp[base + 2] = excl + t1;
  if (base + 3 < NN) rp[base + 3] = excl + t2;
  if (tid == 255) bs[blockIdx.x] = s[255];
}

__global__ __launch_bounds__(128) void k_scan2(int* __restrict__ bs) {
  __shared__ int s[128];
  const int tid = threadIdx.x;
  s[tid] = (tid < NB_SCAN) ? bs[tid] : 0;
  __syncthreads();
  for (int off = 1; off < 128; off <<= 1) {
    int xv = 0;
    if (tid >= off) xv = s[tid - off];
    __syncthreads();
    if (tid >= off) s[tid] += xv;
    __syncthreads();
  }
  if (tid < NB_SCAN) bs[tid] = tid ? s[tid - 1] : 0;
}

__global__ __launch_bounds__(256) void k_scan3(int* __restrict__ rp,
                                               const int* __restrict__ bs,
                                               int* __restrict__ cursor) {
  const int off = bs[blockIdx.x];
  const int base = blockIdx.x * 1024 + threadIdx.x * 4;
  #pragma unroll
  for (int j = 0; j < 4; ++j) {
    const int i = base + j;
    if (i < NN) {
      const int v = rp[i] + off;
      rp[i] = v;
      cursor[i] = v;
    }
  }
  if (blockIdx.x == 0 && threadIdx.x == 0) rp[NN] = NE;
}

// XCD-bucketed scatter (round-6 verified win)
__global__ __launch_bounds__(256) void k_scatter(const int* __restrict__ E,
                                                 const int* __restrict__ flag,
                                                 int* __restrict__ cursor,
                                                 int* __restrict__ csr) {
  const int f = *flag;
  const int r = blockIdx.x & 7;
  const int chunk = blockIdx.x >> 3;
  const int lo = r * SC_RANGE, hi = lo + SC_RANGE;
  const int ebeg = chunk * SC_EPC, eend = ebeg + SC_EPC;
  for (int e = ebeg + threadIdx.x; e < eend; e += 256) {
    int d = edge_at(E, f, NE + e);
    d = min(max(d, 0), NN - 1);
    if (d >= lo && d < hi) {
      int s = edge_at(E, f, e);
      s = min(max(s, 0), NN - 1);
      const int pos = atomicAdd(&cursor[d], 1);
      if ((unsigned)pos < (unsigned)NE) csr[pos] = s;
    }
  }
}

// ---------------- weight pre-split: fp32 [k][n] -> [n][k] bf16 hi/lo ----------------
// slots: 0=W2[0] 1=W1[1] 2=W2[1] 3=W1[2] 4=W2[2] 5=rW1[1] 6=rW1[2] 7=rW1[3]
__global__ __launch_bounds__(256) void k_prepw(const float* __restrict__ W1,
                                               const float* __restrict__ W2,
                                               const float* __restrict__ rW1,
                                               short* __restrict__ wsp) {
  const int g = blockIdx.x * 256 + threadIdx.x;
  const int m = g >> 14, idx = g & 16383;
  const int k = idx >> 7, n = idx & 127;
  const float* src;
  switch (m) {
    case 0: src = W2; break;
    case 1: src = W1 + 1 * HID * HID; break;
    case 2: src = W2 + 1 * HID * HID; break;
    case 3: src = W1 + 2 * HID * HID; break;
    case 4: src = W2 + 2 * HID * HID; break;
    case 5: src = rW1 + 1 * HID * HID; break;
    case 6: src = rW1 + 2 * HID * HID; break;
    default: src = rW1 + 3 * HID * HID; break;
  }
  const float v = src[k * HID + n];
  const unsigned short hb = f2bf(v);
  short* dst = wsp + (size_t)m * 32768;
  dst[n * HID + k] = (short)hb;
  dst[16384 + n * HID + k] = (short)f2bf(v - bf2f(hb));
}

// ---------------- layer-1 rank-2 shortcut ----------------
__global__ __launch_bounds__(256) void k_prep(const float* __restrict__ emb,
                                              const float* __restrict__ W1,
                                              const float* __restrict__ rW1,
                                              float* __restrict__ ee) {
  const int t = threadIdx.x;
  const int f = t & 127;
  const float* er = emb + (t >> 7) * HID;
  float se = 0.f, sr = 0.f;
  for (int k = 0; k < HID; ++k) {
    const float ev = er[k];
    se = fmaf(ev, W1[k * HID + f], se);
    sr = fmaf(ev, rW1[k * HID + f], sr);
  }
  ee[t] = se;        // e0,e1
  ee[256 + t] = sr;  // r0,r1
}

__global__ __launch_bounds__(256) void k_cnt(const int* __restrict__ x,
                                             const int* __restrict__ rp,
                                             const int* __restrict__ csr,
                                             int* __restrict__ a01,
                                             float* __restrict__ momp) {
  const int n = blockIdx.x * 256 + threadIdx.x;
  float m[5] = {0.f, 0.f, 0.f, 0.f, 0.f};
  if (n < NN) {
    const int beg = rp[n], end = rp[n + 1];
    int c1 = 0;
    for (int j = beg; j < end; ++j) c1 += x[csr[j]] & 1;
    const int a1 = c1 + (x[n] & 1);
    const int a0 = (end - beg + 1) - a1;
    a01[n] = a0 | (a1 << 16);
    m[0] = (float)a0;
    m[1] = (float)a1;
    m[2] = (float)a0 * (float)a0;
    m[3] = (float)a1 * (float)a1;
    m[4] = (float)a0 * (float)a1;
  }
  #pragma unroll
  for (int j = 0; j < 5; ++j)
    #pragma unroll
    for (int off = 1; off < 64; off <<= 1) m[j] += __shfl_xor(m[j], off);
  __shared__ float sm[5][4];
  const int lane = threadIdx.x & 63, wv = threadIdx.x >> 6;
  if (lane == 0)
    #pragma unroll
    for (int j = 0; j < 5; ++j) sm[j][wv] = m[j];
  __syncthreads();
  if (threadIdx.x == 0)
    #pragma unroll
    for (int j = 0; j < 5; ++j)
      momp[j * NBC + blockIdx.x] = sm[j][0] + sm[j][1] + sm[j][2] + sm[j][3];
}

__global__ __launch_bounds__(128) void k_bnmom(const float* __restrict__ momp,
                                               const float* __restrict__ ee,
                                               const float* __restrict__ g,
                                               const float* __restrict__ b,
                                               float* __restrict__ a,
                                               float* __restrict__ c) {
  __shared__ float red[5][128];
  const int t = threadIdx.x;
  float s[5] = {0.f, 0.f, 0.f, 0.f, 0.f};
  for (int i = t; i < NBC; i += 128)
    #pragma unroll
    for (int j = 0; j < 5; ++j) s[j] += momp[j * NBC + i];
  #pragma unroll
  for (int j = 0; j < 5; ++j) red[j][t] = s[j];
  __syncthreads();
  for (int off = 64; off; off >>= 1) {
    if (t < off)
      #pragma unroll
      for (int j = 0; j < 5; ++j) red[j][t] += red[j][t + off];
    __syncthreads();
  }
  const float S0 = red[0][0], S1 = red[1][0];
  const float S00 = red[2][0], S11 = red[3][0], S01 = red[4][0];
  const float inv_n = 1.0f / (float)NN;
  const float e0 = ee[t], e1 = ee[128 + t];
  const float mean = (S0 * e0 + S1 * e1) * inv_n;
  const float msq = (S00 * e0 * e0 + 2.f * S01 * e0 * e1 + S11 * e1 * e1) * inv_n;
  float var = fmaxf(msq - mean * mean, 0.f);
  const float rs = rsqrtf(var + BN_EPS);
  const float av = g[t] * rs;
  a[t] = av;
  c[t] = b[t] - mean * av;
}

// u1[n] = a0*e0 + a1*e1
__global__ __launch_bounds__(256) void k_l1expand(const int* __restrict__ a01,
                                                  const float* __restrict__ ee,
                                                  float* __restrict__ u1) {
  const int total = NN * 32;
  for (int i = blockIdx.x * blockDim.x + threadIdx.x; i < total;
       i += gridDim.x * blockDim.x) {
    const int node = i >> 5, q = i & 31;
    const int p = a01[node];
    const float a0 = (float)(p & 0xffff), a1 = (float)(p >> 16);
    const float4 e0q = ((const float4*)ee)[q];
    const float4 e1q = ((const float4*)ee)[32 + q];
    float4 u;
    u.x = a0 * e0q.x + a1 * e1q.x;
    u.y = a0 * e0q.y + a1 * e1q.y;
    u.z = a0 * e0q.z + a1 * e1q.z;
    u.w = a0 * e0q.w + a1 * e1q.w;
    ((float4*)(u1 + (size_t)node * HID))[q] = u;
  }
}

// ---------------- aggregation (fp16 reps): z[n] = h[n] + sum h[src], fp32 out ----------
__global__ __launch_bounds__(256) void k_agg(const __half* __restrict__ h,
                                             const int* __restrict__ rp,
                                             const int* __restrict__ csr,
                                             float* __restrict__ z) {
  const int wid = blockIdx.x * 4 + (threadIdx.x >> 6);
  const int lane = threadIdx.x & 63;
  if (wid >= NN) return;
  const int beg = rp[wid], end = rp[wid + 1];
  float2 acc = __half22float2(*((const __half2*)(h + (size_t)wid * HID) + lane));
  for (int j = beg; j < end; j += 64) {
    const int cnt = min(64, end - j);
    int idx = (lane < cnt) ? csr[j + lane] : 0;
    idx = min(max(idx, 0), NN - 1);
    int k = 0;
    for (; k + 4 <= cnt; k += 4) {
      const int s0 = __shfl(idx, k + 0), s1 = __shfl(idx, k + 1);
      const int s2 = __shfl(idx, k + 2), s3 = __shfl(idx, k + 3);
      const float2 v0 = __half22float2(*((const __half2*)(h + (size_t)s0 * HID) + lane));
      const float2 v1 = __half22float2(*((const __half2*)(h + (size_t)s1 * HID) + lane));
      const float2 v2 = __half22float2(*((const __half2*)(h + (size_t)s2 * HID) + lane));
      const float2 v3 = __half22float2(*((const __half2*)(h + (size_t)s3 * HID) + lane));
      acc.x += (v0.x + v1.x) + (v2.x + v3.x);
      acc.y += (v0.y + v1.y) + (v2.y + v3.y);
    }
    for (; k < cnt; ++k) {
      const int s = __shfl(idx, k);
      const float2 v = __half22float2(*((const __half2*)(h + (size_t)s * HID) + lane));
      acc.x += v.x;
      acc.y += v.y;
    }
  }
  *(float2*)(z + (size_t)wid * HID + lane * 2) = acc;
}

// ---------------- split-bf16 MFMA GEMM, W fragments DIRECT from global ----------------
// A staged in LDS (27KB); W (pre-split, [n][k], L2-resident) loaded per-fragment.
// IN_ACT: 0 identity, 1 relu(a*ina+inc)
// OUT_MODE: 0 store + per-block column stats
template <int IN_ACT, int OUT_MODE>
__global__ __launch_bounds__(256, 4) void k_gemm(
    float* A, const short* __restrict__ Wsp,
    const float* __restrict__ ina, const float* __restrict__ inc,
    float* __restrict__ out, float* __restrict__ part) {
  __shared__ short Ah[BM * SA];
  __shared__ short Al[BM * SA];
  const int tid = threadIdx.x;
  const int lane = tid & 63, wv = tid >> 6;
  const int tq = lane >> 4, tl = lane & 15;
  const int wc = wv * 32;
  const int m0 = blockIdx.x * BM;

  f32x4 acc[6][2];
  #pragma unroll
  for (int i = 0; i < 6; ++i)
    #pragma unroll
    for (int j = 0; j < 2; ++j) acc[i][j] = (f32x4)(0.f);

  for (int kt = 0; kt < HID; kt += 64) {
    if (kt) __syncthreads();
    #pragma unroll
    for (int p = 0; p < 6; ++p) {
      const int flat = p * 256 + tid;
      const int m = flat >> 4, kq = flat & 15;
      const int gm = m0 + m, gk = kt + kq * 4;
      float vv[4] = {0.f, 0.f, 0.f, 0.f};
      if (gm < NN) {
        const float4 v = *(const float4*)(A + (size_t)gm * HID + gk);
        vv[0] = v.x; vv[1] = v.y; vv[2] = v.z; vv[3] = v.w;
        if (IN_ACT == 1) {
          const float4 a4 = *(const float4*)(ina + gk);
          const float4 c4 = *(const float4*)(inc + gk);
          vv[0] = fmaxf(fmaf(vv[0], a4.x, c4.x), 0.f);
          vv[1] = fmaxf(fmaf(vv[1], a4.y, c4.y), 0.f);
          vv[2] = fmaxf(fmaf(vv[2], a4.z, c4.z), 0.f);
          vv[3] = fmaxf(fmaf(vv[3], a4.w, c4.w), 0.f);
        }
      }
      u16x4 hh, ll;
      #pragma unroll
      for (int j = 0; j < 4; ++j) {
        const unsigned short hb = f2bf(vv[j]);
        hh[j] = hb;
        ll[j] = f2bf(vv[j] - bf2f(hb));
      }
      *(u16x4*)(&Ah[m * SA + kq * 4]) = hh;
      *(u16x4*)(&Al[m * SA + kq * 4]) = ll;
    }
    __syncthreads();
    #pragma unroll
    for (int kc = 0; kc < 64; kc += 32) {
      const int lo = kc + tq * 8;        // LDS k-offset within tile
      const int go = kt + lo;            // global k
      bf16x8 wh[2], wl[2];
      #pragma unroll
      for (int fn = 0; fn < 2; ++fn) {
        const int n = wc + fn * 16 + tl;
        wh[fn] = *(const bf16x8*)(Wsp + n * HID + go);
        wl[fn] = *(const bf16x8*)(Wsp + 16384 + n * HID + go);
      }
      #pragma unroll
      for (int fm = 0; fm < 6; ++fm) {
        const int r = (fm * 16 + tl) * SA + lo;
        const bf16x8 ah = *(const bf16x8*)(&Ah[r]);
        const bf16x8 al = *(const bf16x8*)(&Al[r]);
        #pragma unroll
        for (int fn = 0; fn < 2; ++fn) {
          acc[fm][fn] = __builtin_amdgcn_mfma_f32_16x16x32_bf16(ah, wh[fn], acc[fm][fn], 0, 0, 0);
          acc[fm][fn] = __builtin_amdgcn_mfma_f32_16x16x32_bf16(ah, wl[fn], acc[fm][fn], 0, 0, 0);
          acc[fm][fn] = __builtin_amdgcn_mfma_f32_16x16x32_bf16(al, wh[fn], acc[fm][fn], 0, 0, 0);
        }
      }
    }
  }

  #pragma unroll
  for (int fm = 0; fm < 6; ++fm) {
    #pragma unroll
    for (int reg = 0; reg < 4; ++reg) {
      const int row = m0 + fm * 16 + tq * 4 + reg;
      if (row < NN) {
        float* op = out + (size_t)row * HID + wc + tl;
        op[0] = acc[fm][0][reg];
        op[16] = acc[fm][1][reg];
      }
    }
  }
  if (OUT_MODE == 0) {
    #pragma unroll
    for (int fn = 0; fn < 2; ++fn) {
      float s = 0.f, q = 0.f;
      #pragma unroll
      for (int fm = 0; fm < 6; ++fm)
        #pragma unroll
        for (int reg = 0; reg < 4; ++reg) {
          const float v = acc[fm][fn][reg];
          s += v;
          q = fmaf(v, v, q);
        }
      s += __shfl_xor(s, 16); q += __shfl_xor(q, 16);
      s += __shfl_xor(s, 32); q += __shfl_xor(q, 32);
      if (lane < 16) {
        const int col = wc + fn * 16 + lane;
        part[(size_t)blockIdx.x * 256 + col] = s;
        part[(size_t)blockIdx.x * 256 + 128 + col] = q;
      }
    }
  }
}

// ---------------- readout GEMM (W direct from global): K=384 over [h1|h2|h3] ----------
__global__ __launch_bounds__(256, 4) void k_rdgemm(
    const __half* __restrict__ h1, const __half* __restrict__ h2,
    const __half* __restrict__ h3, const short* __restrict__ wsp,
    const int* __restrict__ x, const float* __restrict__ ee,
    const float* __restrict__ rb1, const float* __restrict__ rW2,
    const float* __restrict__ rb2, float* __restrict__ out) {
  __shared__ short Ah[BM * SA];
  __shared__ short Al[BM * SA];
  const int tid = threadIdx.x;
  const int lane = tid & 63, wv = tid >> 6;
  const int tq = lane >> 4, tl = lane & 15;
  const int wc = wv * 32;
  const int m0 = blockIdx.x * BM;

  f32x4 acc[6][2];
  #pragma unroll
  for (int i = 0; i < 6; ++i)
    #pragma unroll
    for (int j = 0; j < 2; ++j) acc[i][j] = (f32x4)(0.f);

  for (int t6 = 0; t6 < 6; ++t6) {  // K=384: {h1,h2,h3} x {0,64}
    const __half* hsrc = (t6 < 2) ? h1 : (t6 < 4) ? h2 : h3;
    const short* Ws = wsp + (size_t)(t6 >> 1) * 32768;
    const int kt = (t6 & 1) * 64;
    if (t6) __syncthreads();
    #pragma unroll
    for (int p = 0; p < 6; ++p) {
      const int flat = p * 256 + tid;
      const int m = flat >> 4, kq = flat & 15;
      const int gm = m0 + m, gk = kt + kq * 4;
      float vv[4] = {0.f, 0.f, 0.f, 0.f};
      if (gm < NN) {
        const __half2 x0 = *(const __half2*)(hsrc + (size_t)gm * HID + gk);
        const __half2 x1 = *(const __half2*)(hsrc + (size_t)gm * HID + gk + 2);
        const float2 f0 = __half22float2(x0);
        const float2 f1 = __half22float2(x1);
        vv[0] = f0.x; vv[1] = f0.y; vv[2] = f1.x; vv[3] = f1.y;
      }
      u16x4 hh, ll;
      #pragma unroll
      for (int j = 0; j < 4; ++j) {
        const unsigned short hb = f2bf(vv[j]);
        hh[j] = hb;
        ll[j] = f2bf(vv[j] - bf2f(hb));
      }
      *(u16x4*)(&Ah[m * SA + kq * 4]) = hh;
      *(u16x4*)(&Al[m * SA + kq * 4]) = ll;
    }
    __syncthreads();
    #pragma unroll
    for (int kc = 0; kc < 64; kc += 32) {
      const int lo = kc + tq * 8;
      const int go = kt + lo;
      bf16x8 wh[2], wl[2];
      #pragma unroll
      for (int fn = 0; fn < 2; ++fn) {
        const int n = wc + fn * 16 + tl;
        wh[fn] = *(const bf16x8*)(Ws + n * HID + go);
        wl[fn] = *(const bf16x8*)(Ws + 16384 + n * HID + go);
      }
      #pragma unroll
      for (int fm = 0; fm < 6; ++fm) {
        const int r = (fm * 16 + tl) * SA + lo;
        const bf16x8 ah = *(const bf16x8*)(&Ah[r]);
        const bf16x8 al = *(const bf16x8*)(&Al[r]);
        #pragma unroll
        for (int fn = 0; fn < 2; ++fn) {
          acc[fm][fn] = __builtin_amdgcn_mfma_f32_16x16x32_bf16(ah, wh[fn], acc[fm][fn], 0, 0, 0);
          acc[fm][fn] = __builtin_amdgcn_mfma_f32_16x16x32_bf16(ah, wl[fn], acc[fm][fn], 0, 0, 0);
          acc[fm][fn] = __builtin_amdgcn_mfma_f32_16x16x32_bf16(al, wh[fn], acc[fm][fn], 0, 0, 0);
        }
      }
    }
  }

  // epilogue: + rb1 + (x ? r1 : r0), relu, dot rW2, reduce 128 cols per row
  const int c0 = wc + tl, c1 = wc + 16 + tl;
  const float rb_0 = rb1[c0], rb_1 = rb1[c1];
  const float w2_0 = rW2[c0], w2_1 = rW2[c1];
  const float r0_0 = ee[256 + c0], r0_1 = ee[256 + c1];
  const float r1_0 = ee[384 + c0], r1_1 = ee[384 + c1];
  __syncthreads();                 // done reading Ah -> reuse as reduction buffer
  float* rs = (float*)Ah;          // [96][4]
  #pragma unroll
  for (int fm = 0; fm < 6; ++fm) {
    #pragma unroll
    for (int reg = 0; reg < 4; ++reg) {
      const int row = fm * 16 + tq * 4 + reg;
      const int grow = m0 + row;
      const int xv = (grow < NN) ? (x[grow] & 1) : 0;
      const float g0 = acc[fm][0][reg] + rb_0 + (xv ? r1_0 : r0_0);
      const float g1 = acc[fm][1][reg] + rb_1 + (xv ? r1_1 : r0_1);
      float p = fmaxf(g0, 0.f) * w2_0 + fmaxf(g1, 0.f) * w2_1;
      p += __shfl_xor(p, 1);
      p += __shfl_xor(p, 2);
      p += __shfl_xor(p, 4);
      p += __shfl_xor(p, 8);
      if (tl == 0) rs[row * 4 + wv] = p;
    }
  }
  __syncthreads();
  if (tid < BM) {
    const int grow = m0 + tid;
    if (grow < NN)
      out[grow] = rs[tid * 4 + 0] + rs[tid * 4 + 1] + rs[tid * 4 + 2] +
                  rs[tid * 4 + 3] + rb2[0];
  }
}

// ---------------- fused stats reduce + BN finalize ----------------
__global__ __launch_bounds__(256) void k_bnstat(const float* __restrict__ part,
                                                const float* __restrict__ g,
                                                const float* __restrict__ b,
                                                float* __restrict__ a,
                                                float* __restrict__ c,
                                                float* __restrict__ S,
                                                int* __restrict__ ctr) {
  const int tid = threadIdx.x;
  float acc = 0.f;
  for (int r = blockIdx.x; r < NBLK; r += 64) acc += part[(size_t)r * 256 + tid];
  atomicAdd(&S[tid], acc);
  __syncthreads();
  __threadfence();
  __shared__ int last;
  if (tid == 0) last = (atomicAdd(ctr, 1) == 63);
  __syncthreads();
  if (!last) return;
  __threadfence();
  const float tot = atomicAdd(&S[tid], 0.f);
  __shared__ float sm[256];
  sm[tid] = tot;
  __syncthreads();
  if (tid < 128) {
    const float inv_n = 1.0f / (float)NN;
    const float mean = sm[tid] * inv_n;
    float var = fmaxf(sm[tid + 128] * inv_n - mean * mean, 0.f);
    const float rs = rsqrtf(var + BN_EPS);
    const float av = g[tid] * rs;
    a[tid] = av;
    c[tid] = b[tid] - mean * av;
  }
}

// ---------------- elementwise: h = elu(v*a + c) -> fp16 ----------------
__global__ __launch_bounds__(256) void k_act(const float* __restrict__ v,
                                             const float* __restrict__ a,
                                             const float* __restrict__ c,
                                             __half* __restrict__ h) {
  const int total = NN * 32;
  for (int i = blockIdx.x * blockDim.x + threadIdx.x; i < total;
       i += gridDim.x * blockDim.x) {
    const int node = i >> 5, q = i & 31;
    const float4 vv = *(const float4*)(v + (size_t)node * HID + q * 4);
    const float4 a4 = ((const float4*)a)[q];
    const float4 c4 = ((const float4*)c)[q];
    float z;
    float o0, o1, o2, o3;
    z = fmaf(vv.x, a4.x, c4.x); o0 = z > 0.f ? z : expm1f(z);
    z = fmaf(vv.y, a4.y, c4.y); o1 = z > 0.f ? z : expm1f(z);
    z = fmaf(vv.z, a4.z, c4.z); o2 = z > 0.f ? z : expm1f(z);
    z = fmaf(vv.w, a4.w, c4.w); o3 = z > 0.f ? z : expm1f(z);
    const __half2 p0 = __floats2half2_rn(o0, o1);
    const __half2 p1 = __floats2half2_rn(o2, o3);
    uint2 u;
    u.x = *reinterpret_cast<const unsigned*>(&p0);
    u.y = *reinterpret_cast<const unsigned*>(&p1);
    *(uint2*)(h + (size_t)node * HID + q * 4) = u;
  }
}

// ---------------- launcher ----------------
extern "C" void kernel_launch(void* const* d_in, const int* in_sizes, int n_in,
                              void* d_out, int out_size, void* d_ws,
                              size_t ws_size, hipStream_t stream) {
  if (ws_size < WS_NEEDED) return;

  const int* x = (const int*)d_in[0];
  const int* E = (const int*)d_in[1];
  const float* emb = (const float*)d_in[2];
  const float* W1 = (const float*)d_in[3];
  const float* W2 = (const float*)d_in[4];
  const float* bn1g = (const float*)d_in[5];
  const float* bn1b = (const float*)d_in[6];
  const float* bn2g = (const float*)d_in[7];
  const float* bn2b = (const float*)d_in[8];
  const float* rW1 = (const float*)d_in[9];
  const float* rb1 = (const float*)d_in[10];
  const float* rW2 = (const float*)d_in[11];
  const float* rb2 = (const float*)d_in[12];
  float* outp = (float*)d_out;

  char* ws = (char*)d_ws;
  float* P = (float*)(ws + OFF_P);
  float* Q = (float*)(ws + OFF_Q);
  float* R = (float*)(ws + OFF_R);
  int* csr = (int*)(ws + OFF_CSR);
  int* rp = (int*)(ws + OFF_RP);
  int* cnt = (int*)(ws + OFF_CNT);
  int* bs = (int*)(ws + OFF_BS);
  int* flag = (int*)(ws + OFF_FLG);
  float* SS = (float*)(ws + OFF_SS);
  int* SCT = (int*)(ws + OFF_SCT);
  float* ac = (float*)(ws + OFF_AC);
  float* ee = (float*)(ws + OFF_E);
  short* wsp = (short*)(ws + OFF_WSP);
  __half* h1 = (__half*)P;
  __half* h2 = (__half*)((char*)P + SZ_H16);
  __half* h3 = (__half*)R;
  float* part = R;                 // 1.07 MB, time-shared with h3
  int* a01 = (int*)((char*)P + (4 << 20));
  float* momp = (float*)((char*)P + (8 << 20));

  hipMemsetAsync(ws + OFF_ZZ, 0, ZZ_BYTES, stream);
  k_detect<<<1, 64, 0, stream>>>(E, flag);
  k_hist<<<SC_CHUNKS * 8, 256, 0, stream>>>(E, flag, cnt);
  k_scan1<<<NB_SCAN, 256, 0, stream>>>(cnt, rp, bs);
  k_scan2<<<1, 128, 0, stream>>>(bs);
  k_scan3<<<NB_SCAN, 256, 0, stream>>>(rp, bs, cnt);
  k_scatter<<<SC_CHUNKS * 8, 256, 0, stream>>>(E, flag, cnt, csr);
  k_prep<<<1, 256, 0, stream>>>(emb, W1, rW1, ee);
  k_prepw<<<512, 256, 0, stream>>>(W1, W2, rW1, wsp);

  float* a1 = ac + 0 * 256, *c1 = a1 + HID;
  float* a2 = ac + 1 * 256, *c2 = a2 + HID;

  // ---- layer 1 (rank-2 shortcut) ----
  k_cnt<<<NBC, 256, 0, stream>>>(x, rp, csr, a01, momp);
  k_bnmom<<<1, 128, 0, stream>>>(momp, ee, bn1g, bn1b, a1, c1);
  k_l1expand<<<2048, 256, 0, stream>>>(a01, ee, Q);
  k_gemm<1, 0><<<NBLK, 256, 0, stream>>>(Q, wsp + 0 * 32768, a1, c1, Q, part);
  k_bnstat<<<64, 256, 0, stream>>>(part, bn2g, bn2b, a2, c2, SS + 0 * 256, SCT + 0);
  k_act<<<2048, 256, 0, stream>>>(Q, a2, c2, h1);

  // ---- layers 2,3 ----
  int inst = 1;
  for (int i = 1; i < 3; ++i) {
    float* b1a = ac + (2 * i) * 256, *b1c = b1a + HID;
    float* b2a = ac + (2 * i + 1) * 256, *b2c = b2a + HID;
    const int s1 = (i == 1) ? 1 : 3;  // W1[i] slot
    const __half* hin = (i == 1) ? h1 : h2;
    k_agg<<<NN / 4, 256, 0, stream>>>(hin, rp, csr, Q);
    k_gemm<0, 0><<<NBLK, 256, 0, stream>>>(Q, wsp + (size_t)s1 * 32768,
                                           nullptr, nullptr, Q, part);
    k_bnstat<<<64, 256, 0, stream>>>(part, bn1g + i * HID, bn1b + i * HID, b1a,
                                     b1c, SS + inst * 256, SCT + inst);
    ++inst;
    k_gemm<1, 0><<<NBLK, 256, 0, stream>>>(Q, wsp + (size_t)(s1 + 1) * 32768,
                                           b1a, b1c, Q, part);
    k_bnstat<<<64, 256, 0, stream>>>(part, bn2g + i * HID, bn2b + i * HID, b2a,
                                     b2c, SS + inst * 256, SCT + inst);
    ++inst;
    k_act<<<2048, 256, 0, stream>>>(Q, b2a, b2c, (i == 1) ? h2 : h3);
  }

  // ---- fused readout GEMM over [h1|h2|h3] + rank-2 rep0 bias ----
  k_rdgemm<<<NBLK, 256, 0, stream>>>(h1, h2, h3, wsp + (size_t)5 * 32768, x, ee,
                                     rb1, rW2, rb2, outp);
}

// Round 9
// 710.134 us; speedup vs baseline: 8.5000x; 1.0132x over previous
//
#include <hip/hip_runtime.h>
#include <hip/hip_fp16.h>
#include <cstdint>
#include <cstddef>

#define NN 100000
#define NE 1600000
#define HID 128
#define BN_EPS 1e-5f
#define NB_SCAN 98  // ceil(100000/1024)
#define BM 96
#define NBLK ((NN + BM - 1) / BM)   // 1042 gemm blocks
#define NBC  ((NN + 255) / 256)     // 391 count blocks
#define SA 72   // LDS stride (16-bit elems)
#define SC_CHUNKS 256
#define SC_RANGE (NN / 8)           // 12500
#define SC_EPC (NE / SC_CHUNKS)     // 6250

typedef __attribute__((ext_vector_type(8))) short bf16x8;
typedef __attribute__((ext_vector_type(8))) _Float16 f16x8;
typedef __attribute__((ext_vector_type(4))) float f32x4;
typedef __attribute__((ext_vector_type(4))) unsigned short u16x4;

// ---------------- workspace layout (bytes) ----------------
static constexpr size_t SZ_NODE = (size_t)NN * HID * 4;            // 51.2 MB
static constexpr size_t SZ_H16  = (size_t)NN * HID * 2;            // 25.6 MB
static constexpr size_t OFF_P   = 0;                               // h1 fp16 + h2 fp16
static constexpr size_t OFF_Q   = SZ_NODE;                         // z/u/v in-place chain (fp32)
static constexpr size_t OFF_R   = 2 * SZ_NODE;                     // part (1.07MB) then h3 fp16
static constexpr size_t OFF_CSR = 3 * SZ_NODE;
static constexpr size_t OFF_RP  = OFF_CSR + (size_t)NE * 4;
static constexpr size_t OFF_ZZ  = ((OFF_RP + (size_t)(NN + 1) * 4 + 255) / 256) * 256;
static constexpr size_t OFF_CNT = OFF_ZZ;
static constexpr size_t OFF_BS  = OFF_CNT + (((size_t)NN * 4 + 255) / 256) * 256;
static constexpr size_t OFF_FLG = OFF_BS + 512;
static constexpr size_t OFF_SS  = OFF_FLG + 256;                   // 5 x 256 f32 atomic sums
static constexpr size_t OFF_SCT = OFF_SS + 5 * 256 * 4;            // 5 int counters
static constexpr size_t ZZ_END  = ((OFF_SCT + 5 * 4 + 255) / 256) * 256;
static constexpr size_t ZZ_BYTES = ZZ_END - OFF_ZZ;
static constexpr size_t OFF_AC  = ZZ_END;                          // 6 x 256 f32 (bn a/c)
static constexpr size_t OFF_E   = OFF_AC + 6 * 256 * 4;            // ee: e0,e1,r0,r1 = 512 f32
static constexpr size_t OFF_WSP = OFF_E + 512 * 4;                 // 8 mats x [2][128][128] shorts
static constexpr size_t WS_NEEDED = OFF_WSP + (size_t)8 * 2 * HID * HID * 2;

// ---------------- helpers ----------------
__device__ __forceinline__ unsigned short f2bf(float f) {
  unsigned u = __float_as_uint(f);
  unsigned r = (u + 0x7fffu + ((u >> 16) & 1u)) >> 16;
  return (unsigned short)r;
}
__device__ __forceinline__ float bf2f(unsigned short b) {
  return __uint_as_float(((unsigned)b) << 16);
}
__device__ __forceinline__ int edge_at(const int* __restrict__ E, int f, int idx) {
  return f ? E[2 * (long long)idx] : E[idx];
}

// ---------------- dtype detection ----------------
__global__ void k_detect(const int* __restrict__ E, int* __restrict__ flag) {
  if (threadIdx.x == 0 && blockIdx.x == 0) {
    int f = 1;
    for (int i = 1; i < 256; i += 2)
      if (E[i] != 0) { f = 0; break; }
    *flag = f;
  }
}

// ---------------- CSR build (XCD-bucketed hist + scatter: round 6/8 verified) --------
__global__ __launch_bounds__(256) void k_hist(const int* __restrict__ E,
                                              const int* __restrict__ flag,
                                              int* __restrict__ cnt) {
  const int f = *flag;
  const int r = blockIdx.x & 7;
  const int chunk = blockIdx.x >> 3;
  const int lo = r * SC_RANGE, hi = lo + SC_RANGE;
  const int ebeg = chunk * SC_EPC, eend = ebeg + SC_EPC;
  for (int e = ebeg + threadIdx.x; e < eend; e += 256) {
    int d = edge_at(E, f, NE + e);
    d = min(max(d, 0), NN - 1);
    if (d >= lo && d < hi) atomicAdd(&cnt[d], 1);
  }
}

__global__ __launch_bounds__(256) void k_scan1(const int* __restrict__ cnt,
                                               int* __restrict__ rp,
                                               int* __restrict__ bs) {
  __shared__ int s[256];
  const int tid = threadIdx.x;
  const int base = blockIdx.x * 1024 + tid * 4;
  int v0 = 0, v1 = 0, v2 = 0, v3 = 0;
  if (base + 0 < NN) v0 = cnt[base + 0];
  if (base + 1 < NN) v1 = cnt[base + 1];
  if (base + 2 < NN) v2 = cnt[base + 2];
  if (base + 3 < NN) v3 = cnt[base + 3];
  const int t0 = v0, t1 = t0 + v1, t2 = t1 + v2, t3 = t2 + v3;
  s[tid] = t3;
  __syncthreads();
  for (int off = 1; off < 256; off <<= 1) {
    int xv = 0;
    if (tid >= off) xv = s[tid - off];
    __syncthreads();
    if (tid >= off) s[tid] += xv;
    __syncthreads();
  }
  const int excl = tid ? s[tid - 1] : 0;
  if (base + 0 < NN) rp[base + 0] = excl;
  if (base + 1 < NN) rp[base + 1] = excl + t0;
  if (base + 2 < NN) rp[base + 2] = excl + t1;
  if (base + 3 < NN) rp[base + 3] = excl + t2;
  if (tid == 255) bs[blockIdx.x] = s[255];
}

__global__ __launch_bounds__(128) void k_scan2(int* __restrict__ bs) {
  __shared__ int s[128];
  const int tid = threadIdx.x;
  s[tid] = (tid < NB_SCAN) ? bs[tid] : 0;
  __syncthreads();
  for (int off = 1; off < 128; off <<= 1) {
    int xv = 0;
    if (tid >= off) xv = s[tid - off];
    __syncthreads();
    if (tid >= off) s[tid] += xv;
    __syncthreads();
  }
  if (tid < NB_SCAN) bs[tid] = tid ? s[tid - 1] : 0;
}

__global__ __launch_bounds__(256) void k_scan3(int* __restrict__ rp,
                                               const int* __restrict__ bs,
                                               int* __restrict__ cursor) {
  const int off = bs[blockIdx.x];
  const int base = blockIdx.x * 1024 + threadIdx.x * 4;
  #pragma unroll
  for (int j = 0; j < 4; ++j) {
    const int i = base + j;
    if (i < NN) {
      const int v = rp[i] + off;
      rp[i] = v;
      cursor[i] = v;
    }
  }
  if (blockIdx.x == 0 && threadIdx.x == 0) rp[NN] = NE;
}

// scatter embeds x[src] in csr bit31: downstream k_cnt reads csr LINEARLY
__global__ __launch_bounds__(256) void k_scatter(const int* __restrict__ E,
                                                 const int* __restrict__ flag,
                                                 const int* __restrict__ x,
                                                 int* __restrict__ cursor,
                                                 int* __restrict__ csr) {
  const int f = *flag;
  const int r = blockIdx.x & 7;
  const int chunk = blockIdx.x >> 3;
  const int lo = r * SC_RANGE, hi = lo + SC_RANGE;
  const int ebeg = chunk * SC_EPC, eend = ebeg + SC_EPC;
  for (int e = ebeg + threadIdx.x; e < eend; e += 256) {
    int d = edge_at(E, f, NE + e);
    d = min(max(d, 0), NN - 1);
    if (d >= lo && d < hi) {
      int s = edge_at(E, f, e);
      s = min(max(s, 0), NN - 1);
      const int xb = x[s] & 1;            // 400KB table: L2-resident gather
      const int pos = atomicAdd(&cursor[d], 1);
      if ((unsigned)pos < (unsigned)NE) csr[pos] = s | (xb << 31);
    }
  }
}

// ---------------- weight pre-split ----------------
// slots 0-4 (layer GEMMs, bf16 hi/lo): 0=W2[0] 1=W1[1] 2=W2[1] 3=W1[2] 4=W2[2]
// slots 5-7 (rdgemm, fp16 hi + fp16 lo*2048): 5=rW1[1] 6=rW1[2] 7=rW1[3]
__global__ __launch_bounds__(256) void k_prepw(const float* __restrict__ W1,
                                               const float* __restrict__ W2,
                                               const float* __restrict__ rW1,
                                               short* __restrict__ wsp) {
  const int g = blockIdx.x * 256 + threadIdx.x;
  const int m = g >> 14, idx = g & 16383;
  const int k = idx >> 7, n = idx & 127;
  const float* src;
  switch (m) {
    case 0: src = W2; break;
    case 1: src = W1 + 1 * HID * HID; break;
    case 2: src = W2 + 1 * HID * HID; break;
    case 3: src = W1 + 2 * HID * HID; break;
    case 4: src = W2 + 2 * HID * HID; break;
    case 5: src = rW1 + 1 * HID * HID; break;
    case 6: src = rW1 + 2 * HID * HID; break;
    default: src = rW1 + 3 * HID * HID; break;
  }
  const float v = src[k * HID + n];
  short* dst = wsp + (size_t)m * 32768;
  if (m < 5) {
    const unsigned short hb = f2bf(v);
    dst[n * HID + k] = (short)hb;
    dst[16384 + n * HID + k] = (short)f2bf(v - bf2f(hb));
  } else {
    const __half hh = __float2half_rn(v);
    const float rem = v - __half2float(hh);
    const __half hl = __float2half_rn(rem * 2048.f);
    dst[n * HID + k] = (short)__half_as_ushort(hh);
    dst[16384 + n * HID + k] = (short)__half_as_ushort(hl);
  }
}

// ---------------- layer-1 rank-2 shortcut ----------------
__global__ __launch_bounds__(256) void k_prep(const float* __restrict__ emb,
                                              const float* __restrict__ W1,
                                              const float* __restrict__ rW1,
                                              float* __restrict__ ee) {
  const int t = threadIdx.x;
  const int f = t & 127;
  const float* er = emb + (t >> 7) * HID;
  float se = 0.f, sr = 0.f;
  for (int k = 0; k < HID; ++k) {
    const float ev = er[k];
    se = fmaf(ev, W1[k * HID + f], se);
    sr = fmaf(ev, rW1[k * HID + f], sr);
  }
  ee[t] = se;        // e0,e1
  ee[256 + t] = sr;  // r0,r1
}

// per-node class counts from LINEAR csr read (x-bit in bit31)
__global__ __launch_bounds__(256) void k_cnt(const int* __restrict__ x,
                                             const int* __restrict__ rp,
                                             const int* __restrict__ csr,
                                             int* __restrict__ a01,
                                             float* __restrict__ momp) {
  const int n = blockIdx.x * 256 + threadIdx.x;
  float m[5] = {0.f, 0.f, 0.f, 0.f, 0.f};
  if (n < NN) {
    const int beg = rp[n], end = rp[n + 1];
    int c1 = 0;
    for (int j = beg; j < end; ++j) c1 += (int)(((unsigned)csr[j]) >> 31);
    const int a1 = c1 + (x[n] & 1);
    const int a0 = (end - beg + 1) - a1;
    a01[n] = a0 | (a1 << 16);
    m[0] = (float)a0;
    m[1] = (float)a1;
    m[2] = (float)a0 * (float)a0;
    m[3] = (float)a1 * (float)a1;
    m[4] = (float)a0 * (float)a1;
  }
  #pragma unroll
  for (int j = 0; j < 5; ++j)
    #pragma unroll
    for (int off = 1; off < 64; off <<= 1) m[j] += __shfl_xor(m[j], off);
  __shared__ float sm[5][4];
  const int lane = threadIdx.x & 63, wv = threadIdx.x >> 6;
  if (lane == 0)
    #pragma unroll
    for (int j = 0; j < 5; ++j) sm[j][wv] = m[j];
  __syncthreads();
  if (threadIdx.x == 0)
    #pragma unroll
    for (int j = 0; j < 5; ++j)
      momp[j * NBC + blockIdx.x] = sm[j][0] + sm[j][1] + sm[j][2] + sm[j][3];
}

__global__ __launch_bounds__(128) void k_bnmom(const float* __restrict__ momp,
                                               const float* __restrict__ ee,
                                               const float* __restrict__ g,
                                               const float* __restrict__ b,
                                               float* __restrict__ a,
                                               float* __restrict__ c) {
  __shared__ float red[5][128];
  const int t = threadIdx.x;
  float s[5] = {0.f, 0.f, 0.f, 0.f, 0.f};
  for (int i = t; i < NBC; i += 128)
    #pragma unroll
    for (int j = 0; j < 5; ++j) s[j] += momp[j * NBC + i];
  #pragma unroll
  for (int j = 0; j < 5; ++j) red[j][t] = s[j];
  __syncthreads();
  for (int off = 64; off; off >>= 1) {
    if (t < off)
      #pragma unroll
      for (int j = 0; j < 5; ++j) red[j][t] += red[j][t + off];
    __syncthreads();
  }
  const float S0 = red[0][0], S1 = red[1][0];
  const float S00 = red[2][0], S11 = red[3][0], S01 = red[4][0];
  const float inv_n = 1.0f / (float)NN;
  const float e0 = ee[t], e1 = ee[128 + t];
  const float mean = (S0 * e0 + S1 * e1) * inv_n;
  const float msq = (S00 * e0 * e0 + 2.f * S01 * e0 * e1 + S11 * e1 * e1) * inv_n;
  float var = fmaxf(msq - mean * mean, 0.f);
  const float rs = rsqrtf(var + BN_EPS);
  const float av = g[t] * rs;
  a[t] = av;
  c[t] = b[t] - mean * av;
}

// ---------------- aggregation (fp16 reps, bit31-masked csr) ----------------
__global__ __launch_bounds__(256) void k_agg(const __half* __restrict__ h,
                                             const int* __restrict__ rp,
                                             const int* __restrict__ csr,
                                             float* __restrict__ z) {
  const int wid = blockIdx.x * 4 + (threadIdx.x >> 6);
  const int lane = threadIdx.x & 63;
  if (wid >= NN) return;
  const int beg = rp[wid], end = rp[wid + 1];
  float2 acc = __half22float2(*((const __half2*)(h + (size_t)wid * HID) + lane));
  for (int j = beg; j < end; j += 64) {
    const int cnt = min(64, end - j);
    int idx = (lane < cnt) ? (csr[j + lane] & 0x7fffffff) : 0;
    idx = min(idx, NN - 1);
    int k = 0;
    for (; k + 4 <= cnt; k += 4) {
      const int s0 = __shfl(idx, k + 0), s1 = __shfl(idx, k + 1);
      const int s2 = __shfl(idx, k + 2), s3 = __shfl(idx, k + 3);
      const float2 v0 = __half22float2(*((const __half2*)(h + (size_t)s0 * HID) + lane));
      const float2 v1 = __half22float2(*((const __half2*)(h + (size_t)s1 * HID) + lane));
      const float2 v2 = __half22float2(*((const __half2*)(h + (size_t)s2 * HID) + lane));
      const float2 v3 = __half22float2(*((const __half2*)(h + (size_t)s3 * HID) + lane));
      acc.x += (v0.x + v1.x) + (v2.x + v3.x);
      acc.y += (v0.y + v1.y) + (v2.y + v3.y);
    }
    for (; k < cnt; ++k) {
      const int s = __shfl(idx, k);
      const float2 v = __half22float2(*((const __half2*)(h + (size_t)s * HID) + lane));
      acc.x += v.x;
      acc.y += v.y;
    }
  }
  *(float2*)(z + (size_t)wid * HID + lane * 2) = acc;
}

// ---------------- split-bf16 MFMA GEMM, W fragments DIRECT from global ----------------
// IN_ACT: 0 identity, 1 relu(a*ina+inc), 2 rank-2 expand (a01/ee) + relu(.*ina+inc)
// OUT_MODE: 0 store + per-block column stats
template <int IN_ACT, int OUT_MODE>
__global__ __launch_bounds__(256, 4) void k_gemm(
    float* A, const short* __restrict__ Wsp,
    const float* __restrict__ ina, const float* __restrict__ inc,
    float* __restrict__ out, float* __restrict__ part,
    const int* __restrict__ a01, const float* __restrict__ ee) {
  __shared__ short Ah[BM * SA];
  __shared__ short Al[BM * SA];
  const int tid = threadIdx.x;
  const int lane = tid & 63, wv = tid >> 6;
  const int tq = lane >> 4, tl = lane & 15;
  const int wc = wv * 32;
  const int m0 = blockIdx.x * BM;

  f32x4 acc[6][2];
  #pragma unroll
  for (int i = 0; i < 6; ++i)
    #pragma unroll
    for (int j = 0; j < 2; ++j) acc[i][j] = (f32x4)(0.f);

  for (int kt = 0; kt < HID; kt += 64) {
    if (kt) __syncthreads();
    #pragma unroll
    for (int p = 0; p < 6; ++p) {
      const int flat = p * 256 + tid;
      const int m = flat >> 4, kq = flat & 15;
      const int gm = m0 + m, gk = kt + kq * 4;
      float vv[4] = {0.f, 0.f, 0.f, 0.f};
      if (gm < NN) {
        if (IN_ACT == 2) {
          const int pk = a01[gm];
          const float a0 = (float)(pk & 0xffff), a1 = (float)(pk >> 16);
          const float4 e0q = *(const float4*)(ee + gk);
          const float4 e1q = *(const float4*)(ee + 128 + gk);
          vv[0] = a0 * e0q.x + a1 * e1q.x;
          vv[1] = a0 * e0q.y + a1 * e1q.y;
          vv[2] = a0 * e0q.z + a1 * e1q.z;
          vv[3] = a0 * e0q.w + a1 * e1q.w;
        } else {
          const float4 v = *(const float4*)(A + (size_t)gm * HID + gk);
          vv[0] = v.x; vv[1] = v.y; vv[2] = v.z; vv[3] = v.w;
        }
        if (IN_ACT >= 1) {
          const float4 a4 = *(const float4*)(ina + gk);
          const float4 c4 = *(const float4*)(inc + gk);
          vv[0] = fmaxf(fmaf(vv[0], a4.x, c4.x), 0.f);
          vv[1] = fmaxf(fmaf(vv[1], a4.y, c4.y), 0.f);
          vv[2] = fmaxf(fmaf(vv[2], a4.z, c4.z), 0.f);
          vv[3] = fmaxf(fmaf(vv[3], a4.w, c4.w), 0.f);
        }
      }
      u16x4 hh, ll;
      #pragma unroll
      for (int j = 0; j < 4; ++j) {
        const unsigned short hb = f2bf(vv[j]);
        hh[j] = hb;
        ll[j] = f2bf(vv[j] - bf2f(hb));
      }
      *(u16x4*)(&Ah[m * SA + kq * 4]) = hh;
      *(u16x4*)(&Al[m * SA + kq * 4]) = ll;
    }
    __syncthreads();
    #pragma unroll
    for (int kc = 0; kc < 64; kc += 32) {
      const int lo = kc + tq * 8;
      const int go = kt + lo;
      bf16x8 wh[2], wl[2];
      #pragma unroll
      for (int fn = 0; fn < 2; ++fn) {
        const int n = wc + fn * 16 + tl;
        wh[fn] = *(const bf16x8*)(Wsp + n * HID + go);
        wl[fn] = *(const bf16x8*)(Wsp + 16384 + n * HID + go);
      }
      #pragma unroll
      for (int fm = 0; fm < 6; ++fm) {
        const int r = (fm * 16 + tl) * SA + lo;
        const bf16x8 ah = *(const bf16x8*)(&Ah[r]);
        const bf16x8 al = *(const bf16x8*)(&Al[r]);
        #pragma unroll
        for (int fn = 0; fn < 2; ++fn) {
          acc[fm][fn] = __builtin_amdgcn_mfma_f32_16x16x32_bf16(ah, wh[fn], acc[fm][fn], 0, 0, 0);
          acc[fm][fn] = __builtin_amdgcn_mfma_f32_16x16x32_bf16(ah, wl[fn], acc[fm][fn], 0, 0, 0);
          acc[fm][fn] = __builtin_amdgcn_mfma_f32_16x16x32_bf16(al, wh[fn], acc[fm][fn], 0, 0, 0);
        }
      }
    }
  }

  #pragma unroll
  for (int fm = 0; fm < 6; ++fm) {
    #pragma unroll
    for (int reg = 0; reg < 4; ++reg) {
      const int row = m0 + fm * 16 + tq * 4 + reg;
      if (row < NN) {
        float* op = out + (size_t)row * HID + wc + tl;
        op[0] = acc[fm][0][reg];
        op[16] = acc[fm][1][reg];
      }
    }
  }
  if (OUT_MODE == 0) {
    #pragma unroll
    for (int fn = 0; fn < 2; ++fn) {
      float s = 0.f, q = 0.f;
      #pragma unroll
      for (int fm = 0; fm < 6; ++fm)
        #pragma unroll
        for (int reg = 0; reg < 4; ++reg) {
          const float v = acc[fm][fn][reg];
          s += v;
          q = fmaf(v, v, q);
        }
      s += __shfl_xor(s, 16); q += __shfl_xor(q, 16);
      s += __shfl_xor(s, 32); q += __shfl_xor(q, 32);
      if (lane < 16) {
        const int col = wc + fn * 16 + lane;
        part[(size_t)blockIdx.x * 256 + col] = s;
        part[(size_t)blockIdx.x * 256 + 128 + col] = q;
      }
    }
  }
}

// ---------------- readout GEMM: exact-fp16 A, fp16-split W (hi + lo*2048) -------------
// A staging = raw copy (h IS fp16); 2 MFMAs/fragment; final = acc_hi + acc_lo/2048.
__global__ __launch_bounds__(256, 3) void k_rdgemm(
    const __half* __restrict__ h1, const __half* __restrict__ h2,
    const __half* __restrict__ h3, const short* __restrict__ wsp,
    const int* __restrict__ x, const float* __restrict__ ee,
    const float* __restrict__ rb1, const float* __restrict__ rW2,
    const float* __restrict__ rb2, float* __restrict__ out) {
  __shared__ short Ah[BM * SA];   // raw fp16
  const int tid = threadIdx.x;
  const int lane = tid & 63, wv = tid >> 6;
  const int tq = lane >> 4, tl = lane & 15;
  const int wc = wv * 32;
  const int m0 = blockIdx.x * BM;

  f32x4 ach[6][2], acl[6][2];
  #pragma unroll
  for (int i = 0; i < 6; ++i)
    #pragma unroll
    for (int j = 0; j < 2; ++j) { ach[i][j] = (f32x4)(0.f); acl[i][j] = (f32x4)(0.f); }

  for (int t6 = 0; t6 < 6; ++t6) {  // K=384: {h1,h2,h3} x {0,64}
    const __half* hsrc = (t6 < 2) ? h1 : (t6 < 4) ? h2 : h3;
    const short* Ws = wsp + (size_t)(t6 >> 1) * 32768;
    const int kt = (t6 & 1) * 64;
    if (t6) __syncthreads();
    // raw fp16 copy into LDS — zero conversion
    #pragma unroll
    for (int p = 0; p < 6; ++p) {
      const int flat = p * 256 + tid;
      const int m = flat >> 4, kq = flat & 15;
      const int gm = m0 + m, gk = kt + kq * 4;
      u16x4 hv = (u16x4)(0);
      if (gm < NN) hv = *(const u16x4*)((const unsigned short*)hsrc + (size_t)gm * HID + gk);
      *(u16x4*)(&Ah[m * SA + kq * 4]) = hv;
    }
    __syncthreads();
    #pragma unroll
    for (int kc = 0; kc < 64; kc += 32) {
      const int lo = kc + tq * 8;
      const int go = kt + lo;
      f16x8 wh[2], wl[2];
      #pragma unroll
      for (int fn = 0; fn < 2; ++fn) {
        const int n = wc + fn * 16 + tl;
        wh[fn] = *(const f16x8*)(Ws + n * HID + go);
        wl[fn] = *(const f16x8*)(Ws + 16384 + n * HID + go);
      }
      #pragma unroll
      for (int fm = 0; fm < 6; ++fm) {
        const f16x8 a = *(const f16x8*)(&Ah[(fm * 16 + tl) * SA + lo]);
        #pragma unroll
        for (int fn = 0; fn < 2; ++fn) {
          ach[fm][fn] = __builtin_amdgcn_mfma_f32_16x16x32_f16(a, wh[fn], ach[fm][fn], 0, 0, 0);
          acl[fm][fn] = __builtin_amdgcn_mfma_f32_16x16x32_f16(a, wl[fn], acl[fm][fn], 0, 0, 0);
        }
      }
    }
  }

  // epilogue: combine hi + lo/2048, + rb1 + (x ? r1 : r0), relu, dot rW2, row-reduce
  const int c0 = wc + tl, c1 = wc + 16 + tl;
  const float rb_0 = rb1[c0], rb_1 = rb1[c1];
  const float w2_0 = rW2[c0], w2_1 = rW2[c1];
  const float r0_0 = ee[256 + c0], r0_1 = ee[256 + c1];
  const float r1_0 = ee[384 + c0], r1_1 = ee[384 + c1];
  const float LS = 1.0f / 2048.0f;
  __syncthreads();
  float* rs = (float*)Ah;          // [96][4]
  #pragma unroll
  for (int fm = 0; fm < 6; ++fm) {
    #pragma unroll
    for (int reg = 0; reg < 4; ++reg) {
      const int row = fm * 16 + tq * 4 + reg;
      const int grow = m0 + row;
      const int xv = (grow < NN) ? (x[grow] & 1) : 0;
      const float g0 = ach[fm][0][reg] + acl[fm][0][reg] * LS + rb_0 + (xv ? r1_0 : r0_0);
      const float g1 = ach[fm][1][reg] + acl[fm][1][reg] * LS + rb_1 + (xv ? r1_1 : r0_1);
      float p = fmaxf(g0, 0.f) * w2_0 + fmaxf(g1, 0.f) * w2_1;
      p += __shfl_xor(p, 1);
      p += __shfl_xor(p, 2);
      p += __shfl_xor(p, 4);
      p += __shfl_xor(p, 8);
      if (tl == 0) rs[row * 4 + wv] = p;
    }
  }
  __syncthreads();
  if (tid < BM) {
    const int grow = m0 + tid;
    if (grow < NN)
      out[grow] = rs[tid * 4 + 0] + rs[tid * 4 + 1] + rs[tid * 4 + 2] +
                  rs[tid * 4 + 3] + rb2[0];
  }
}

// ---------------- fused stats reduce + BN finalize ----------------
__global__ __launch_bounds__(256) void k_bnstat(const float* __restrict__ part,
                                                const float* __restrict__ g,
                                                const float* __restrict__ b,
                                                float* __restrict__ a,
                                                float* __restrict__ c,
                                                float* __restrict__ S,
                                                int* __restrict__ ctr) {
  const int tid = threadIdx.x;
  float acc = 0.f;
  for (int r = blockIdx.x; r < NBLK; r += 64) acc += part[(size_t)r * 256 + tid];
  atomicAdd(&S[tid], acc);
  __syncthreads();
  __threadfence();
  __shared__ int last;
  if (tid == 0) last = (atomicAdd(ctr, 1) == 63);
  __syncthreads();
  if (!last) return;
  __threadfence();
  const float tot = atomicAdd(&S[tid], 0.f);
  __shared__ float sm[256];
  sm[tid] = tot;
  __syncthreads();
  if (tid < 128) {
    const float inv_n = 1.0f / (float)NN;
    const float mean = sm[tid] * inv_n;
    float var = fmaxf(sm[tid + 128] * inv_n - mean * mean, 0.f);
    const float rs = rsqrtf(var + BN_EPS);
    const float av = g[tid] * rs;
    a[tid] = av;
    c[tid] = b[tid] - mean * av;
  }
}

// ---------------- elementwise: h = elu(v*a + c) -> fp16 ----------------
__global__ __launch_bounds__(256) void k_act(const float* __restrict__ v,
                                             const float* __restrict__ a,
                                             const float* __restrict__ c,
                                             __half* __restrict__ h) {
  const int total = NN * 32;
  for (int i = blockIdx.x * blockDim.x + threadIdx.x; i < total;
       i += gridDim.x * blockDim.x) {
    const int node = i >> 5, q = i & 31;
    const float4 vv = *(const float4*)(v + (size_t)node * HID + q * 4);
    const float4 a4 = ((const float4*)a)[q];
    const float4 c4 = ((const float4*)c)[q];
    float z;
    float o0, o1, o2, o3;
    z = fmaf(vv.x, a4.x, c4.x); o0 = z > 0.f ? z : expm1f(z);
    z = fmaf(vv.y, a4.y, c4.y); o1 = z > 0.f ? z : expm1f(z);
    z = fmaf(vv.z, a4.z, c4.z); o2 = z > 0.f ? z : expm1f(z);
    z = fmaf(vv.w, a4.w, c4.w); o3 = z > 0.f ? z : expm1f(z);
    const __half2 p0 = __floats2half2_rn(o0, o1);
    const __half2 p1 = __floats2half2_rn(o2, o3);
    uint2 u;
    u.x = *reinterpret_cast<const unsigned*>(&p0);
    u.y = *reinterpret_cast<const unsigned*>(&p1);
    *(uint2*)(h + (size_t)node * HID + q * 4) = u;
  }
}

// ---------------- launcher ----------------
extern "C" void kernel_launch(void* const* d_in, const int* in_sizes, int n_in,
                              void* d_out, int out_size, void* d_ws,
                              size_t ws_size, hipStream_t stream) {
  if (ws_size < WS_NEEDED) return;

  const int* x = (const int*)d_in[0];
  const int* E = (const int*)d_in[1];
  const float* emb = (const float*)d_in[2];
  const float* W1 = (const float*)d_in[3];
  const float* W2 = (const float*)d_in[4];
  const float* bn1g = (const float*)d_in[5];
  const float* bn1b = (const float*)d_in[6];
  const float* bn2g = (const float*)d_in[7];
  const float* bn2b = (const float*)d_in[8];
  const float* rW1 = (const float*)d_in[9];
  const float* rb1 = (const float*)d_in[10];
  const float* rW2 = (const float*)d_in[11];
  const float* rb2 = (const float*)d_in[12];
  float* outp = (float*)d_out;

  char* ws = (char*)d_ws;
  float* P = (float*)(ws + OFF_P);
  float* Q = (float*)(ws + OFF_Q);
  float* R = (float*)(ws + OFF_R);
  int* csr = (int*)(ws + OFF_CSR);
  int* rp = (int*)(ws + OFF_RP);
  int* cnt = (int*)(ws + OFF_CNT);
  int* bs = (int*)(ws + OFF_BS);
  int* flag = (int*)(ws + OFF_FLG);
  float* SS = (float*)(ws + OFF_SS);
  int* SCT = (int*)(ws + OFF_SCT);
  float* ac = (float*)(ws + OFF_AC);
  float* ee = (float*)(ws + OFF_E);
  short* wsp = (short*)(ws + OFF_WSP);
  __half* h1 = (__half*)P;
  __half* h2 = (__half*)((char*)P + SZ_H16);
  __half* h3 = (__half*)R;
  float* part = R;                 // 1.07 MB, time-shared with h3
  int* a01 = (int*)((char*)P + (4 << 20));
  float* momp = (float*)((char*)P + (8 << 20));

  hipMemsetAsync(ws + OFF_ZZ, 0, ZZ_BYTES, stream);
  k_detect<<<1, 64, 0, stream>>>(E, flag);
  k_hist<<<SC_CHUNKS * 8, 256, 0, stream>>>(E, flag, cnt);
  k_scan1<<<NB_SCAN, 256, 0, stream>>>(cnt, rp, bs);
  k_scan2<<<1, 128, 0, stream>>>(bs);
  k_scan3<<<NB_SCAN, 256, 0, stream>>>(rp, bs, cnt);
  k_scatter<<<SC_CHUNKS * 8, 256, 0, stream>>>(E, flag, x, cnt, csr);
  k_prep<<<1, 256, 0, stream>>>(emb, W1, rW1, ee);
  k_prepw<<<512, 256, 0, stream>>>(W1, W2, rW1, wsp);

  float* a1 = ac + 0 * 256, *c1 = a1 + HID;
  float* a2 = ac + 1 * 256, *c2 = a2 + HID;

  // ---- layer 1 (rank-2 shortcut; u1 expanded inside the GEMM) ----
  k_cnt<<<NBC, 256, 0, stream>>>(x, rp, csr, a01, momp);
  k_bnmom<<<1, 128, 0, stream>>>(momp, ee, bn1g, bn1b, a1, c1);
  k_gemm<2, 0><<<NBLK, 256, 0, stream>>>(Q, wsp + 0 * 32768, a1, c1, Q, part,
                                         a01, ee);
  k_bnstat<<<64, 256, 0, stream>>>(part, bn2g, bn2b, a2, c2, SS + 0 * 256, SCT + 0);
  k_act<<<2048, 256, 0, stream>>>(Q, a2, c2, h1);

  // ---- layers 2,3 ----
  int inst = 1;
  for (int i = 1; i < 3; ++i) {
    float* b1a = ac + (2 * i) * 256, *b1c = b1a + HID;
    float* b2a = ac + (2 * i + 1) * 256, *b2c = b2a + HID;
    const int s1 = (i == 1) ? 1 : 3;  // W1[i] slot
    const __half* hin = (i == 1) ? h1 : h2;
    k_agg<<<NN / 4, 256, 0, stream>>>(hin, rp, csr, Q);
    k_gemm<0, 0><<<NBLK, 256, 0, stream>>>(Q, wsp + (size_t)s1 * 32768,
                                           nullptr, nullptr, Q, part, nullptr,
                                           nullptr);
    k_bnstat<<<64, 256, 0, stream>>>(part, bn1g + i * HID, bn1b + i * HID, b1a,
                                     b1c, SS + inst * 256, SCT + inst);
    ++inst;
    k_gemm<1, 0><<<NBLK, 256, 0, stream>>>(Q, wsp + (size_t)(s1 + 1) * 32768,
                                           b1a, b1c, Q, part, nullptr, nullptr);
    k_bnstat<<<64, 256, 0, stream>>>(part, bn2g + i * HID, bn2b + i * HID, b2a,
                                     b2c, SS + inst * 256, SCT + inst);
    ++inst;
    k_act<<<2048, 256, 0, stream>>>(Q, b2a, b2c, (i == 1) ? h2 : h3);
  }

  // ---- fused readout GEMM over [h1|h2|h3] + rank-2 rep0 bias ----
  k_rdgemm<<<NBLK, 256, 0, stream>>>(h1, h2, h3, wsp + (size_t)5 * 32768, x, ee,
                                     rb1, rW2, rb2, outp);
}